// Round 1
// baseline (2155.624 us; speedup 1.0000x reference)
//
#include <hip/hip_runtime.h>
#include <math.h>

#define BB 8
#define LL 12
#define NN 1024
#define FF 3
#define HH 32
#define NDD 10
#define TTT 10
#define PP 3
#define DOUTT 128
constexpr float kALPHA = 3.0f;

// ---------------- workspace layout (floats) ----------------
constexpr size_t OFF_HIST   = 0;                                         // B*L*N*32
constexpr size_t OFF_H0     = OFF_HIST  + (size_t)BB*LL*NN*HH;           // B*L*N*96 (xs0|xs1|resid)
constexpr size_t OFF_S4     = OFF_H0    + (size_t)BB*LL*NN*3*HH;         // B*L*N*4
constexpr size_t OFF_RATIO  = OFF_S4    + (size_t)BB*LL*NN*4;            // B*N*3
constexpr size_t OFF_CENT   = OFF_RATIO + (size_t)BB*NN*3;               // 32
constexpr size_t OFF_M1     = OFF_CENT  + 32;                            // N*10
constexpr size_t OFF_M2     = OFF_M1    + (size_t)NN*NDD;                // N*10
constexpr size_t OFF_LABEL  = OFF_M2    + (size_t)NN*NDD;                // N ints
constexpr size_t OFF_AN     = OFF_LABEL + NN;                            // N*N
constexpr size_t OFF_ACOMB  = OFF_AN    + (size_t)NN*NN;                 // N*N
constexpr size_t OFF_X0     = OFF_ACOMB + (size_t)NN*NN;                 // N * 8192
constexpr size_t OFF_HFIN   = OFF_X0    + (size_t)NN*BB*HH*HH;           // N * 8192
constexpr size_t OFF_WCOMBO = OFF_HFIN  + (size_t)NN*BB*HH*HH;           // 32*128
constexpr size_t OFF_XOUT   = OFF_WCOMBO+ (size_t)HH*DOUTT;              // B*12*N*128
constexpr size_t OFF_FC     = OFF_XOUT  + (size_t)BB*LL*NN*DOUTT;        // B*12*N*3
constexpr size_t WS_FLOATS  = OFF_FC    + (size_t)BB*LL*NN*3;            // ~179 MB

// ---------------- K1: embed + std decomposition ----------------
__global__ __launch_bounds__(256) void k1_embed(
    const float* __restrict__ hd, const float* __restrict__ W_emb, const float* __restrict__ b_emb,
    const float* __restrict__ T_emb, const float* __restrict__ D_emb, const float* __restrict__ node_u,
    const float* __restrict__ W_std, const float* __restrict__ b_std,
    const float* __restrict__ W_mlp, const float* __restrict__ b_mlp,
    float* __restrict__ hist, float* __restrict__ h0, float* __restrict__ s4)
{
    __shared__ float sW[2*62*32];
    for (int i = threadIdx.x; i < 2*62*32; i += 256) sW[i] = W_std[i];
    __syncthreads();

    int pos = blockIdx.x*256 + threadIdx.x;           // 0..98303
    int n = pos & (NN-1);
    const float* hp = hd + (size_t)pos*5;
    float f0 = hp[0], f1 = hp[1], f2 = hp[2];
    int ti = (int)(hp[3]*288.0f);
    int di = (int)hp[4];

    float tv[10], dv[10], nu[10];
#pragma unroll
    for (int t = 0; t < 10; t++) {
        tv[t] = T_emb[ti*10+t]; dv[t] = D_emb[di*10+t]; nu[t] = node_u[n*10+t];
    }
    float h[32];
#pragma unroll
    for (int j = 0; j < 32; j++) h[j] = b_emb[j] + f0*W_emb[j] + f1*W_emb[32+j] + f2*W_emb[64+j];

    float a0[32], a1[32];
#pragma unroll
    for (int j = 0; j < 32; j++) { a0[j] = b_std[j]; a1[j] = b_std[32+j]; }

    auto accum = [&](float v, int i) {
#pragma unroll
        for (int q = 0; q < 8; q++) {
            float4 w0 = *(const float4*)&sW[i*32 + q*4];
            float4 w1 = *(const float4*)&sW[(62+i)*32 + q*4];
            a0[q*4+0] += v*w0.x; a0[q*4+1] += v*w0.y; a0[q*4+2] += v*w0.z; a0[q*4+3] += v*w0.w;
            a1[q*4+0] += v*w1.x; a1[q*4+1] += v*w1.y; a1[q*4+2] += v*w1.z; a1[q*4+3] += v*w1.w;
        }
    };
#pragma unroll
    for (int i = 0; i < 32; i++) accum(h[i], i);
#pragma unroll
    for (int i = 0; i < 10; i++) accum(nu[i], 32+i);
#pragma unroll
    for (int i = 0; i < 10; i++) accum(tv[i], 42+i);
#pragma unroll
    for (int i = 0; i < 10; i++) accum(dv[i], 52+i);

    float x0v[32], x1v[32], rv[32];
    float s0 = b_mlp[0], s1 = b_mlp[1], s2 = b_mlp[2], s3 = b_mlp[3];
#pragma unroll
    for (int j = 0; j < 32; j++) {
        float sg0 = 1.f/(1.f + __expf(-a0[j]));
        float sg1 = 1.f/(1.f + __expf(-a1[j]));
        x0v[j] = sg0*h[j]; x1v[j] = sg1*h[j]; rv[j] = h[j] - x0v[j] - x1v[j];
        s0 += h[j]  * W_mlp[j];
        s1 += x0v[j]* W_mlp[32+j];
        s2 += x1v[j]* W_mlp[64+j];
        s3 += rv[j] * W_mlp[96+j];
    }
    float* ho = hist + (size_t)pos*32;
    float* hz = h0   + (size_t)pos*96;
#pragma unroll
    for (int q = 0; q < 8; q++) {
        *(float4*)&ho[q*4]    = make_float4(h[q*4],   h[q*4+1],   h[q*4+2],   h[q*4+3]);
        *(float4*)&hz[q*4]    = make_float4(x0v[q*4], x0v[q*4+1], x0v[q*4+2], x0v[q*4+3]);
        *(float4*)&hz[32+q*4] = make_float4(x1v[q*4], x1v[q*4+1], x1v[q*4+2], x1v[q*4+3]);
        *(float4*)&hz[64+q*4] = make_float4(rv[q*4],  rv[q*4+1],  rv[q*4+2],  rv[q*4+3]);
    }
    *(float4*)&s4[(size_t)pos*4] = make_float4(s0, s1, s2, s3);
}

// ---------------- K2: ratios ----------------
__global__ void k2_ratio(const float* __restrict__ s4, float* __restrict__ ratio)
{
    int bn = blockIdx.x*256 + threadIdx.x;
    if (bn >= BB*NN) return;
    int b = bn >> 10, n = bn & 1023;
    float a0=0, a1=0, a2=0, a3=0;
    for (int l = 0; l < 12; l++) {
        const float* sp = s4 + ((size_t)(b*12+l)*NN + n)*4;
        a0 += sp[0]; a1 += sp[1]; a2 += sp[2]; a3 += sp[3];
    }
    float hm = a0/12.f;
    float* rp = ratio + (size_t)bn*3;
    rp[0] = (a1/12.f)/(hm + 1e-6f);
    rp[1] = (a2/12.f)/(hm + 1e-6f);
    rp[2] = (a3/12.f)/(hm + 1e-6f);
}

// ---------------- K3: per-b centers (max over n) ----------------
__global__ __launch_bounds__(256) void k3_centers(const float* __restrict__ ratio, float* __restrict__ centers)
{
    int b = blockIdx.x;
    float m0=-3.4e38f, m1v=-3.4e38f, m2v=-3.4e38f;
    for (int n = threadIdx.x; n < NN; n += 256) {
        const float* rp = ratio + ((size_t)b*NN + n)*3;
        m0 = fmaxf(m0, rp[0]); m1v = fmaxf(m1v, rp[1]); m2v = fmaxf(m2v, rp[2]);
    }
#pragma unroll
    for (int off = 32; off > 0; off >>= 1) {
        m0  = fmaxf(m0,  __shfl_down(m0,  off));
        m1v = fmaxf(m1v, __shfl_down(m1v, off));
        m2v = fmaxf(m2v, __shfl_down(m2v, off));
    }
    __shared__ float red[4][3];
    int wid = threadIdx.x >> 6, lane = threadIdx.x & 63;
    if (lane == 0) { red[wid][0]=m0; red[wid][1]=m1v; red[wid][2]=m2v; }
    __syncthreads();
    if (threadIdx.x == 0) {
        centers[b*3+0] = fmaxf(fmaxf(red[0][0],red[1][0]), fmaxf(red[2][0],red[3][0]));
        centers[b*3+1] = fmaxf(fmaxf(red[0][1],red[1][1]), fmaxf(red[2][1],red[3][1]));
        centers[b*3+2] = fmaxf(fmaxf(red[0][2],red[1][2]), fmaxf(red[2][2],red[3][2]));
    }
}

// ---------------- K4: labels + m1/m2 = tanh(3*node) ----------------
__global__ void k4_labels(const float* __restrict__ ratio, const float* __restrict__ centers,
                          const float* __restrict__ node_u, const float* __restrict__ node_d,
                          int* __restrict__ label, float* __restrict__ m1, float* __restrict__ m2)
{
    int n = blockIdx.x*256 + threadIdx.x;
    if (n >= NN) return;
    int c0=0, c1=0, c2=0;
    for (int b = 0; b < BB; b++) {
        const float* rp = ratio + ((size_t)b*NN + n)*3;
        const float* cp = centers + b*3;
        float d0 = fabsf(rp[0]-cp[0]), d1 = fabsf(rp[1]-cp[1]), d2 = fabsf(rp[2]-cp[2]);
        int a = 0; float best = d0;
        if (d1 < best) { best = d1; a = 1; }
        if (d2 < best) { best = d2; a = 2; }
        if (a == 0) c0++; else if (a == 1) c1++; else c2++;
    }
    int lab = 0, bc = c0;
    if (c1 > bc) { bc = c1; lab = 1; }
    if (c2 > bc) { bc = c2; lab = 2; }
    label[n] = lab;
#pragma unroll
    for (int d = 0; d < 10; d++) {
        m1[n*10+d] = tanhf(kALPHA*node_u[n*10+d]);
        m2[n*10+d] = tanhf(kALPHA*node_d[n*10+d]);
    }
}

// ---------------- K5: An = normalized label-masked adjacency ----------------
__global__ __launch_bounds__(256) void k5_A(const float* __restrict__ m1, const float* __restrict__ m2,
                                            const int* __restrict__ label, float* __restrict__ An)
{
    int n = blockIdx.x;
    __shared__ float row[1024];
    __shared__ float m1n[10], m2n[10];
    __shared__ float ssum[4];
    int t = threadIdx.x;
    if (t < 10) { m1n[t] = m1[n*10+t]; m2n[t] = m2[n*10+t]; }
    __syncthreads();
    int labn = label[n];
    float lsum = 0.f;
    for (int m = t; m < 1024; m += 256) {
        float a = 0.f;
        if (label[m] == labn) {
            float x = 0.f;
#pragma unroll
            for (int d = 0; d < 10; d++) x += m1n[d]*m2[m*10+d] - m2n[d]*m1[m*10+d];
            a = fmaxf(tanhf(3.f*x), 0.f);
        }
        row[m] = a; lsum += a;
    }
#pragma unroll
    for (int off = 32; off > 0; off >>= 1) lsum += __shfl_down(lsum, off);
    int wid = t >> 6, lane = t & 63;
    if (lane == 0) ssum[wid] = lsum;
    __syncthreads();
    float inv = 1.f/((ssum[0]+ssum[1]+ssum[2]+ssum[3]) + 1e-6f);
    for (int m = t; m < 1024; m += 256) An[(size_t)n*1024 + m] = row[m]*inv;
}

// ---------------- generic fp32 GEMM, 128x128 tile, 8x8 micro ----------------
// MODE 0: C = 0.9025*(A@B) + 0.0475*A + 0.05*I   (Acomb; A square, K==Ncol)
// MODE 1: C = A@B                                (propagation)
template<int MODE>
__global__ __launch_bounds__(256) void gemm128(const float* __restrict__ A, const float* __restrict__ Bm,
                                               float* __restrict__ C, int Mrows, int Ncol, int K)
{
    __shared__ float As[16][132];
    __shared__ float Bs[16][128];
    const int tid = threadIdx.x;
    const int tc = tid & 15, tr = tid >> 4;
    const int row0 = blockIdx.y*128, col0 = blockIdx.x*128;
    float acc[8][8];
#pragma unroll
    for (int i = 0; i < 8; i++)
#pragma unroll
        for (int j = 0; j < 8; j++) acc[i][j] = 0.f;

    const int ar = tid >> 2;          // 0..63
    const int ak = (tid & 3)*4;       // 0,4,8,12
    const int bc = (tid & 31)*4;      // col quad
    const int bk = tid >> 5;          // 0..7

    for (int k0 = 0; k0 < K; k0 += 16) {
        float4 a0 = *(const float4*)&A[(size_t)(row0+ar)*K + k0 + ak];
        float4 a1 = *(const float4*)&A[(size_t)(row0+64+ar)*K + k0 + ak];
        float4 b0 = *(const float4*)&Bm[(size_t)(k0+bk)*Ncol + col0 + bc];
        float4 b1 = *(const float4*)&Bm[(size_t)(k0+8+bk)*Ncol + col0 + bc];
        __syncthreads();
        As[ak+0][ar] = a0.x; As[ak+1][ar] = a0.y; As[ak+2][ar] = a0.z; As[ak+3][ar] = a0.w;
        As[ak+0][64+ar] = a1.x; As[ak+1][64+ar] = a1.y; As[ak+2][64+ar] = a1.z; As[ak+3][64+ar] = a1.w;
        *(float4*)&Bs[bk][bc]   = b0;
        *(float4*)&Bs[8+bk][bc] = b1;
        __syncthreads();
#pragma unroll
        for (int kk = 0; kk < 16; kk++) {
            float av[8], bv[8];
            *(float4*)&av[0] = *(const float4*)&As[kk][tr*8];
            *(float4*)&av[4] = *(const float4*)&As[kk][tr*8+4];
            *(float4*)&bv[0] = *(const float4*)&Bs[kk][tc*8];
            *(float4*)&bv[4] = *(const float4*)&Bs[kk][tc*8+4];
#pragma unroll
            for (int i = 0; i < 8; i++)
#pragma unroll
                for (int j = 0; j < 8; j++) acc[i][j] += av[i]*bv[j];
        }
    }
#pragma unroll
    for (int i = 0; i < 8; i++) {
        int r = row0 + tr*8 + i;
#pragma unroll
        for (int q = 0; q < 2; q++) {
            int c = col0 + tc*8 + q*4;
            float4 o;
            o.x = acc[i][q*4+0]; o.y = acc[i][q*4+1]; o.z = acc[i][q*4+2]; o.w = acc[i][q*4+3];
            if (MODE == 0) {
                o.x = 0.9025f*o.x + 0.0475f*A[(size_t)r*K + c+0] + ((r==c+0)?0.05f:0.f);
                o.y = 0.9025f*o.y + 0.0475f*A[(size_t)r*K + c+1] + ((r==c+1)?0.05f:0.f);
                o.z = 0.9025f*o.z + 0.0475f*A[(size_t)r*K + c+2] + ((r==c+2)?0.05f:0.f);
                o.w = 0.9025f*o.w + 0.0475f*A[(size_t)r*K + c+3] + ((r==c+3)?0.05f:0.f);
            }
            *(float4*)&C[(size_t)r*Ncol + c] = o;
        }
    }
}

// ---------------- K7: x0[n, b*1024 + c*32 + h] = sum_l W_start[c,l]*hist[b,l,n,h] + b_start[c] ----------------
__global__ __launch_bounds__(256) void k7_x0(const float* __restrict__ hist,
                                             const float* __restrict__ W_start, const float* __restrict__ b_start,
                                             float* __restrict__ x0)
{
    int bid = blockIdx.x; int n = bid & (NN-1), b = bid >> 10;
    __shared__ float hl[384];  // [l*32+h]
    __shared__ float sw[384];  // [c*12+l]
    int t = threadIdx.x;
    for (int idx = t; idx < 384; idx += 256) {
        int l = idx >> 5, hh = idx & 31;
        hl[idx] = hist[((size_t)(b*12+l)*NN + n)*32 + hh];
    }
    for (int idx = t; idx < 384; idx += 256) sw[idx] = W_start[idx];
    __syncthreads();
    int c = t >> 3, h4 = (t & 7)*4;
    float bs = b_start[c];
    float o0 = bs, o1 = bs, o2 = bs, o3 = bs;
#pragma unroll
    for (int l = 0; l < 12; l++) {
        float w = sw[c*12+l];
        o0 += w*hl[l*32+h4];   o1 += w*hl[l*32+h4+1];
        o2 += w*hl[l*32+h4+2]; o3 += w*hl[l*32+h4+3];
    }
    *(float4*)&x0[(size_t)n*8192 + b*1024 + c*32 + h4] = make_float4(o0, o1, o2, o3);
}

// ---------------- Kw: Wcombo = (Wg0+Wg1) @ W_rnn  (32x128) ----------------
__global__ void kw_combo(const float* __restrict__ W_g, const float* __restrict__ W_rnn, float* __restrict__ wcombo)
{
    int j = threadIdx.x; // 128
    for (int hh = 0; hh < 32; hh++) {
        float s = 0.f;
        for (int k = 0; k < 32; k++) s += (W_g[hh*32+k] + W_g[1024 + hh*32+k]) * W_rnn[k*128 + j];
        wcombo[hh*128 + j] = s;
    }
}

// ---------------- K9: per (b,n): xr=tanh(h2@Wcombo+b_rnn); e1 relu; e2; *M ----------------
__global__ void k9_rnn(const float* __restrict__ hfin, const float* __restrict__ wcombo,
                       const float* __restrict__ b_rnn, const float* __restrict__ W_e1,
                       const float* __restrict__ b_e1, const float* __restrict__ W_e2,
                       const float* __restrict__ b_e2, const float* __restrict__ Mm,
                       float* __restrict__ xout)
{
    int bid = blockIdx.x; int n = bid & (NN-1), b = bid >> 10;
    __shared__ float hs[1024];
    int t = threadIdx.x;  // 0..63, handles j = t and t+64
    const float4* src = (const float4*)(hfin + (size_t)n*8192 + b*1024);
    for (int i = t; i < 256; i += 64) ((float4*)hs)[i] = src[i];
    __syncthreads();

    float wc0[32], wc1[32];
#pragma unroll
    for (int hh = 0; hh < 32; hh++) { wc0[hh] = wcombo[hh*128 + t]; wc1[hh] = wcombo[hh*128 + 64 + t]; }
    float br0 = b_rnn[t], br1 = b_rnn[64+t];
    float xr0[32], xr1[32];
#pragma unroll
    for (int c = 0; c < 32; c++) {
        float hv[32];
#pragma unroll
        for (int q = 0; q < 8; q++) *(float4*)&hv[q*4] = *(const float4*)&hs[c*32 + q*4];
        float a0 = br0, a1 = br1;
#pragma unroll
        for (int hh = 0; hh < 32; hh++) { a0 += hv[hh]*wc0[hh]; a1 += hv[hh]*wc1[hh]; }
        xr0[c] = tanhf(a0); xr1[c] = tanhf(a1);
    }
    float v0[12], v1[12];
#pragma unroll
    for (int o2 = 0; o2 < 12; o2++) { v0[o2] = b_e2[o2]; v1[o2] = b_e2[o2]; }
    for (int o1 = 0; o1 < 128; o1++) {
        float u0 = b_e1[o1], u1 = b_e1[o1];
        const float4* w4 = (const float4*)(W_e1 + o1*32);
#pragma unroll
        for (int q = 0; q < 8; q++) {
            float4 w = w4[q];
            u0 += w.x*xr0[q*4+0] + w.y*xr0[q*4+1] + w.z*xr0[q*4+2] + w.w*xr0[q*4+3];
            u1 += w.x*xr1[q*4+0] + w.y*xr1[q*4+1] + w.z*xr1[q*4+2] + w.w*xr1[q*4+3];
        }
        u0 = fmaxf(u0, 0.f); u1 = fmaxf(u1, 0.f);
#pragma unroll
        for (int o2 = 0; o2 < 12; o2++) {
            float w = W_e2[o2*128 + o1];
            v0[o2] += w*u0; v1[o2] += w*u1;
        }
    }
    float mm0 = Mm[n*128 + t], mm1 = Mm[n*128 + 64 + t];
#pragma unroll
    for (int o2 = 0; o2 < 12; o2++) {
        size_t base = ((size_t)(b*12+o2)*NN + n)*128;
        xout[base + t]      = v0[o2]*mm0;
        xout[base + 64 + t] = v1[o2]*mm1;
    }
}

// ---------------- K10: head GEMM (relu(fh) @ W_f1, +b, relu, @W_f2 -> fc partials) ----------------
__global__ __launch_bounds__(256) void k10_head(
    const float* __restrict__ xout, const float* __restrict__ hist, const float* __restrict__ h0,
    const float* __restrict__ hd, const float* __restrict__ T_emb, const float* __restrict__ D_emb,
    const float* __restrict__ W_f1, const float* __restrict__ b_f1, const float* __restrict__ W_f2,
    float* __restrict__ fc)
{
    __shared__ float As[16][132];
    __shared__ float Bs[16][128];
    __shared__ float fcp[128*3];
    const int tid = threadIdx.x;
    const int tc = tid & 15, tr = tid >> 4;
    const int pos0 = blockIdx.y*128, col0 = blockIdx.x*128;
    float acc[8][8];
#pragma unroll
    for (int i = 0; i < 8; i++)
#pragma unroll
        for (int j = 0; j < 8; j++) acc[i][j] = 0.f;
    for (int i = tid; i < 128*3; i += 256) fcp[i] = 0.f;

    const int bcq = (tid & 31)*4;
    const int bkk = tid >> 5;

    for (int k0 = 0; k0 < 288; k0 += 16) {
        __syncthreads();
        // gather rf tile (relu'd fh): 128 rows x 16 k
#pragma unroll
        for (int pass = 0; pass < 8; pass++) {
            int idx = pass*256 + tid;
            int kk = idx & 15, r = idx >> 4;
            int k = k0 + kk;
            int pos = pos0 + r;
            float v = 0.f;
            if (k < 128)       v = xout[(size_t)pos*128 + k];
            else if (k < 160)  v = hist[(size_t)pos*32 + (k-128)];
            else if (k < 256)  v = h0[(size_t)pos*96 + (k-160)];
            else if (k < 266) { int ti = (int)(hd[(size_t)pos*5+3]*288.0f); v = T_emb[ti*10 + (k-256)]; }
            else if (k < 276) { int di = (int)hd[(size_t)pos*5+4];          v = D_emb[di*10 + (k-266)]; }
            As[kk][r] = fmaxf(v, 0.f);
        }
        {
            int kg0 = k0 + bkk, kg1 = k0 + 8 + bkk;
            float4 z = make_float4(0.f, 0.f, 0.f, 0.f);
            *(float4*)&Bs[bkk][bcq]   = (kg0 < 276) ? *(const float4*)&W_f1[(size_t)kg0*512 + col0 + bcq] : z;
            *(float4*)&Bs[8+bkk][bcq] = (kg1 < 276) ? *(const float4*)&W_f1[(size_t)kg1*512 + col0 + bcq] : z;
        }
        __syncthreads();
#pragma unroll
        for (int kk = 0; kk < 16; kk++) {
            float av[8], bv[8];
            *(float4*)&av[0] = *(const float4*)&As[kk][tr*8];
            *(float4*)&av[4] = *(const float4*)&As[kk][tr*8+4];
            *(float4*)&bv[0] = *(const float4*)&Bs[kk][tc*8];
            *(float4*)&bv[4] = *(const float4*)&Bs[kk][tc*8+4];
#pragma unroll
            for (int i = 0; i < 8; i++)
#pragma unroll
                for (int j = 0; j < 8; j++) acc[i][j] += av[i]*bv[j];
        }
    }
    float bf[8];
#pragma unroll
    for (int j = 0; j < 8; j++) bf[j] = b_f1[col0 + tc*8 + j];
#pragma unroll
    for (int i = 0; i < 8; i++) {
        float p0 = 0.f, p1 = 0.f, p2 = 0.f;
#pragma unroll
        for (int j = 0; j < 8; j++) {
            float z = fmaxf(acc[i][j] + bf[j], 0.f);
            int c = col0 + tc*8 + j;
            p0 += z*W_f2[c*3+0]; p1 += z*W_f2[c*3+1]; p2 += z*W_f2[c*3+2];
        }
        int rr = tr*8 + i;
        atomicAdd(&fcp[rr*3+0], p0);
        atomicAdd(&fcp[rr*3+1], p1);
        atomicAdd(&fcp[rr*3+2], p2);
    }
    __syncthreads();
    for (int i = tid; i < 384; i += 256) {
        atomicAdd(&fc[(size_t)pos0*3 + i], fcp[i]);
    }
}

// ---------------- K11: e3 epilogue + transpose ----------------
__global__ void k11_e3(const float* __restrict__ fc, const float* __restrict__ b_f2,
                       const float* __restrict__ W_e3, const float* __restrict__ b_e3,
                       float* __restrict__ out)
{
    int idx = blockIdx.x*256 + threadIdx.x;   // (b*N+n)*12 + o*3 + k
    if (idx >= BB*NN*12) return;
    int ok = idx % 12;
    int o = ok / 3, k = ok % 3;
    int bn = idx / 12;
    int n = bn & 1023, b = bn >> 10;
    float s = b_e3[o];
    float bk = b_f2[k];
#pragma unroll
    for (int c = 0; c < 12; c++)
        s += W_e3[o*12+c] * (fc[((size_t)(b*12+c)*NN + n)*3 + k] + bk);
    out[idx] = s;
}

extern "C" void kernel_launch(void* const* d_in, const int* in_sizes, int n_in,
                              void* d_out, int out_size, void* d_ws, size_t ws_size,
                              hipStream_t stream)
{
    const float* hd      = (const float*)d_in[0];
    const float* W_emb   = (const float*)d_in[1];
    const float* b_emb   = (const float*)d_in[2];
    const float* T_emb   = (const float*)d_in[3];
    const float* D_emb   = (const float*)d_in[4];
    const float* node_u  = (const float*)d_in[5];
    const float* node_d  = (const float*)d_in[6];
    const float* W_std   = (const float*)d_in[7];
    const float* b_std   = (const float*)d_in[8];
    const float* W_mlp   = (const float*)d_in[9];
    const float* b_mlp   = (const float*)d_in[10];
    const float* W_start = (const float*)d_in[11];
    const float* b_start = (const float*)d_in[12];
    const float* W_g     = (const float*)d_in[13];
    const float* W_rnn   = (const float*)d_in[14];
    const float* b_rnn   = (const float*)d_in[15];
    const float* W_e1    = (const float*)d_in[16];
    const float* b_e1    = (const float*)d_in[17];
    const float* W_e2    = (const float*)d_in[18];
    const float* b_e2    = (const float*)d_in[19];
    const float* Mm      = (const float*)d_in[20];
    const float* W_f1    = (const float*)d_in[21];
    const float* b_f1    = (const float*)d_in[22];
    const float* W_f2    = (const float*)d_in[23];
    const float* b_f2    = (const float*)d_in[24];
    const float* W_e3    = (const float*)d_in[25];
    const float* b_e3    = (const float*)d_in[26];

    float* ws      = (float*)d_ws;
    float* hist    = ws + OFF_HIST;
    float* h0      = ws + OFF_H0;
    float* s4      = ws + OFF_S4;
    float* ratio   = ws + OFF_RATIO;
    float* cent    = ws + OFF_CENT;
    float* m1      = ws + OFF_M1;
    float* m2      = ws + OFF_M2;
    int*   label   = (int*)(ws + OFF_LABEL);
    float* An      = ws + OFF_AN;
    float* Acomb   = ws + OFF_ACOMB;
    float* x0      = ws + OFF_X0;
    float* hfin    = ws + OFF_HFIN;
    float* wcombo  = ws + OFF_WCOMBO;
    float* xoutb   = ws + OFF_XOUT;
    float* fc      = ws + OFF_FC;

    k1_embed<<<(BB*LL*NN)/256, 256, 0, stream>>>(hd, W_emb, b_emb, T_emb, D_emb, node_u,
                                                 W_std, b_std, W_mlp, b_mlp, hist, h0, s4);
    k2_ratio<<<(BB*NN)/256, 256, 0, stream>>>(s4, ratio);
    k3_centers<<<BB, 256, 0, stream>>>(ratio, cent);
    k4_labels<<<NN/256, 256, 0, stream>>>(ratio, cent, node_u, node_d, label, m1, m2);
    k5_A<<<NN, 256, 0, stream>>>(m1, m2, label, An);
    gemm128<0><<<dim3(8, 8), 256, 0, stream>>>(An, An, Acomb, 1024, 1024, 1024);
    k7_x0<<<BB*NN, 256, 0, stream>>>(hist, W_start, b_start, x0);
    gemm128<1><<<dim3(64, 8), 256, 0, stream>>>(Acomb, x0, hfin, 1024, 8192, 1024);
    kw_combo<<<1, 128, 0, stream>>>(W_g, W_rnn, wcombo);
    k9_rnn<<<BB*NN, 64, 0, stream>>>(hfin, wcombo, b_rnn, W_e1, b_e1, W_e2, b_e2, Mm, xoutb);
    hipMemsetAsync(fc, 0, (size_t)BB*LL*NN*3*sizeof(float), stream);
    k10_head<<<dim3(4, 768), 256, 0, stream>>>(xoutb, hist, h0, hd, T_emb, D_emb, W_f1, b_f1, W_f2, fc);
    k11_e3<<<(BB*NN*12)/256, 256, 0, stream>>>(fc, b_f2, W_e3, b_e3, (float*)d_out);
}

// Round 2
// 1310.669 us; speedup vs baseline: 1.6447x; 1.6447x over previous
//
#include <hip/hip_runtime.h>
#include <math.h>

#define BB 8
#define LL 12
#define NN 1024
#define FF 3
#define HH 32
#define NDD 10
#define TTT 10
#define PP 3
#define DOUTT 128
constexpr float kALPHA = 3.0f;

// ---------------- workspace layout (floats) ----------------
constexpr size_t OFF_HIST   = 0;                                         // B*L*N*32
constexpr size_t OFF_H0     = OFF_HIST  + (size_t)BB*LL*NN*HH;           // B*L*N*96 (xs0|xs1|resid)
constexpr size_t OFF_S4     = OFF_H0    + (size_t)BB*LL*NN*3*HH;         // B*L*N*4
constexpr size_t OFF_RATIO  = OFF_S4    + (size_t)BB*LL*NN*4;            // B*N*3
constexpr size_t OFF_CENT   = OFF_RATIO + (size_t)BB*NN*3;               // 32
constexpr size_t OFF_M1     = OFF_CENT  + 32;                            // N*10
constexpr size_t OFF_M2     = OFF_M1    + (size_t)NN*NDD;                // N*10
constexpr size_t OFF_LABEL  = OFF_M2    + (size_t)NN*NDD;                // N ints
constexpr size_t OFF_AN     = OFF_LABEL + NN;                            // N*N
constexpr size_t OFF_ACOMB  = OFF_AN    + (size_t)NN*NN;                 // N*N
constexpr size_t OFF_X0     = OFF_ACOMB + (size_t)NN*NN;                 // N * 8192
constexpr size_t OFF_HFIN   = OFF_X0    + (size_t)NN*BB*HH*HH;           // N * 8192
constexpr size_t OFF_WCOMBO = OFF_HFIN  + (size_t)NN*BB*HH*HH;           // 32*128
constexpr size_t OFF_XOUT   = OFF_WCOMBO+ (size_t)HH*DOUTT;              // B*12*N*128
constexpr size_t OFF_FC     = OFF_XOUT  + (size_t)BB*LL*NN*DOUTT;        // B*12*N*3
constexpr size_t WS_FLOATS  = OFF_FC    + (size_t)BB*LL*NN*3;            // ~179 MB

// ---------------- K1: embed + std decomposition ----------------
__global__ __launch_bounds__(256) void k1_embed(
    const float* __restrict__ hd, const float* __restrict__ W_emb, const float* __restrict__ b_emb,
    const float* __restrict__ T_emb, const float* __restrict__ D_emb, const float* __restrict__ node_u,
    const float* __restrict__ W_std, const float* __restrict__ b_std,
    const float* __restrict__ W_mlp, const float* __restrict__ b_mlp,
    float* __restrict__ hist, float* __restrict__ h0, float* __restrict__ s4)
{
    __shared__ float sW[2*62*32];
    for (int i = threadIdx.x; i < 2*62*32; i += 256) sW[i] = W_std[i];
    __syncthreads();

    int pos = blockIdx.x*256 + threadIdx.x;           // 0..98303
    int n = pos & (NN-1);
    const float* hp = hd + (size_t)pos*5;
    float f0 = hp[0], f1 = hp[1], f2 = hp[2];
    int ti = (int)(hp[3]*288.0f);
    int di = (int)hp[4];

    float tv[10], dv[10], nu[10];
#pragma unroll
    for (int t = 0; t < 10; t++) {
        tv[t] = T_emb[ti*10+t]; dv[t] = D_emb[di*10+t]; nu[t] = node_u[n*10+t];
    }
    float h[32];
#pragma unroll
    for (int j = 0; j < 32; j++) h[j] = b_emb[j] + f0*W_emb[j] + f1*W_emb[32+j] + f2*W_emb[64+j];

    float a0[32], a1[32];
#pragma unroll
    for (int j = 0; j < 32; j++) { a0[j] = b_std[j]; a1[j] = b_std[32+j]; }

    auto accum = [&](float v, int i) {
#pragma unroll
        for (int q = 0; q < 8; q++) {
            float4 w0 = *(const float4*)&sW[i*32 + q*4];
            float4 w1 = *(const float4*)&sW[(62+i)*32 + q*4];
            a0[q*4+0] += v*w0.x; a0[q*4+1] += v*w0.y; a0[q*4+2] += v*w0.z; a0[q*4+3] += v*w0.w;
            a1[q*4+0] += v*w1.x; a1[q*4+1] += v*w1.y; a1[q*4+2] += v*w1.z; a1[q*4+3] += v*w1.w;
        }
    };
#pragma unroll
    for (int i = 0; i < 32; i++) accum(h[i], i);
#pragma unroll
    for (int i = 0; i < 10; i++) accum(nu[i], 32+i);
#pragma unroll
    for (int i = 0; i < 10; i++) accum(tv[i], 42+i);
#pragma unroll
    for (int i = 0; i < 10; i++) accum(dv[i], 52+i);

    float x0v[32], x1v[32], rv[32];
    float s0 = b_mlp[0], s1 = b_mlp[1], s2 = b_mlp[2], s3 = b_mlp[3];
#pragma unroll
    for (int j = 0; j < 32; j++) {
        float sg0 = 1.f/(1.f + __expf(-a0[j]));
        float sg1 = 1.f/(1.f + __expf(-a1[j]));
        x0v[j] = sg0*h[j]; x1v[j] = sg1*h[j]; rv[j] = h[j] - x0v[j] - x1v[j];
        s0 += h[j]  * W_mlp[j];
        s1 += x0v[j]* W_mlp[32+j];
        s2 += x1v[j]* W_mlp[64+j];
        s3 += rv[j] * W_mlp[96+j];
    }
    float* ho = hist + (size_t)pos*32;
    float* hz = h0   + (size_t)pos*96;
#pragma unroll
    for (int q = 0; q < 8; q++) {
        *(float4*)&ho[q*4]    = make_float4(h[q*4],   h[q*4+1],   h[q*4+2],   h[q*4+3]);
        *(float4*)&hz[q*4]    = make_float4(x0v[q*4], x0v[q*4+1], x0v[q*4+2], x0v[q*4+3]);
        *(float4*)&hz[32+q*4] = make_float4(x1v[q*4], x1v[q*4+1], x1v[q*4+2], x1v[q*4+3]);
        *(float4*)&hz[64+q*4] = make_float4(rv[q*4],  rv[q*4+1],  rv[q*4+2],  rv[q*4+3]);
    }
    *(float4*)&s4[(size_t)pos*4] = make_float4(s0, s1, s2, s3);
}

// ---------------- K2: ratios ----------------
__global__ void k2_ratio(const float* __restrict__ s4, float* __restrict__ ratio)
{
    int bn = blockIdx.x*256 + threadIdx.x;
    if (bn >= BB*NN) return;
    int b = bn >> 10, n = bn & 1023;
    float a0=0, a1=0, a2=0, a3=0;
    for (int l = 0; l < 12; l++) {
        const float* sp = s4 + ((size_t)(b*12+l)*NN + n)*4;
        a0 += sp[0]; a1 += sp[1]; a2 += sp[2]; a3 += sp[3];
    }
    float hm = a0/12.f;
    float* rp = ratio + (size_t)bn*3;
    rp[0] = (a1/12.f)/(hm + 1e-6f);
    rp[1] = (a2/12.f)/(hm + 1e-6f);
    rp[2] = (a3/12.f)/(hm + 1e-6f);
}

// ---------------- K3: per-b centers (max over n) ----------------
__global__ __launch_bounds__(256) void k3_centers(const float* __restrict__ ratio, float* __restrict__ centers)
{
    int b = blockIdx.x;
    float m0=-3.4e38f, m1v=-3.4e38f, m2v=-3.4e38f;
    for (int n = threadIdx.x; n < NN; n += 256) {
        const float* rp = ratio + ((size_t)b*NN + n)*3;
        m0 = fmaxf(m0, rp[0]); m1v = fmaxf(m1v, rp[1]); m2v = fmaxf(m2v, rp[2]);
    }
#pragma unroll
    for (int off = 32; off > 0; off >>= 1) {
        m0  = fmaxf(m0,  __shfl_down(m0,  off));
        m1v = fmaxf(m1v, __shfl_down(m1v, off));
        m2v = fmaxf(m2v, __shfl_down(m2v, off));
    }
    __shared__ float red[4][3];
    int wid = threadIdx.x >> 6, lane = threadIdx.x & 63;
    if (lane == 0) { red[wid][0]=m0; red[wid][1]=m1v; red[wid][2]=m2v; }
    __syncthreads();
    if (threadIdx.x == 0) {
        centers[b*3+0] = fmaxf(fmaxf(red[0][0],red[1][0]), fmaxf(red[2][0],red[3][0]));
        centers[b*3+1] = fmaxf(fmaxf(red[0][1],red[1][1]), fmaxf(red[2][1],red[3][1]));
        centers[b*3+2] = fmaxf(fmaxf(red[0][2],red[1][2]), fmaxf(red[2][2],red[3][2]));
    }
}

// ---------------- K4: labels + m1/m2 = tanh(3*node) ----------------
__global__ void k4_labels(const float* __restrict__ ratio, const float* __restrict__ centers,
                          const float* __restrict__ node_u, const float* __restrict__ node_d,
                          int* __restrict__ label, float* __restrict__ m1, float* __restrict__ m2)
{
    int n = blockIdx.x*256 + threadIdx.x;
    if (n >= NN) return;
    int c0=0, c1=0, c2=0;
    for (int b = 0; b < BB; b++) {
        const float* rp = ratio + ((size_t)b*NN + n)*3;
        const float* cp = centers + b*3;
        float d0 = fabsf(rp[0]-cp[0]), d1 = fabsf(rp[1]-cp[1]), d2 = fabsf(rp[2]-cp[2]);
        int a = 0; float best = d0;
        if (d1 < best) { best = d1; a = 1; }
        if (d2 < best) { best = d2; a = 2; }
        if (a == 0) c0++; else if (a == 1) c1++; else c2++;
    }
    int lab = 0, bc = c0;
    if (c1 > bc) { bc = c1; lab = 1; }
    if (c2 > bc) { bc = c2; lab = 2; }
    label[n] = lab;
#pragma unroll
    for (int d = 0; d < 10; d++) {
        m1[n*10+d] = tanhf(kALPHA*node_u[n*10+d]);
        m2[n*10+d] = tanhf(kALPHA*node_d[n*10+d]);
    }
}

// ---------------- K5: An = normalized label-masked adjacency ----------------
__global__ __launch_bounds__(256) void k5_A(const float* __restrict__ m1, const float* __restrict__ m2,
                                            const int* __restrict__ label, float* __restrict__ An)
{
    int n = blockIdx.x;
    __shared__ float row[1024];
    __shared__ float m1n[10], m2n[10];
    __shared__ float ssum[4];
    int t = threadIdx.x;
    if (t < 10) { m1n[t] = m1[n*10+t]; m2n[t] = m2[n*10+t]; }
    __syncthreads();
    int labn = label[n];
    float lsum = 0.f;
    for (int m = t; m < 1024; m += 256) {
        float a = 0.f;
        if (label[m] == labn) {
            float x = 0.f;
#pragma unroll
            for (int d = 0; d < 10; d++) x += m1n[d]*m2[m*10+d] - m2n[d]*m1[m*10+d];
            a = fmaxf(tanhf(3.f*x), 0.f);
        }
        row[m] = a; lsum += a;
    }
#pragma unroll
    for (int off = 32; off > 0; off >>= 1) lsum += __shfl_down(lsum, off);
    int wid = t >> 6, lane = t & 63;
    if (lane == 0) ssum[wid] = lsum;
    __syncthreads();
    float inv = 1.f/((ssum[0]+ssum[1]+ssum[2]+ssum[3]) + 1e-6f);
    for (int m = t; m < 1024; m += 256) An[(size_t)n*1024 + m] = row[m]*inv;
}

// ---------------- generic fp32 GEMM, 128x128 tile, 8x8 micro ----------------
// MODE 0: C = 0.9025*(A@B) + 0.0475*A + 0.05*I   (Acomb; A square, K==Ncol)
// MODE 1: C = A@B                                (propagation)
template<int MODE>
__global__ __launch_bounds__(256) void gemm128(const float* __restrict__ A, const float* __restrict__ Bm,
                                               float* __restrict__ C, int Mrows, int Ncol, int K)
{
    __shared__ float As[16][132];
    __shared__ float Bs[16][128];
    const int tid = threadIdx.x;
    const int tc = tid & 15, tr = tid >> 4;
    const int row0 = blockIdx.y*128, col0 = blockIdx.x*128;
    float acc[8][8];
#pragma unroll
    for (int i = 0; i < 8; i++)
#pragma unroll
        for (int j = 0; j < 8; j++) acc[i][j] = 0.f;

    const int ar = tid >> 2;          // 0..63
    const int ak = (tid & 3)*4;       // 0,4,8,12
    const int bc = (tid & 31)*4;      // col quad
    const int bk = tid >> 5;          // 0..7

    for (int k0 = 0; k0 < K; k0 += 16) {
        float4 a0 = *(const float4*)&A[(size_t)(row0+ar)*K + k0 + ak];
        float4 a1 = *(const float4*)&A[(size_t)(row0+64+ar)*K + k0 + ak];
        float4 b0 = *(const float4*)&Bm[(size_t)(k0+bk)*Ncol + col0 + bc];
        float4 b1 = *(const float4*)&Bm[(size_t)(k0+8+bk)*Ncol + col0 + bc];
        __syncthreads();
        As[ak+0][ar] = a0.x; As[ak+1][ar] = a0.y; As[ak+2][ar] = a0.z; As[ak+3][ar] = a0.w;
        As[ak+0][64+ar] = a1.x; As[ak+1][64+ar] = a1.y; As[ak+2][64+ar] = a1.z; As[ak+3][64+ar] = a1.w;
        *(float4*)&Bs[bk][bc]   = b0;
        *(float4*)&Bs[8+bk][bc] = b1;
        __syncthreads();
#pragma unroll
        for (int kk = 0; kk < 16; kk++) {
            float av[8], bv[8];
            *(float4*)&av[0] = *(const float4*)&As[kk][tr*8];
            *(float4*)&av[4] = *(const float4*)&As[kk][tr*8+4];
            *(float4*)&bv[0] = *(const float4*)&Bs[kk][tc*8];
            *(float4*)&bv[4] = *(const float4*)&Bs[kk][tc*8+4];
#pragma unroll
            for (int i = 0; i < 8; i++)
#pragma unroll
                for (int j = 0; j < 8; j++) acc[i][j] += av[i]*bv[j];
        }
    }
#pragma unroll
    for (int i = 0; i < 8; i++) {
        int r = row0 + tr*8 + i;
#pragma unroll
        for (int q = 0; q < 2; q++) {
            int c = col0 + tc*8 + q*4;
            float4 o;
            o.x = acc[i][q*4+0]; o.y = acc[i][q*4+1]; o.z = acc[i][q*4+2]; o.w = acc[i][q*4+3];
            if (MODE == 0) {
                o.x = 0.9025f*o.x + 0.0475f*A[(size_t)r*K + c+0] + ((r==c+0)?0.05f:0.f);
                o.y = 0.9025f*o.y + 0.0475f*A[(size_t)r*K + c+1] + ((r==c+1)?0.05f:0.f);
                o.z = 0.9025f*o.z + 0.0475f*A[(size_t)r*K + c+2] + ((r==c+2)?0.05f:0.f);
                o.w = 0.9025f*o.w + 0.0475f*A[(size_t)r*K + c+3] + ((r==c+3)?0.05f:0.f);
            }
            *(float4*)&C[(size_t)r*Ncol + c] = o;
        }
    }
}

// ---------------- K7: x0[n, b*1024 + c*32 + h] ----------------
__global__ __launch_bounds__(256) void k7_x0(const float* __restrict__ hist,
                                             const float* __restrict__ W_start, const float* __restrict__ b_start,
                                             float* __restrict__ x0)
{
    int bid = blockIdx.x; int n = bid & (NN-1), b = bid >> 10;
    __shared__ float hl[384];  // [l*32+h]
    __shared__ float sw[384];  // [c*12+l]
    int t = threadIdx.x;
    for (int idx = t; idx < 384; idx += 256) {
        int l = idx >> 5, hh = idx & 31;
        hl[idx] = hist[((size_t)(b*12+l)*NN + n)*32 + hh];
    }
    for (int idx = t; idx < 384; idx += 256) sw[idx] = W_start[idx];
    __syncthreads();
    int c = t >> 3, h4 = (t & 7)*4;
    float bs = b_start[c];
    float o0 = bs, o1 = bs, o2 = bs, o3 = bs;
#pragma unroll
    for (int l = 0; l < 12; l++) {
        float w = sw[c*12+l];
        o0 += w*hl[l*32+h4];   o1 += w*hl[l*32+h4+1];
        o2 += w*hl[l*32+h4+2]; o3 += w*hl[l*32+h4+3];
    }
    *(float4*)&x0[(size_t)n*8192 + b*1024 + c*32 + h4] = make_float4(o0, o1, o2, o3);
}

// ---------------- Kw: Wcombo = (Wg0+Wg1) @ W_rnn  (32x128) ----------------
__global__ void kw_combo(const float* __restrict__ W_g, const float* __restrict__ W_rnn, float* __restrict__ wcombo)
{
    int j = threadIdx.x; // 128
    for (int hh = 0; hh < 32; hh++) {
        float s = 0.f;
        for (int k = 0; k < 32; k++) s += (W_g[hh*32+k] + W_g[1024 + hh*32+k]) * W_rnn[k*128 + j];
        wcombo[hh*128 + j] = s;
    }
}

// ---------------- K9 v2: per (b,n): xr=tanh(h2@Wcombo+b_rnn); e1 relu; e2; *M ----------------
// 256 threads/block. LDS-staged weights, register-blocked inner loops.
__global__ __launch_bounds__(256) void k9_rnn2(
    const float* __restrict__ hfin, const float* __restrict__ wcombo,
    const float* __restrict__ b_rnn, const float* __restrict__ W_e1,
    const float* __restrict__ b_e1, const float* __restrict__ W_e2,
    const float* __restrict__ b_e2, const float* __restrict__ Mm,
    float* __restrict__ xout)
{
    __shared__ float sXr[32*128];          // 16 KB [c][j]
    __shared__ float sH[1024];             // 4 KB  [c][h]
    __shared__ float sWbuf[4096 + 2048];   // 24 KB: phase A = Wcombo[h][j]; phase B = We1[o1][c] | We2t[o1][16]
    __shared__ float sV[12*128];           // 6 KB  [o2][j]
    __shared__ float sBe1[128];

    const int bid = blockIdx.x;
    const int n = bid & (NN-1), b = bid >> 10;
    const int t = threadIdx.x;
    const int j2 = t & 63;                 // j0 = j2, j1 = j2+64
    const int og = t >> 6;                 // 0..3
    const int j0 = j2, j1 = j2 + 64;

    // stage phase-A weights + hfin block + zero sV
    for (int i = t; i < 4096; i += 256) sWbuf[i] = wcombo[i];
    for (int i = t; i < 1024; i += 256) sH[i] = hfin[(size_t)n*8192 + (size_t)b*1024 + i];
    for (int i = t; i < 1536; i += 256) sV[i] = 0.f;
    if (t < 128) sBe1[t] = b_e1[t];
    __syncthreads();

    // ---- phase A: xr[c][j] = tanh(sum_h H[c][h]*Wc[h][j] + b_rnn[j]) ----
    float wc0[32], wc1[32];
#pragma unroll
    for (int h = 0; h < 32; h++) { wc0[h] = sWbuf[h*128 + j0]; wc1[h] = sWbuf[h*128 + j1]; }
    float br0 = b_rnn[j0], br1 = b_rnn[j1];
#pragma unroll
    for (int ci = 0; ci < 8; ci++) {
        int c = og*8 + ci;
        float u0 = br0, u1 = br1;
#pragma unroll
        for (int q = 0; q < 8; q++) {
            float4 hv = *(const float4*)&sH[c*32 + q*4];
            u0 += hv.x*wc0[q*4+0] + hv.y*wc0[q*4+1] + hv.z*wc0[q*4+2] + hv.w*wc0[q*4+3];
            u1 += hv.x*wc1[q*4+0] + hv.y*wc1[q*4+1] + hv.z*wc1[q*4+2] + hv.w*wc1[q*4+3];
        }
        sXr[c*128 + j0] = tanhf(u0);
        sXr[c*128 + j1] = tanhf(u1);
    }
    __syncthreads();

    // restage phase-B weights
    for (int i = t; i < 4096; i += 256) sWbuf[i] = W_e1[i];                    // [o1][c]
    for (int i = t; i < 2048; i += 256) {
        int o1 = i >> 4, o2 = i & 15;
        sWbuf[4096 + i] = (o2 < 12) ? W_e2[o2*128 + o1] : 0.f;                 // [o1][o2 pad16]
    }
    __syncthreads();

    // ---- phase B: y[o1][j] = relu(We1[o1]·xr[:,j] + be1); v[o2][j] += We2[o2][o1]*y ----
    float xr0[32], xr1[32];
#pragma unroll
    for (int c = 0; c < 32; c++) { xr0[c] = sXr[c*128 + j0]; xr1[c] = sXr[c*128 + j1]; }
    float v0[12], v1[12];
#pragma unroll
    for (int o2 = 0; o2 < 12; o2++) { v0[o2] = 0.f; v1[o2] = 0.f; }

#pragma unroll 4
    for (int oi = 0; oi < 32; oi++) {
        int o1 = og*32 + oi;
        float u0 = sBe1[o1], u1 = sBe1[o1];
#pragma unroll
        for (int q = 0; q < 8; q++) {
            float4 w = *(const float4*)&sWbuf[o1*32 + q*4];
            u0 += w.x*xr0[q*4+0] + w.y*xr0[q*4+1] + w.z*xr0[q*4+2] + w.w*xr0[q*4+3];
            u1 += w.x*xr1[q*4+0] + w.y*xr1[q*4+1] + w.z*xr1[q*4+2] + w.w*xr1[q*4+3];
        }
        u0 = fmaxf(u0, 0.f); u1 = fmaxf(u1, 0.f);
#pragma unroll
        for (int q = 0; q < 3; q++) {
            float4 w2 = *(const float4*)&sWbuf[4096 + o1*16 + q*4];
            v0[q*4+0] += w2.x*u0; v0[q*4+1] += w2.y*u0; v0[q*4+2] += w2.z*u0; v0[q*4+3] += w2.w*u0;
            v1[q*4+0] += w2.x*u1; v1[q*4+1] += w2.y*u1; v1[q*4+2] += w2.z*u1; v1[q*4+3] += w2.w*u1;
        }
    }

    // reduce the 4 og-groups into sV (serialized, deterministic)
#pragma unroll
    for (int g = 0; g < 4; g++) {
        if (og == g) {
#pragma unroll
            for (int o2 = 0; o2 < 12; o2++) {
                sV[o2*128 + j0] += v0[o2];
                sV[o2*128 + j1] += v1[o2];
            }
        }
        __syncthreads();
    }

    // epilogue: add b_e2, apply M, write
    for (int i = t; i < 1536; i += 256) {
        int o2 = i >> 7, j = i & 127;
        float val = (sV[i] + b_e2[o2]) * Mm[n*128 + j];
        xout[((size_t)(b*12 + o2)*NN + n)*128 + j] = val;
    }
}

// ---------------- K10: head GEMM (relu(fh) @ W_f1, +b, relu, @W_f2 -> fc partials) ----------------
__global__ __launch_bounds__(256) void k10_head(
    const float* __restrict__ xout, const float* __restrict__ hist, const float* __restrict__ h0,
    const float* __restrict__ hd, const float* __restrict__ T_emb, const float* __restrict__ D_emb,
    const float* __restrict__ W_f1, const float* __restrict__ b_f1, const float* __restrict__ W_f2,
    float* __restrict__ fc)
{
    __shared__ float As[16][132];
    __shared__ float Bs[16][128];
    __shared__ float fcp[128*3];
    const int tid = threadIdx.x;
    const int tc = tid & 15, tr = tid >> 4;
    const int pos0 = blockIdx.y*128, col0 = blockIdx.x*128;
    float acc[8][8];
#pragma unroll
    for (int i = 0; i < 8; i++)
#pragma unroll
        for (int j = 0; j < 8; j++) acc[i][j] = 0.f;
    for (int i = tid; i < 128*3; i += 256) fcp[i] = 0.f;

    const int bcq = (tid & 31)*4;
    const int bkk = tid >> 5;

    for (int k0 = 0; k0 < 288; k0 += 16) {
        __syncthreads();
#pragma unroll
        for (int pass = 0; pass < 8; pass++) {
            int idx = pass*256 + tid;
            int kk = idx & 15, r = idx >> 4;
            int k = k0 + kk;
            int pos = pos0 + r;
            float v = 0.f;
            if (k < 128)       v = xout[(size_t)pos*128 + k];
            else if (k < 160)  v = hist[(size_t)pos*32 + (k-128)];
            else if (k < 256)  v = h0[(size_t)pos*96 + (k-160)];
            else if (k < 266) { int ti = (int)(hd[(size_t)pos*5+3]*288.0f); v = T_emb[ti*10 + (k-256)]; }
            else if (k < 276) { int di = (int)hd[(size_t)pos*5+4];          v = D_emb[di*10 + (k-266)]; }
            As[kk][r] = fmaxf(v, 0.f);
        }
        {
            int kg0 = k0 + bkk, kg1 = k0 + 8 + bkk;
            float4 z = make_float4(0.f, 0.f, 0.f, 0.f);
            *(float4*)&Bs[bkk][bcq]   = (kg0 < 276) ? *(const float4*)&W_f1[(size_t)kg0*512 + col0 + bcq] : z;
            *(float4*)&Bs[8+bkk][bcq] = (kg1 < 276) ? *(const float4*)&W_f1[(size_t)kg1*512 + col0 + bcq] : z;
        }
        __syncthreads();
#pragma unroll
        for (int kk = 0; kk < 16; kk++) {
            float av[8], bv[8];
            *(float4*)&av[0] = *(const float4*)&As[kk][tr*8];
            *(float4*)&av[4] = *(const float4*)&As[kk][tr*8+4];
            *(float4*)&bv[0] = *(const float4*)&Bs[kk][tc*8];
            *(float4*)&bv[4] = *(const float4*)&Bs[kk][tc*8+4];
#pragma unroll
            for (int i = 0; i < 8; i++)
#pragma unroll
                for (int j = 0; j < 8; j++) acc[i][j] += av[i]*bv[j];
        }
    }
    float bf[8];
#pragma unroll
    for (int j = 0; j < 8; j++) bf[j] = b_f1[col0 + tc*8 + j];
#pragma unroll
    for (int i = 0; i < 8; i++) {
        float p0 = 0.f, p1 = 0.f, p2 = 0.f;
#pragma unroll
        for (int j = 0; j < 8; j++) {
            float z = fmaxf(acc[i][j] + bf[j], 0.f);
            int c = col0 + tc*8 + j;
            p0 += z*W_f2[c*3+0]; p1 += z*W_f2[c*3+1]; p2 += z*W_f2[c*3+2];
        }
        int rr = tr*8 + i;
        atomicAdd(&fcp[rr*3+0], p0);
        atomicAdd(&fcp[rr*3+1], p1);
        atomicAdd(&fcp[rr*3+2], p2);
    }
    __syncthreads();
    for (int i = tid; i < 384; i += 256) {
        atomicAdd(&fc[(size_t)pos0*3 + i], fcp[i]);
    }
}

// ---------------- K11: e3 epilogue + transpose ----------------
__global__ void k11_e3(const float* __restrict__ fc, const float* __restrict__ b_f2,
                       const float* __restrict__ W_e3, const float* __restrict__ b_e3,
                       float* __restrict__ out)
{
    int idx = blockIdx.x*256 + threadIdx.x;   // (b*N+n)*12 + o*3 + k
    if (idx >= BB*NN*12) return;
    int ok = idx % 12;
    int o = ok / 3, k = ok % 3;
    int bn = idx / 12;
    int n = bn & 1023, b = bn >> 10;
    float s = b_e3[o];
    float bk = b_f2[k];
#pragma unroll
    for (int c = 0; c < 12; c++)
        s += W_e3[o*12+c] * (fc[((size_t)(b*12+c)*NN + n)*3 + k] + bk);
    out[idx] = s;
}

extern "C" void kernel_launch(void* const* d_in, const int* in_sizes, int n_in,
                              void* d_out, int out_size, void* d_ws, size_t ws_size,
                              hipStream_t stream)
{
    const float* hd      = (const float*)d_in[0];
    const float* W_emb   = (const float*)d_in[1];
    const float* b_emb   = (const float*)d_in[2];
    const float* T_emb   = (const float*)d_in[3];
    const float* D_emb   = (const float*)d_in[4];
    const float* node_u  = (const float*)d_in[5];
    const float* node_d  = (const float*)d_in[6];
    const float* W_std   = (const float*)d_in[7];
    const float* b_std   = (const float*)d_in[8];
    const float* W_mlp   = (const float*)d_in[9];
    const float* b_mlp   = (const float*)d_in[10];
    const float* W_start = (const float*)d_in[11];
    const float* b_start = (const float*)d_in[12];
    const float* W_g     = (const float*)d_in[13];
    const float* W_rnn   = (const float*)d_in[14];
    const float* b_rnn   = (const float*)d_in[15];
    const float* W_e1    = (const float*)d_in[16];
    const float* b_e1    = (const float*)d_in[17];
    const float* W_e2    = (const float*)d_in[18];
    const float* b_e2    = (const float*)d_in[19];
    const float* Mm      = (const float*)d_in[20];
    const float* W_f1    = (const float*)d_in[21];
    const float* b_f1    = (const float*)d_in[22];
    const float* W_f2    = (const float*)d_in[23];
    const float* b_f2    = (const float*)d_in[24];
    const float* W_e3    = (const float*)d_in[25];
    const float* b_e3    = (const float*)d_in[26];

    float* ws      = (float*)d_ws;
    float* hist    = ws + OFF_HIST;
    float* h0      = ws + OFF_H0;
    float* s4      = ws + OFF_S4;
    float* ratio   = ws + OFF_RATIO;
    float* cent    = ws + OFF_CENT;
    float* m1      = ws + OFF_M1;
    float* m2      = ws + OFF_M2;
    int*   label   = (int*)(ws + OFF_LABEL);
    float* An      = ws + OFF_AN;
    float* Acomb   = ws + OFF_ACOMB;
    float* x0      = ws + OFF_X0;
    float* hfin    = ws + OFF_HFIN;
    float* wcombo  = ws + OFF_WCOMBO;
    float* xoutb   = ws + OFF_XOUT;
    float* fc      = ws + OFF_FC;

    k1_embed<<<(BB*LL*NN)/256, 256, 0, stream>>>(hd, W_emb, b_emb, T_emb, D_emb, node_u,
                                                 W_std, b_std, W_mlp, b_mlp, hist, h0, s4);
    k2_ratio<<<(BB*NN)/256, 256, 0, stream>>>(s4, ratio);
    k3_centers<<<BB, 256, 0, stream>>>(ratio, cent);
    k4_labels<<<NN/256, 256, 0, stream>>>(ratio, cent, node_u, node_d, label, m1, m2);
    k5_A<<<NN, 256, 0, stream>>>(m1, m2, label, An);
    gemm128<0><<<dim3(8, 8), 256, 0, stream>>>(An, An, Acomb, 1024, 1024, 1024);
    k7_x0<<<BB*NN, 256, 0, stream>>>(hist, W_start, b_start, x0);
    gemm128<1><<<dim3(64, 8), 256, 0, stream>>>(Acomb, x0, hfin, 1024, 8192, 1024);
    kw_combo<<<1, 128, 0, stream>>>(W_g, W_rnn, wcombo);
    k9_rnn2<<<BB*NN, 256, 0, stream>>>(hfin, wcombo, b_rnn, W_e1, b_e1, W_e2, b_e2, Mm, xoutb);
    hipMemsetAsync(fc, 0, (size_t)BB*LL*NN*3*sizeof(float), stream);
    k10_head<<<dim3(4, 768), 256, 0, stream>>>(xoutb, hist, h0, hd, T_emb, D_emb, W_f1, b_f1, W_f2, fc);
    k11_e3<<<(BB*NN*12)/256, 256, 0, stream>>>(fc, b_f2, W_e3, b_e3, (float*)d_out);
}

// Round 3
// 892.676 us; speedup vs baseline: 2.4148x; 1.4682x over previous
//
#include <hip/hip_runtime.h>
#include <math.h>

#define BB 8
#define LL 12
#define NN 1024
#define FF 3
#define HH 32
#define NDD 10
#define TTT 10
#define PP 3
#define DOUTT 128
constexpr float kALPHA = 3.0f;

typedef __attribute__((ext_vector_type(8))) short short8v;   // 8 bf16 (4 VGPR)
typedef __attribute__((ext_vector_type(4))) float float4v;

__device__ __forceinline__ unsigned short f2bf(float x) {
    union { float f; unsigned u; } v; v.f = x;
    unsigned r = v.u + 0x7FFF + ((v.u >> 16) & 1);
    return (unsigned short)(r >> 16);
}
__device__ __forceinline__ float bf2f(unsigned short u) {
    union { unsigned u; float f; } v; v.u = ((unsigned)u) << 16;
    return v.f;
}

// ---------------- workspace layout (floats) ----------------
constexpr size_t OFF_HIST   = 0;                                         // B*L*N*32
constexpr size_t OFF_H0     = OFF_HIST  + (size_t)BB*LL*NN*HH;           // B*L*N*96
constexpr size_t OFF_S4     = OFF_H0    + (size_t)BB*LL*NN*3*HH;         // B*L*N*4
constexpr size_t OFF_RATIO  = OFF_S4    + (size_t)BB*LL*NN*4;            // B*N*3
constexpr size_t OFF_CENT   = OFF_RATIO + (size_t)BB*NN*3;               // 32
constexpr size_t OFF_M1     = OFF_CENT  + 32;                            // N*10
constexpr size_t OFF_M2     = OFF_M1    + (size_t)NN*NDD;                // N*10
constexpr size_t OFF_LABEL  = OFF_M2    + (size_t)NN*NDD;                // N ints
constexpr size_t OFF_AN     = OFF_LABEL + NN;                            // N*N fp32
constexpr size_t OFF_ACOMBB = OFF_AN    + (size_t)NN*NN;                 // N*N bf16 (in 1M-float slot)
constexpr size_t OFF_X0     = OFF_ACOMBB+ (size_t)NN*NN;                 // N*8192 fp32 (later fhB overlay)
constexpr size_t OFF_HFIN   = OFF_X0    + (size_t)NN*BB*HH*HH;           // N*8192 fp32
constexpr size_t OFF_WCOMBO = OFF_HFIN  + (size_t)NN*BB*HH*HH;           // 32*128
constexpr size_t OFF_XOUT   = OFF_WCOMBO+ (size_t)HH*DOUTT;              // B*12*N*128
constexpr size_t OFF_FC     = OFF_XOUT  + (size_t)BB*LL*NN*DOUTT;        // B*12*N*3
constexpr size_t OFF_ANB    = OFF_FC    + (size_t)BB*LL*NN*3;            // 1024*1024 bf16
constexpr size_t OFF_ANBT   = OFF_ANB   + (size_t)NN*NN/2;               // 1024*1024 bf16
constexpr size_t OFF_X0T    = OFF_ANBT  + (size_t)NN*NN/2;               // 8192*1024 bf16
constexpr size_t OFF_W1HI   = OFF_X0T   + (size_t)BB*HH*HH*NN/2;         // 512*288 bf16
constexpr size_t OFF_W1LO   = OFF_W1HI  + (size_t)512*288/2;
constexpr size_t WS_FLOATS  = OFF_W1LO  + (size_t)512*288/2;             // ~201 MB

// ---------------- K1: embed + std decomposition ----------------
__global__ __launch_bounds__(256) void k1_embed(
    const float* __restrict__ hd, const float* __restrict__ W_emb, const float* __restrict__ b_emb,
    const float* __restrict__ T_emb, const float* __restrict__ D_emb, const float* __restrict__ node_u,
    const float* __restrict__ W_std, const float* __restrict__ b_std,
    const float* __restrict__ W_mlp, const float* __restrict__ b_mlp,
    float* __restrict__ hist, float* __restrict__ h0, float* __restrict__ s4)
{
    __shared__ float sW[2*62*32];
    for (int i = threadIdx.x; i < 2*62*32; i += 256) sW[i] = W_std[i];
    __syncthreads();

    int pos = blockIdx.x*256 + threadIdx.x;
    int n = pos & (NN-1);
    const float* hp = hd + (size_t)pos*5;
    float f0 = hp[0], f1 = hp[1], f2 = hp[2];
    int ti = (int)(hp[3]*288.0f);
    int di = (int)hp[4];

    float tv[10], dv[10], nu[10];
#pragma unroll
    for (int t = 0; t < 10; t++) {
        tv[t] = T_emb[ti*10+t]; dv[t] = D_emb[di*10+t]; nu[t] = node_u[n*10+t];
    }
    float h[32];
#pragma unroll
    for (int j = 0; j < 32; j++) h[j] = b_emb[j] + f0*W_emb[j] + f1*W_emb[32+j] + f2*W_emb[64+j];

    float a0[32], a1[32];
#pragma unroll
    for (int j = 0; j < 32; j++) { a0[j] = b_std[j]; a1[j] = b_std[32+j]; }

    auto accum = [&](float v, int i) {
#pragma unroll
        for (int q = 0; q < 8; q++) {
            float4 w0 = *(const float4*)&sW[i*32 + q*4];
            float4 w1 = *(const float4*)&sW[(62+i)*32 + q*4];
            a0[q*4+0] += v*w0.x; a0[q*4+1] += v*w0.y; a0[q*4+2] += v*w0.z; a0[q*4+3] += v*w0.w;
            a1[q*4+0] += v*w1.x; a1[q*4+1] += v*w1.y; a1[q*4+2] += v*w1.z; a1[q*4+3] += v*w1.w;
        }
    };
#pragma unroll
    for (int i = 0; i < 32; i++) accum(h[i], i);
#pragma unroll
    for (int i = 0; i < 10; i++) accum(nu[i], 32+i);
#pragma unroll
    for (int i = 0; i < 10; i++) accum(tv[i], 42+i);
#pragma unroll
    for (int i = 0; i < 10; i++) accum(dv[i], 52+i);

    float x0v[32], x1v[32], rv[32];
    float s0 = b_mlp[0], s1 = b_mlp[1], s2 = b_mlp[2], s3 = b_mlp[3];
#pragma unroll
    for (int j = 0; j < 32; j++) {
        float sg0 = 1.f/(1.f + __expf(-a0[j]));
        float sg1 = 1.f/(1.f + __expf(-a1[j]));
        x0v[j] = sg0*h[j]; x1v[j] = sg1*h[j]; rv[j] = h[j] - x0v[j] - x1v[j];
        s0 += h[j]  * W_mlp[j];
        s1 += x0v[j]* W_mlp[32+j];
        s2 += x1v[j]* W_mlp[64+j];
        s3 += rv[j] * W_mlp[96+j];
    }
    float* ho = hist + (size_t)pos*32;
    float* hz = h0   + (size_t)pos*96;
#pragma unroll
    for (int q = 0; q < 8; q++) {
        *(float4*)&ho[q*4]    = make_float4(h[q*4],   h[q*4+1],   h[q*4+2],   h[q*4+3]);
        *(float4*)&hz[q*4]    = make_float4(x0v[q*4], x0v[q*4+1], x0v[q*4+2], x0v[q*4+3]);
        *(float4*)&hz[32+q*4] = make_float4(x1v[q*4], x1v[q*4+1], x1v[q*4+2], x1v[q*4+3]);
        *(float4*)&hz[64+q*4] = make_float4(rv[q*4],  rv[q*4+1],  rv[q*4+2],  rv[q*4+3]);
    }
    *(float4*)&s4[(size_t)pos*4] = make_float4(s0, s1, s2, s3);
}

// ---------------- K2: ratios ----------------
__global__ void k2_ratio(const float* __restrict__ s4, float* __restrict__ ratio)
{
    int bn = blockIdx.x*256 + threadIdx.x;
    if (bn >= BB*NN) return;
    int b = bn >> 10, n = bn & 1023;
    float a0=0, a1=0, a2=0, a3=0;
    for (int l = 0; l < 12; l++) {
        const float* sp = s4 + ((size_t)(b*12+l)*NN + n)*4;
        a0 += sp[0]; a1 += sp[1]; a2 += sp[2]; a3 += sp[3];
    }
    float hm = a0/12.f;
    float* rp = ratio + (size_t)bn*3;
    rp[0] = (a1/12.f)/(hm + 1e-6f);
    rp[1] = (a2/12.f)/(hm + 1e-6f);
    rp[2] = (a3/12.f)/(hm + 1e-6f);
}

// ---------------- K3: per-b centers ----------------
__global__ __launch_bounds__(256) void k3_centers(const float* __restrict__ ratio, float* __restrict__ centers)
{
    int b = blockIdx.x;
    float m0=-3.4e38f, m1v=-3.4e38f, m2v=-3.4e38f;
    for (int n = threadIdx.x; n < NN; n += 256) {
        const float* rp = ratio + ((size_t)b*NN + n)*3;
        m0 = fmaxf(m0, rp[0]); m1v = fmaxf(m1v, rp[1]); m2v = fmaxf(m2v, rp[2]);
    }
#pragma unroll
    for (int off = 32; off > 0; off >>= 1) {
        m0  = fmaxf(m0,  __shfl_down(m0,  off));
        m1v = fmaxf(m1v, __shfl_down(m1v, off));
        m2v = fmaxf(m2v, __shfl_down(m2v, off));
    }
    __shared__ float red[4][3];
    int wid = threadIdx.x >> 6, lane = threadIdx.x & 63;
    if (lane == 0) { red[wid][0]=m0; red[wid][1]=m1v; red[wid][2]=m2v; }
    __syncthreads();
    if (threadIdx.x == 0) {
        centers[b*3+0] = fmaxf(fmaxf(red[0][0],red[1][0]), fmaxf(red[2][0],red[3][0]));
        centers[b*3+1] = fmaxf(fmaxf(red[0][1],red[1][1]), fmaxf(red[2][1],red[3][1]));
        centers[b*3+2] = fmaxf(fmaxf(red[0][2],red[1][2]), fmaxf(red[2][2],red[3][2]));
    }
}

// ---------------- K4: labels + m1/m2 ----------------
__global__ void k4_labels(const float* __restrict__ ratio, const float* __restrict__ centers,
                          const float* __restrict__ node_u, const float* __restrict__ node_d,
                          int* __restrict__ label, float* __restrict__ m1, float* __restrict__ m2)
{
    int n = blockIdx.x*256 + threadIdx.x;
    if (n >= NN) return;
    int c0=0, c1=0, c2=0;
    for (int b = 0; b < BB; b++) {
        const float* rp = ratio + ((size_t)b*NN + n)*3;
        const float* cp = centers + b*3;
        float d0 = fabsf(rp[0]-cp[0]), d1 = fabsf(rp[1]-cp[1]), d2 = fabsf(rp[2]-cp[2]);
        int a = 0; float best = d0;
        if (d1 < best) { best = d1; a = 1; }
        if (d2 < best) { best = d2; a = 2; }
        if (a == 0) c0++; else if (a == 1) c1++; else c2++;
    }
    int lab = 0, bc = c0;
    if (c1 > bc) { bc = c1; lab = 1; }
    if (c2 > bc) { bc = c2; lab = 2; }
    label[n] = lab;
#pragma unroll
    for (int d = 0; d < 10; d++) {
        m1[n*10+d] = tanhf(kALPHA*node_u[n*10+d]);
        m2[n*10+d] = tanhf(kALPHA*node_d[n*10+d]);
    }
}

// ---------------- K5: An ----------------
__global__ __launch_bounds__(256) void k5_A(const float* __restrict__ m1, const float* __restrict__ m2,
                                            const int* __restrict__ label, float* __restrict__ An)
{
    int n = blockIdx.x;
    __shared__ float row[1024];
    __shared__ float m1n[10], m2n[10];
    __shared__ float ssum[4];
    int t = threadIdx.x;
    if (t < 10) { m1n[t] = m1[n*10+t]; m2n[t] = m2[n*10+t]; }
    __syncthreads();
    int labn = label[n];
    float lsum = 0.f;
    for (int m = t; m < 1024; m += 256) {
        float a = 0.f;
        if (label[m] == labn) {
            float x = 0.f;
#pragma unroll
            for (int d = 0; d < 10; d++) x += m1n[d]*m2[m*10+d] - m2n[d]*m1[m*10+d];
            a = fmaxf(tanhf(3.f*x), 0.f);
        }
        row[m] = a; lsum += a;
    }
#pragma unroll
    for (int off = 32; off > 0; off >>= 1) lsum += __shfl_down(lsum, off);
    int wid = t >> 6, lane = t & 63;
    if (lane == 0) ssum[wid] = lsum;
    __syncthreads();
    float inv = 1.f/((ssum[0]+ssum[1]+ssum[2]+ssum[3]) + 1e-6f);
    for (int m = t; m < 1024; m += 256) An[(size_t)n*1024 + m] = row[m]*inv;
}

// ---------------- transpose fp32 [R][C] -> bf16 outT[C][R] (optional direct convert) ----------------
template<bool ALSO_DIRECT>
__global__ __launch_bounds__(256) void kt_transpose(const float* __restrict__ in,
                                                    unsigned short* __restrict__ outT,
                                                    unsigned short* __restrict__ outD,
                                                    int R, int C)
{
    __shared__ float tile[64][65];
    int c0 = blockIdx.x*64, r0 = blockIdx.y*64;
    for (int i = threadIdx.x; i < 64*64; i += 256) {
        int r = i >> 6, c = i & 63;
        float v = in[(size_t)(r0+r)*C + c0+c];
        tile[r][c] = v;
        if (ALSO_DIRECT) outD[(size_t)(r0+r)*C + c0+c] = f2bf(v);
    }
    __syncthreads();
    for (int i = threadIdx.x; i < 64*64; i += 256) {
        int c = i >> 6, r = i & 63;
        outT[(size_t)(c0+c)*R + r0+r] = f2bf(tile[r][c]);
    }
}

// ---------------- bf16 MFMA GEMM, 128x128 tile, 4 waves, 16x16x32 frags ----------------
// A [M][K] bf16 (lda=K), B [N][K] bf16 (ldb=K).
// MODE 0: AcombB(bf16) = bf16(0.9025*acc + 0.0475*An(from A bf16) + 0.05*I)
// MODE 1: C(fp32) = acc
template<int MODE>
__global__ __launch_bounds__(256) void gemm_mfma(
    const unsigned short* __restrict__ A, const unsigned short* __restrict__ B,
    void* __restrict__ Cout, int Nout, int K)
{
    __shared__ unsigned short As[128*40];
    __shared__ unsigned short Bs[128*40];
    const int t = threadIdx.x;
    const int lane = t & 63, wid = t >> 6;
    const int wr = wid >> 1, wc = wid & 1;
    const int l15 = lane & 15, l4 = lane >> 4;
    const int row0 = blockIdx.y*128, col0 = blockIdx.x*128;
    const int sr = t >> 2;            // 0..63
    const int sk = (t & 3)*8;         // bf16 offset in k

    float4v acc[4][4];
#pragma unroll
    for (int i = 0; i < 4; i++)
#pragma unroll
        for (int j = 0; j < 4; j++) acc[i][j] = (float4v){0.f,0.f,0.f,0.f};

    for (int k0 = 0; k0 < K; k0 += 32) {
        __syncthreads();
        *(short8v*)&As[(sr)*40 + sk]    = *(const short8v*)&A[(size_t)(row0+sr)*K + k0 + sk];
        *(short8v*)&As[(sr+64)*40 + sk] = *(const short8v*)&A[(size_t)(row0+sr+64)*K + k0 + sk];
        *(short8v*)&Bs[(sr)*40 + sk]    = *(const short8v*)&B[(size_t)(col0+sr)*K + k0 + sk];
        *(short8v*)&Bs[(sr+64)*40 + sk] = *(const short8v*)&B[(size_t)(col0+sr+64)*K + k0 + sk];
        __syncthreads();
        short8v a[4], b[4];
#pragma unroll
        for (int f = 0; f < 4; f++) {
            a[f] = *(const short8v*)&As[(wr*64 + f*16 + l15)*40 + l4*8];
            b[f] = *(const short8v*)&Bs[(wc*64 + f*16 + l15)*40 + l4*8];
        }
#pragma unroll
        for (int i = 0; i < 4; i++)
#pragma unroll
            for (int j = 0; j < 4; j++)
                acc[i][j] = __builtin_amdgcn_mfma_f32_16x16x32_bf16(a[i], b[j], acc[i][j], 0, 0, 0);
    }

#pragma unroll
    for (int i = 0; i < 4; i++) {
#pragma unroll
        for (int j = 0; j < 4; j++) {
            int gc = col0 + wc*64 + j*16 + l15;
#pragma unroll
            for (int r = 0; r < 4; r++) {
                int gr = row0 + wr*64 + i*16 + l4*4 + r;
                if (MODE == 0) {
                    float an = bf2f(A[(size_t)gr*K + gc]);
                    float v = 0.9025f*acc[i][j][r] + 0.0475f*an + ((gr==gc) ? 0.05f : 0.f);
                    ((unsigned short*)Cout)[(size_t)gr*Nout + gc] = f2bf(v);
                } else {
                    ((float*)Cout)[(size_t)gr*Nout + gc] = acc[i][j][r];
                }
            }
        }
    }
}

// ---------------- K7: x0[n, b*1024 + c*32 + h] ----------------
__global__ __launch_bounds__(256) void k7_x0(const float* __restrict__ hist,
                                             const float* __restrict__ W_start, const float* __restrict__ b_start,
                                             float* __restrict__ x0)
{
    int bid = blockIdx.x; int n = bid & (NN-1), b = bid >> 10;
    __shared__ float hl[384];
    __shared__ float sw[384];
    int t = threadIdx.x;
    for (int idx = t; idx < 384; idx += 256) {
        int l = idx >> 5, hh = idx & 31;
        hl[idx] = hist[((size_t)(b*12+l)*NN + n)*32 + hh];
    }
    for (int idx = t; idx < 384; idx += 256) sw[idx] = W_start[idx];
    __syncthreads();
    int c = t >> 3, h4 = (t & 7)*4;
    float bs = b_start[c];
    float o0 = bs, o1 = bs, o2 = bs, o3 = bs;
#pragma unroll
    for (int l = 0; l < 12; l++) {
        float w = sw[c*12+l];
        o0 += w*hl[l*32+h4];   o1 += w*hl[l*32+h4+1];
        o2 += w*hl[l*32+h4+2]; o3 += w*hl[l*32+h4+3];
    }
    *(float4*)&x0[(size_t)n*8192 + b*1024 + c*32 + h4] = make_float4(o0, o1, o2, o3);
}

// ---------------- Kw: Wcombo ----------------
__global__ void kw_combo(const float* __restrict__ W_g, const float* __restrict__ W_rnn, float* __restrict__ wcombo)
{
    int j = threadIdx.x;
    for (int hh = 0; hh < 32; hh++) {
        float s = 0.f;
        for (int k = 0; k < 32; k++) s += (W_g[hh*32+k] + W_g[1024 + hh*32+k]) * W_rnn[k*128 + j];
        wcombo[hh*128 + j] = s;
    }
}

// ---------------- K9 v2 ----------------
__global__ __launch_bounds__(256) void k9_rnn2(
    const float* __restrict__ hfin, const float* __restrict__ wcombo,
    const float* __restrict__ b_rnn, const float* __restrict__ W_e1,
    const float* __restrict__ b_e1, const float* __restrict__ W_e2,
    const float* __restrict__ b_e2, const float* __restrict__ Mm,
    float* __restrict__ xout)
{
    __shared__ float sXr[32*128];
    __shared__ float sH[1024];
    __shared__ float sWbuf[4096 + 2048];
    __shared__ float sV[12*128];
    __shared__ float sBe1[128];

    const int bid = blockIdx.x;
    const int n = bid & (NN-1), b = bid >> 10;
    const int t = threadIdx.x;
    const int j2 = t & 63;
    const int og = t >> 6;
    const int j0 = j2, j1 = j2 + 64;

    for (int i = t; i < 4096; i += 256) sWbuf[i] = wcombo[i];
    for (int i = t; i < 1024; i += 256) sH[i] = hfin[(size_t)n*8192 + (size_t)b*1024 + i];
    for (int i = t; i < 1536; i += 256) sV[i] = 0.f;
    if (t < 128) sBe1[t] = b_e1[t];
    __syncthreads();

    float wc0[32], wc1[32];
#pragma unroll
    for (int h = 0; h < 32; h++) { wc0[h] = sWbuf[h*128 + j0]; wc1[h] = sWbuf[h*128 + j1]; }
    float br0 = b_rnn[j0], br1 = b_rnn[j1];
#pragma unroll
    for (int ci = 0; ci < 8; ci++) {
        int c = og*8 + ci;
        float u0 = br0, u1 = br1;
#pragma unroll
        for (int q = 0; q < 8; q++) {
            float4 hv = *(const float4*)&sH[c*32 + q*4];
            u0 += hv.x*wc0[q*4+0] + hv.y*wc0[q*4+1] + hv.z*wc0[q*4+2] + hv.w*wc0[q*4+3];
            u1 += hv.x*wc1[q*4+0] + hv.y*wc1[q*4+1] + hv.z*wc1[q*4+2] + hv.w*wc1[q*4+3];
        }
        sXr[c*128 + j0] = tanhf(u0);
        sXr[c*128 + j1] = tanhf(u1);
    }
    __syncthreads();

    for (int i = t; i < 4096; i += 256) sWbuf[i] = W_e1[i];
    for (int i = t; i < 2048; i += 256) {
        int o1 = i >> 4, o2 = i & 15;
        sWbuf[4096 + i] = (o2 < 12) ? W_e2[o2*128 + o1] : 0.f;
    }
    __syncthreads();

    float xr0[32], xr1[32];
#pragma unroll
    for (int c = 0; c < 32; c++) { xr0[c] = sXr[c*128 + j0]; xr1[c] = sXr[c*128 + j1]; }
    float v0[12], v1[12];
#pragma unroll
    for (int o2 = 0; o2 < 12; o2++) { v0[o2] = 0.f; v1[o2] = 0.f; }

#pragma unroll 4
    for (int oi = 0; oi < 32; oi++) {
        int o1 = og*32 + oi;
        float u0 = sBe1[o1], u1 = sBe1[o1];
#pragma unroll
        for (int q = 0; q < 8; q++) {
            float4 w = *(const float4*)&sWbuf[o1*32 + q*4];
            u0 += w.x*xr0[q*4+0] + w.y*xr0[q*4+1] + w.z*xr0[q*4+2] + w.w*xr0[q*4+3];
            u1 += w.x*xr1[q*4+0] + w.y*xr1[q*4+1] + w.z*xr1[q*4+2] + w.w*xr1[q*4+3];
        }
        u0 = fmaxf(u0, 0.f); u1 = fmaxf(u1, 0.f);
#pragma unroll
        for (int q = 0; q < 3; q++) {
            float4 w2 = *(const float4*)&sWbuf[4096 + o1*16 + q*4];
            v0[q*4+0] += w2.x*u0; v0[q*4+1] += w2.y*u0; v0[q*4+2] += w2.z*u0; v0[q*4+3] += w2.w*u0;
            v1[q*4+0] += w2.x*u1; v1[q*4+1] += w2.y*u1; v1[q*4+2] += w2.z*u1; v1[q*4+3] += w2.w*u1;
        }
    }

#pragma unroll
    for (int g = 0; g < 4; g++) {
        if (og == g) {
#pragma unroll
            for (int o2 = 0; o2 < 12; o2++) {
                sV[o2*128 + j0] += v0[o2];
                sV[o2*128 + j1] += v1[o2];
            }
        }
        __syncthreads();
    }

    for (int i = t; i < 1536; i += 256) {
        int o2 = i >> 7, j = i & 127;
        float val = (sV[i] + b_e2[o2]) * Mm[n*128 + j];
        xout[((size_t)(b*12 + o2)*NN + n)*128 + j] = val;
    }
}

// ---------------- kp_fh: build relu(fh) bf16 [98304][288] ----------------
__global__ __launch_bounds__(256) void kp_fh(
    const float* __restrict__ xout, const float* __restrict__ hist, const float* __restrict__ h0,
    const float* __restrict__ hd, const float* __restrict__ T_emb, const float* __restrict__ D_emb,
    unsigned short* __restrict__ fhB)
{
    int pos_base = blockIdx.x * 128;
    for (int idx = threadIdx.x; idx < 128*288; idx += 256) {
        int r = idx / 288, k = idx - r*288;
        int pos = pos_base + r;
        float v = 0.f;
        if (k < 128)       v = xout[(size_t)pos*128 + k];
        else if (k < 160)  v = hist[(size_t)pos*32 + (k-128)];
        else if (k < 256)  v = h0[(size_t)pos*96 + (k-160)];
        else if (k < 266) { int ti = (int)(hd[(size_t)pos*5+3]*288.0f); v = T_emb[ti*10 + (k-256)]; }
        else if (k < 276) { int di = (int)hd[(size_t)pos*5+4];          v = D_emb[di*10 + (k-266)]; }
        fhB[(size_t)pos*288 + k] = f2bf(fmaxf(v, 0.f));
    }
}

// ---------------- kt_w1: W_f1 -> hi/lo bf16 [512][288] (n-major) ----------------
__global__ void kt_w1(const float* __restrict__ W_f1, unsigned short* __restrict__ w1hi,
                      unsigned short* __restrict__ w1lo)
{
    int idx = blockIdx.x*256 + threadIdx.x;
    if (idx >= 512*288) return;
    int n = idx / 288, k = idx - n*288;
    float w = (k < 276) ? W_f1[(size_t)k*512 + n] : 0.f;
    unsigned short hi = f2bf(w);
    w1hi[idx] = hi;
    w1lo[idx] = f2bf(w - bf2f(hi));
}

// ---------------- K10 MFMA head: fc += (relu(fhB @ W1 + b_f1)) @ W_f2 ----------------
__global__ __launch_bounds__(256) void k10_mfma(
    const unsigned short* __restrict__ fhB, const unsigned short* __restrict__ w1hi,
    const unsigned short* __restrict__ w1lo, const float* __restrict__ b_f1,
    const float* __restrict__ W_f2, float* __restrict__ fc)
{
    __shared__ unsigned short As[128*40];
    __shared__ unsigned short Bh[128*40];
    __shared__ unsigned short Bl[128*40];
    __shared__ float fcp[384];

    const int t = threadIdx.x;
    const int lane = t & 63, wid = t >> 6;
    const int wr = wid >> 1, wc = wid & 1;
    const int l15 = lane & 15, l4 = lane >> 4;
    const int pos0 = blockIdx.y*128, col0 = blockIdx.x*128;
    const int sr = t >> 2;
    const int sk = (t & 3)*8;

    for (int i = t; i < 384; i += 256) fcp[i] = 0.f;

    float4v acc[4][4];
#pragma unroll
    for (int i = 0; i < 4; i++)
#pragma unroll
        for (int j = 0; j < 4; j++) acc[i][j] = (float4v){0.f,0.f,0.f,0.f};

    for (int k0 = 0; k0 < 288; k0 += 32) {
        __syncthreads();
        *(short8v*)&As[(sr)*40 + sk]    = *(const short8v*)&fhB[(size_t)(pos0+sr)*288 + k0 + sk];
        *(short8v*)&As[(sr+64)*40 + sk] = *(const short8v*)&fhB[(size_t)(pos0+sr+64)*288 + k0 + sk];
        *(short8v*)&Bh[(sr)*40 + sk]    = *(const short8v*)&w1hi[(size_t)(col0+sr)*288 + k0 + sk];
        *(short8v*)&Bh[(sr+64)*40 + sk] = *(const short8v*)&w1hi[(size_t)(col0+sr+64)*288 + k0 + sk];
        *(short8v*)&Bl[(sr)*40 + sk]    = *(const short8v*)&w1lo[(size_t)(col0+sr)*288 + k0 + sk];
        *(short8v*)&Bl[(sr+64)*40 + sk] = *(const short8v*)&w1lo[(size_t)(col0+sr+64)*288 + k0 + sk];
        __syncthreads();
        short8v a[4], bh[4], bl[4];
#pragma unroll
        for (int f = 0; f < 4; f++) {
            a[f]  = *(const short8v*)&As[(wr*64 + f*16 + l15)*40 + l4*8];
            bh[f] = *(const short8v*)&Bh[(wc*64 + f*16 + l15)*40 + l4*8];
            bl[f] = *(const short8v*)&Bl[(wc*64 + f*16 + l15)*40 + l4*8];
        }
#pragma unroll
        for (int i = 0; i < 4; i++)
#pragma unroll
            for (int j = 0; j < 4; j++) {
                acc[i][j] = __builtin_amdgcn_mfma_f32_16x16x32_bf16(a[i], bh[j], acc[i][j], 0, 0, 0);
                acc[i][j] = __builtin_amdgcn_mfma_f32_16x16x32_bf16(a[i], bl[j], acc[i][j], 0, 0, 0);
            }
    }

    // epilogue: z = relu(acc + b_f1), pk = z @ W_f2 (per-lane), then LDS atomics
    float pk[4][4][3];
#pragma unroll
    for (int i = 0; i < 4; i++)
#pragma unroll
        for (int r = 0; r < 4; r++)
#pragma unroll
            for (int k = 0; k < 3; k++) pk[i][r][k] = 0.f;

#pragma unroll
    for (int j = 0; j < 4; j++) {
        int gc = col0 + wc*64 + j*16 + l15;
        float bias = b_f1[gc];
        float w20 = W_f2[gc*3+0], w21 = W_f2[gc*3+1], w22 = W_f2[gc*3+2];
#pragma unroll
        for (int i = 0; i < 4; i++)
#pragma unroll
            for (int r = 0; r < 4; r++) {
                float z = fmaxf(acc[i][j][r] + bias, 0.f);
                pk[i][r][0] += z*w20; pk[i][r][1] += z*w21; pk[i][r][2] += z*w22;
            }
    }
#pragma unroll
    for (int i = 0; i < 4; i++)
#pragma unroll
        for (int r = 0; r < 4; r++) {
            int rowL = wr*64 + i*16 + l4*4 + r;
            atomicAdd(&fcp[rowL*3 + 0], pk[i][r][0]);
            atomicAdd(&fcp[rowL*3 + 1], pk[i][r][1]);
            atomicAdd(&fcp[rowL*3 + 2], pk[i][r][2]);
        }
    __syncthreads();
    for (int i = t; i < 384; i += 256) {
        atomicAdd(&fc[(size_t)pos0*3 + i], fcp[i]);
    }
}

// ---------------- K11: e3 epilogue + transpose ----------------
__global__ void k11_e3(const float* __restrict__ fc, const float* __restrict__ b_f2,
                       const float* __restrict__ W_e3, const float* __restrict__ b_e3,
                       float* __restrict__ out)
{
    int idx = blockIdx.x*256 + threadIdx.x;
    if (idx >= BB*NN*12) return;
    int ok = idx % 12;
    int o = ok / 3, k = ok % 3;
    int bn = idx / 12;
    int n = bn & 1023, b = bn >> 10;
    float s = b_e3[o];
    float bk = b_f2[k];
#pragma unroll
    for (int c = 0; c < 12; c++)
        s += W_e3[o*12+c] * (fc[((size_t)(b*12+c)*NN + n)*3 + k] + bk);
    out[idx] = s;
}

extern "C" void kernel_launch(void* const* d_in, const int* in_sizes, int n_in,
                              void* d_out, int out_size, void* d_ws, size_t ws_size,
                              hipStream_t stream)
{
    const float* hd      = (const float*)d_in[0];
    const float* W_emb   = (const float*)d_in[1];
    const float* b_emb   = (const float*)d_in[2];
    const float* T_emb   = (const float*)d_in[3];
    const float* D_emb   = (const float*)d_in[4];
    const float* node_u  = (const float*)d_in[5];
    const float* node_d  = (const float*)d_in[6];
    const float* W_std   = (const float*)d_in[7];
    const float* b_std   = (const float*)d_in[8];
    const float* W_mlp   = (const float*)d_in[9];
    const float* b_mlp   = (const float*)d_in[10];
    const float* W_start = (const float*)d_in[11];
    const float* b_start = (const float*)d_in[12];
    const float* W_g     = (const float*)d_in[13];
    const float* W_rnn   = (const float*)d_in[14];
    const float* b_rnn   = (const float*)d_in[15];
    const float* W_e1    = (const float*)d_in[16];
    const float* b_e1    = (const float*)d_in[17];
    const float* W_e2    = (const float*)d_in[18];
    const float* b_e2    = (const float*)d_in[19];
    const float* Mm      = (const float*)d_in[20];
    const float* W_f1    = (const float*)d_in[21];
    const float* b_f1    = (const float*)d_in[22];
    const float* W_f2    = (const float*)d_in[23];
    const float* b_f2    = (const float*)d_in[24];
    const float* W_e3    = (const float*)d_in[25];
    const float* b_e3    = (const float*)d_in[26];

    float* ws      = (float*)d_ws;
    float* hist    = ws + OFF_HIST;
    float* h0      = ws + OFF_H0;
    float* s4      = ws + OFF_S4;
    float* ratio   = ws + OFF_RATIO;
    float* cent    = ws + OFF_CENT;
    float* m1      = ws + OFF_M1;
    float* m2      = ws + OFF_M2;
    int*   label   = (int*)(ws + OFF_LABEL);
    float* An      = ws + OFF_AN;
    unsigned short* AcombB = (unsigned short*)(ws + OFF_ACOMBB);
    float* x0      = ws + OFF_X0;
    float* hfin    = ws + OFF_HFIN;
    float* wcombo  = ws + OFF_WCOMBO;
    float* xoutb   = ws + OFF_XOUT;
    float* fc      = ws + OFF_FC;
    unsigned short* AnB   = (unsigned short*)(ws + OFF_ANB);
    unsigned short* AnBT  = (unsigned short*)(ws + OFF_ANBT);
    unsigned short* x0T   = (unsigned short*)(ws + OFF_X0T);
    unsigned short* w1hi  = (unsigned short*)(ws + OFF_W1HI);
    unsigned short* w1lo  = (unsigned short*)(ws + OFF_W1LO);
    unsigned short* fhB   = (unsigned short*)(ws + OFF_X0);   // overlays x0+hfin after k9

    k1_embed<<<(BB*LL*NN)/256, 256, 0, stream>>>(hd, W_emb, b_emb, T_emb, D_emb, node_u,
                                                 W_std, b_std, W_mlp, b_mlp, hist, h0, s4);
    k2_ratio<<<(BB*NN)/256, 256, 0, stream>>>(s4, ratio);
    k3_centers<<<BB, 256, 0, stream>>>(ratio, cent);
    k4_labels<<<NN/256, 256, 0, stream>>>(ratio, cent, node_u, node_d, label, m1, m2);
    k5_A<<<NN, 256, 0, stream>>>(m1, m2, label, An);
    kt_transpose<true><<<dim3(16, 16), 256, 0, stream>>>(An, AnBT, AnB, 1024, 1024);
    gemm_mfma<0><<<dim3(8, 8), 256, 0, stream>>>(AnB, AnBT, AcombB, 1024, 1024);
    k7_x0<<<BB*NN, 256, 0, stream>>>(hist, W_start, b_start, x0);
    kt_transpose<false><<<dim3(128, 16), 256, 0, stream>>>(x0, x0T, (unsigned short*)0, 1024, 8192);
    gemm_mfma<1><<<dim3(64, 8), 256, 0, stream>>>(AcombB, x0T, hfin, 8192, 1024);
    kw_combo<<<1, 128, 0, stream>>>(W_g, W_rnn, wcombo);
    k9_rnn2<<<BB*NN, 256, 0, stream>>>(hfin, wcombo, b_rnn, W_e1, b_e1, W_e2, b_e2, Mm, xoutb);
    kp_fh<<<(BB*LL*NN)/128, 256, 0, stream>>>(xoutb, hist, h0, hd, T_emb, D_emb, fhB);
    kt_w1<<<(512*288)/256, 256, 0, stream>>>(W_f1, w1hi, w1lo);
    hipMemsetAsync(fc, 0, (size_t)BB*LL*NN*3*sizeof(float), stream);
    k10_mfma<<<dim3(4, 768), 256, 0, stream>>>(fhB, w1hi, w1lo, b_f1, W_f2, fc);
    k11_e3<<<(BB*NN*12)/256, 256, 0, stream>>>(fc, b_f2, W_e3, b_e3, (float*)d_out);
}

// Round 4
// 851.714 us; speedup vs baseline: 2.5309x; 1.0481x over previous
//
#include <hip/hip_runtime.h>
#include <math.h>

#define BB 8
#define LL 12
#define NN 1024
#define FF 3
#define HH 32
#define NDD 10
#define TTT 10
#define PP 3
#define DOUTT 128
constexpr float kALPHA = 3.0f;

typedef __attribute__((ext_vector_type(8))) short short8v;   // 8 bf16 (4 VGPR)
typedef __attribute__((ext_vector_type(4))) float float4v;

__device__ __forceinline__ unsigned short f2bf(float x) {
    union { float f; unsigned u; } v; v.f = x;
    unsigned r = v.u + 0x7FFF + ((v.u >> 16) & 1);
    return (unsigned short)(r >> 16);
}
__device__ __forceinline__ float bf2f(unsigned short u) {
    union { unsigned u; float f; } v; v.u = ((unsigned)u) << 16;
    return v.f;
}

// async global->LDS, 16B per lane. LDS dest = wave-uniform base + lane*16.
__device__ __forceinline__ void gload_lds16(const unsigned short* g, unsigned short* l) {
    __builtin_amdgcn_global_load_lds(
        (const __attribute__((address_space(1))) void*)g,
        (__attribute__((address_space(3))) void*)l,
        16, 0, 0);
}

// Stage a 128x32 bf16 tile (row-major, row stride = `stride` elems) into LDS,
// XOR-swizzled: LDS chunk (row, ql) holds global chunk (row, ql ^ ((row>>1)&3)).
// 512 chunks of 16B; 256 threads -> 2 rounds.
__device__ __forceinline__ void stage_tile(const unsigned short* __restrict__ g, int stride,
                                           unsigned short* tile, int tid) {
#pragma unroll
    for (int rr = 0; rr < 2; rr++) {
        int c = rr*256 + tid;
        int row = c >> 2;
        int q = (c & 3) ^ ((row >> 1) & 3);
        gload_lds16(g + (size_t)row*stride + q*8,
                    tile + ((size_t)(rr*256 + (tid & 192)))*8);
    }
}

// ---------------- workspace layout (floats) ----------------
constexpr size_t OFF_HIST   = 0;                                         // B*L*N*32
constexpr size_t OFF_H0     = OFF_HIST  + (size_t)BB*LL*NN*HH;           // B*L*N*96
constexpr size_t OFF_S4     = OFF_H0    + (size_t)BB*LL*NN*3*HH;         // B*L*N*4
constexpr size_t OFF_RATIO  = OFF_S4    + (size_t)BB*LL*NN*4;            // B*N*3
constexpr size_t OFF_CENT   = OFF_RATIO + (size_t)BB*NN*3;               // 32
constexpr size_t OFF_M1     = OFF_CENT  + 32;                            // N*10
constexpr size_t OFF_M2     = OFF_M1    + (size_t)NN*NDD;                // N*10
constexpr size_t OFF_LABEL  = OFF_M2    + (size_t)NN*NDD;                // N ints
constexpr size_t OFF_AN     = OFF_LABEL + NN;                            // N*N fp32
constexpr size_t OFF_ACOMBB = OFF_AN    + (size_t)NN*NN;                 // N*N bf16
constexpr size_t OFF_X0     = OFF_ACOMBB+ (size_t)NN*NN;                 // N*8192 fp32 (later fhB overlay)
constexpr size_t OFF_HFIN   = OFF_X0    + (size_t)NN*BB*HH*HH;           // N*8192 fp32
constexpr size_t OFF_WCOMBO = OFF_HFIN  + (size_t)NN*BB*HH*HH;           // 32*128
constexpr size_t OFF_XOUT   = OFF_WCOMBO+ (size_t)HH*DOUTT;              // B*12*N*128
constexpr size_t OFF_FC     = OFF_XOUT  + (size_t)BB*LL*NN*DOUTT;        // B*12*N*3
constexpr size_t OFF_ANB    = OFF_FC    + (size_t)BB*LL*NN*3;            // 1024*1024 bf16
constexpr size_t OFF_ANBT   = OFF_ANB   + (size_t)NN*NN/2;               // 1024*1024 bf16
constexpr size_t OFF_X0T    = OFF_ANBT  + (size_t)NN*NN/2;               // 8192*1024 bf16
constexpr size_t OFF_W1HI   = OFF_X0T   + (size_t)BB*HH*HH*NN/2;         // 512*288 bf16
constexpr size_t OFF_W1LO   = OFF_W1HI  + (size_t)512*288/2;
constexpr size_t WS_FLOATS  = OFF_W1LO  + (size_t)512*288/2;             // ~201 MB

// ---------------- K1: embed + std decomposition ----------------
__global__ __launch_bounds__(256) void k1_embed(
    const float* __restrict__ hd, const float* __restrict__ W_emb, const float* __restrict__ b_emb,
    const float* __restrict__ T_emb, const float* __restrict__ D_emb, const float* __restrict__ node_u,
    const float* __restrict__ W_std, const float* __restrict__ b_std,
    const float* __restrict__ W_mlp, const float* __restrict__ b_mlp,
    float* __restrict__ hist, float* __restrict__ h0, float* __restrict__ s4)
{
    __shared__ float sW[2*62*32];
    for (int i = threadIdx.x; i < 2*62*32; i += 256) sW[i] = W_std[i];
    __syncthreads();

    int pos = blockIdx.x*256 + threadIdx.x;
    int n = pos & (NN-1);
    const float* hp = hd + (size_t)pos*5;
    float f0 = hp[0], f1 = hp[1], f2 = hp[2];
    int ti = (int)(hp[3]*288.0f);
    int di = (int)hp[4];

    float tv[10], dv[10], nu[10];
#pragma unroll
    for (int t = 0; t < 10; t++) {
        tv[t] = T_emb[ti*10+t]; dv[t] = D_emb[di*10+t]; nu[t] = node_u[n*10+t];
    }
    float h[32];
#pragma unroll
    for (int j = 0; j < 32; j++) h[j] = b_emb[j] + f0*W_emb[j] + f1*W_emb[32+j] + f2*W_emb[64+j];

    float a0[32], a1[32];
#pragma unroll
    for (int j = 0; j < 32; j++) { a0[j] = b_std[j]; a1[j] = b_std[32+j]; }

    auto accum = [&](float v, int i) {
#pragma unroll
        for (int q = 0; q < 8; q++) {
            float4 w0 = *(const float4*)&sW[i*32 + q*4];
            float4 w1 = *(const float4*)&sW[(62+i)*32 + q*4];
            a0[q*4+0] += v*w0.x; a0[q*4+1] += v*w0.y; a0[q*4+2] += v*w0.z; a0[q*4+3] += v*w0.w;
            a1[q*4+0] += v*w1.x; a1[q*4+1] += v*w1.y; a1[q*4+2] += v*w1.z; a1[q*4+3] += v*w1.w;
        }
    };
#pragma unroll
    for (int i = 0; i < 32; i++) accum(h[i], i);
#pragma unroll
    for (int i = 0; i < 10; i++) accum(nu[i], 32+i);
#pragma unroll
    for (int i = 0; i < 10; i++) accum(tv[i], 42+i);
#pragma unroll
    for (int i = 0; i < 10; i++) accum(dv[i], 52+i);

    float x0v[32], x1v[32], rv[32];
    float s0 = b_mlp[0], s1 = b_mlp[1], s2 = b_mlp[2], s3 = b_mlp[3];
#pragma unroll
    for (int j = 0; j < 32; j++) {
        float sg0 = 1.f/(1.f + __expf(-a0[j]));
        float sg1 = 1.f/(1.f + __expf(-a1[j]));
        x0v[j] = sg0*h[j]; x1v[j] = sg1*h[j]; rv[j] = h[j] - x0v[j] - x1v[j];
        s0 += h[j]  * W_mlp[j];
        s1 += x0v[j]* W_mlp[32+j];
        s2 += x1v[j]* W_mlp[64+j];
        s3 += rv[j] * W_mlp[96+j];
    }
    float* ho = hist + (size_t)pos*32;
    float* hz = h0   + (size_t)pos*96;
#pragma unroll
    for (int q = 0; q < 8; q++) {
        *(float4*)&ho[q*4]    = make_float4(h[q*4],   h[q*4+1],   h[q*4+2],   h[q*4+3]);
        *(float4*)&hz[q*4]    = make_float4(x0v[q*4], x0v[q*4+1], x0v[q*4+2], x0v[q*4+3]);
        *(float4*)&hz[32+q*4] = make_float4(x1v[q*4], x1v[q*4+1], x1v[q*4+2], x1v[q*4+3]);
        *(float4*)&hz[64+q*4] = make_float4(rv[q*4],  rv[q*4+1],  rv[q*4+2],  rv[q*4+3]);
    }
    *(float4*)&s4[(size_t)pos*4] = make_float4(s0, s1, s2, s3);
}

// ---------------- K2: ratios ----------------
__global__ void k2_ratio(const float* __restrict__ s4, float* __restrict__ ratio)
{
    int bn = blockIdx.x*256 + threadIdx.x;
    if (bn >= BB*NN) return;
    int b = bn >> 10, n = bn & 1023;
    float a0=0, a1=0, a2=0, a3=0;
    for (int l = 0; l < 12; l++) {
        const float* sp = s4 + ((size_t)(b*12+l)*NN + n)*4;
        a0 += sp[0]; a1 += sp[1]; a2 += sp[2]; a3 += sp[3];
    }
    float hm = a0/12.f;
    float* rp = ratio + (size_t)bn*3;
    rp[0] = (a1/12.f)/(hm + 1e-6f);
    rp[1] = (a2/12.f)/(hm + 1e-6f);
    rp[2] = (a3/12.f)/(hm + 1e-6f);
}

// ---------------- K3: per-b centers ----------------
__global__ __launch_bounds__(256) void k3_centers(const float* __restrict__ ratio, float* __restrict__ centers)
{
    int b = blockIdx.x;
    float m0=-3.4e38f, m1v=-3.4e38f, m2v=-3.4e38f;
    for (int n = threadIdx.x; n < NN; n += 256) {
        const float* rp = ratio + ((size_t)b*NN + n)*3;
        m0 = fmaxf(m0, rp[0]); m1v = fmaxf(m1v, rp[1]); m2v = fmaxf(m2v, rp[2]);
    }
#pragma unroll
    for (int off = 32; off > 0; off >>= 1) {
        m0  = fmaxf(m0,  __shfl_down(m0,  off));
        m1v = fmaxf(m1v, __shfl_down(m1v, off));
        m2v = fmaxf(m2v, __shfl_down(m2v, off));
    }
    __shared__ float red[4][3];
    int wid = threadIdx.x >> 6, lane = threadIdx.x & 63;
    if (lane == 0) { red[wid][0]=m0; red[wid][1]=m1v; red[wid][2]=m2v; }
    __syncthreads();
    if (threadIdx.x == 0) {
        centers[b*3+0] = fmaxf(fmaxf(red[0][0],red[1][0]), fmaxf(red[2][0],red[3][0]));
        centers[b*3+1] = fmaxf(fmaxf(red[0][1],red[1][1]), fmaxf(red[2][1],red[3][1]));
        centers[b*3+2] = fmaxf(fmaxf(red[0][2],red[1][2]), fmaxf(red[2][2],red[3][2]));
    }
}

// ---------------- K4: labels + m1/m2 ----------------
__global__ void k4_labels(const float* __restrict__ ratio, const float* __restrict__ centers,
                          const float* __restrict__ node_u, const float* __restrict__ node_d,
                          int* __restrict__ label, float* __restrict__ m1, float* __restrict__ m2)
{
    int n = blockIdx.x*256 + threadIdx.x;
    if (n >= NN) return;
    int c0=0, c1=0, c2=0;
    for (int b = 0; b < BB; b++) {
        const float* rp = ratio + ((size_t)b*NN + n)*3;
        const float* cp = centers + b*3;
        float d0 = fabsf(rp[0]-cp[0]), d1 = fabsf(rp[1]-cp[1]), d2 = fabsf(rp[2]-cp[2]);
        int a = 0; float best = d0;
        if (d1 < best) { best = d1; a = 1; }
        if (d2 < best) { best = d2; a = 2; }
        if (a == 0) c0++; else if (a == 1) c1++; else c2++;
    }
    int lab = 0, bc = c0;
    if (c1 > bc) { bc = c1; lab = 1; }
    if (c2 > bc) { bc = c2; lab = 2; }
    label[n] = lab;
#pragma unroll
    for (int d = 0; d < 10; d++) {
        m1[n*10+d] = tanhf(kALPHA*node_u[n*10+d]);
        m2[n*10+d] = tanhf(kALPHA*node_d[n*10+d]);
    }
}

// ---------------- K5: An ----------------
__global__ __launch_bounds__(256) void k5_A(const float* __restrict__ m1, const float* __restrict__ m2,
                                            const int* __restrict__ label, float* __restrict__ An)
{
    int n = blockIdx.x;
    __shared__ float row[1024];
    __shared__ float m1n[10], m2n[10];
    __shared__ float ssum[4];
    int t = threadIdx.x;
    if (t < 10) { m1n[t] = m1[n*10+t]; m2n[t] = m2[n*10+t]; }
    __syncthreads();
    int labn = label[n];
    float lsum = 0.f;
    for (int m = t; m < 1024; m += 256) {
        float a = 0.f;
        if (label[m] == labn) {
            float x = 0.f;
#pragma unroll
            for (int d = 0; d < 10; d++) x += m1n[d]*m2[m*10+d] - m2n[d]*m1[m*10+d];
            a = fmaxf(tanhf(3.f*x), 0.f);
        }
        row[m] = a; lsum += a;
    }
#pragma unroll
    for (int off = 32; off > 0; off >>= 1) lsum += __shfl_down(lsum, off);
    int wid = t >> 6, lane = t & 63;
    if (lane == 0) ssum[wid] = lsum;
    __syncthreads();
    float inv = 1.f/((ssum[0]+ssum[1]+ssum[2]+ssum[3]) + 1e-6f);
    for (int m = t; m < 1024; m += 256) An[(size_t)n*1024 + m] = row[m]*inv;
}

// ---------------- transpose fp32 [R][C] -> bf16 outT[C][R] ----------------
template<bool ALSO_DIRECT>
__global__ __launch_bounds__(256) void kt_transpose(const float* __restrict__ in,
                                                    unsigned short* __restrict__ outT,
                                                    unsigned short* __restrict__ outD,
                                                    int R, int C)
{
    __shared__ float tile[64][65];
    int c0 = blockIdx.x*64, r0 = blockIdx.y*64;
    for (int i = threadIdx.x; i < 64*64; i += 256) {
        int r = i >> 6, c = i & 63;
        float v = in[(size_t)(r0+r)*C + c0+c];
        tile[r][c] = v;
        if (ALSO_DIRECT) outD[(size_t)(r0+r)*C + c0+c] = f2bf(v);
    }
    __syncthreads();
    for (int i = threadIdx.x; i < 64*64; i += 256) {
        int c = i >> 6, r = i & 63;
        outT[(size_t)(c0+c)*R + r0+r] = f2bf(tile[r][c]);
    }
}

// ---------------- bf16 MFMA GEMM, 128x128 tile, 2-phase pipelined, swizzled gload_lds ----------------
// A [M][K] bf16 (lda=K), B [N][K] bf16 (ldb=K).
// MODE 0: AcombB(bf16) = bf16(0.9025*acc + 0.0475*A + 0.05*I)
// MODE 1: C(fp32) = acc
template<int MODE>
__global__ __launch_bounds__(256) void gemm_mfma(
    const unsigned short* __restrict__ A, const unsigned short* __restrict__ B,
    void* __restrict__ Cout, int Nout, int K)
{
    __shared__ __align__(16) unsigned short lds[2][2][128*32];
    const int t = threadIdx.x;

    // XCD-chunked 2D block remap (gx % 8 == 0 required; true for both uses)
    int id = blockIdx.x + gridDim.x*blockIdx.y;
    int gx8 = gridDim.x >> 3;
    int xcd = id & 7, local = id >> 3;
    int bx = xcd*gx8 + (local % gx8);
    int by = local / gx8;

    const int lane = t & 63, wid = t >> 6;
    const int wr = wid >> 1, wc = wid & 1;
    const int l15 = lane & 15, l4 = lane >> 4;
    const int swq8 = (l4 ^ ((l15 >> 1) & 3))*8;
    const int row0 = by*128, col0 = bx*128;

    float4v acc[4][4];
#pragma unroll
    for (int i = 0; i < 4; i++)
#pragma unroll
        for (int j = 0; j < 4; j++) acc[i][j] = (float4v){0.f,0.f,0.f,0.f};

    const unsigned short* Ab = A + (size_t)row0*K;
    const unsigned short* Bb = B + (size_t)col0*K;

    stage_tile(Ab, K, lds[0][0], t);
    stage_tile(Bb, K, lds[0][1], t);
    __syncthreads();

    const int nk = K >> 5;
    for (int ks = 0; ks < nk; ks++) {
        int cur = ks & 1;
        if (ks + 1 < nk) {
            stage_tile(Ab + (ks+1)*32, K, lds[cur^1][0], t);
            stage_tile(Bb + (ks+1)*32, K, lds[cur^1][1], t);
        }
        short8v a[4], b[4];
#pragma unroll
        for (int f = 0; f < 4; f++) {
            a[f] = *(const short8v*)&lds[cur][0][(wr*64 + f*16 + l15)*32 + swq8];
            b[f] = *(const short8v*)&lds[cur][1][(wc*64 + f*16 + l15)*32 + swq8];
        }
#pragma unroll
        for (int i = 0; i < 4; i++)
#pragma unroll
            for (int j = 0; j < 4; j++)
                acc[i][j] = __builtin_amdgcn_mfma_f32_16x16x32_bf16(a[i], b[j], acc[i][j], 0, 0, 0);
        __syncthreads();
    }

#pragma unroll
    for (int i = 0; i < 4; i++) {
#pragma unroll
        for (int j = 0; j < 4; j++) {
            int gc = col0 + wc*64 + j*16 + l15;
#pragma unroll
            for (int r = 0; r < 4; r++) {
                int gr = row0 + wr*64 + i*16 + l4*4 + r;
                if (MODE == 0) {
                    float an = bf2f(A[(size_t)gr*K + gc]);
                    float v = 0.9025f*acc[i][j][r] + 0.0475f*an + ((gr==gc) ? 0.05f : 0.f);
                    ((unsigned short*)Cout)[(size_t)gr*Nout + gc] = f2bf(v);
                } else {
                    ((float*)Cout)[(size_t)gr*Nout + gc] = acc[i][j][r];
                }
            }
        }
    }
}

// ---------------- K7: x0[n, b*1024 + c*32 + h] ----------------
__global__ __launch_bounds__(256) void k7_x0(const float* __restrict__ hist,
                                             const float* __restrict__ W_start, const float* __restrict__ b_start,
                                             float* __restrict__ x0)
{
    int bid = blockIdx.x; int n = bid & (NN-1), b = bid >> 10;
    __shared__ float hl[384];
    __shared__ float sw[384];
    int t = threadIdx.x;
    for (int idx = t; idx < 384; idx += 256) {
        int l = idx >> 5, hh = idx & 31;
        hl[idx] = hist[((size_t)(b*12+l)*NN + n)*32 + hh];
    }
    for (int idx = t; idx < 384; idx += 256) sw[idx] = W_start[idx];
    __syncthreads();
    int c = t >> 3, h4 = (t & 7)*4;
    float bs = b_start[c];
    float o0 = bs, o1 = bs, o2 = bs, o3 = bs;
#pragma unroll
    for (int l = 0; l < 12; l++) {
        float w = sw[c*12+l];
        o0 += w*hl[l*32+h4];   o1 += w*hl[l*32+h4+1];
        o2 += w*hl[l*32+h4+2]; o3 += w*hl[l*32+h4+3];
    }
    *(float4*)&x0[(size_t)n*8192 + b*1024 + c*32 + h4] = make_float4(o0, o1, o2, o3);
}

// ---------------- Kw: Wcombo ----------------
__global__ void kw_combo(const float* __restrict__ W_g, const float* __restrict__ W_rnn, float* __restrict__ wcombo)
{
    int j = threadIdx.x;
    for (int hh = 0; hh < 32; hh++) {
        float s = 0.f;
        for (int k = 0; k < 32; k++) s += (W_g[hh*32+k] + W_g[1024 + hh*32+k]) * W_rnn[k*128 + j];
        wcombo[hh*128 + j] = s;
    }
}

// ---------------- K9 v2 ----------------
__global__ __launch_bounds__(256) void k9_rnn2(
    const float* __restrict__ hfin, const float* __restrict__ wcombo,
    const float* __restrict__ b_rnn, const float* __restrict__ W_e1,
    const float* __restrict__ b_e1, const float* __restrict__ W_e2,
    const float* __restrict__ b_e2, const float* __restrict__ Mm,
    float* __restrict__ xout)
{
    __shared__ float sXr[32*128];
    __shared__ float sH[1024];
    __shared__ float sWbuf[4096 + 2048];
    __shared__ float sV[12*128];
    __shared__ float sBe1[128];

    const int bid = blockIdx.x;
    const int n = bid & (NN-1), b = bid >> 10;
    const int t = threadIdx.x;
    const int j2 = t & 63;
    const int og = t >> 6;
    const int j0 = j2, j1 = j2 + 64;

    for (int i = t; i < 4096; i += 256) sWbuf[i] = wcombo[i];
    for (int i = t; i < 1024; i += 256) sH[i] = hfin[(size_t)n*8192 + (size_t)b*1024 + i];
    for (int i = t; i < 1536; i += 256) sV[i] = 0.f;
    if (t < 128) sBe1[t] = b_e1[t];
    __syncthreads();

    float wc0[32], wc1[32];
#pragma unroll
    for (int h = 0; h < 32; h++) { wc0[h] = sWbuf[h*128 + j0]; wc1[h] = sWbuf[h*128 + j1]; }
    float br0 = b_rnn[j0], br1 = b_rnn[j1];
#pragma unroll
    for (int ci = 0; ci < 8; ci++) {
        int c = og*8 + ci;
        float u0 = br0, u1 = br1;
#pragma unroll
        for (int q = 0; q < 8; q++) {
            float4 hv = *(const float4*)&sH[c*32 + q*4];
            u0 += hv.x*wc0[q*4+0] + hv.y*wc0[q*4+1] + hv.z*wc0[q*4+2] + hv.w*wc0[q*4+3];
            u1 += hv.x*wc1[q*4+0] + hv.y*wc1[q*4+1] + hv.z*wc1[q*4+2] + hv.w*wc1[q*4+3];
        }
        sXr[c*128 + j0] = tanhf(u0);
        sXr[c*128 + j1] = tanhf(u1);
    }
    __syncthreads();

    for (int i = t; i < 4096; i += 256) sWbuf[i] = W_e1[i];
    for (int i = t; i < 2048; i += 256) {
        int o1 = i >> 4, o2 = i & 15;
        sWbuf[4096 + i] = (o2 < 12) ? W_e2[o2*128 + o1] : 0.f;
    }
    __syncthreads();

    float xr0[32], xr1[32];
#pragma unroll
    for (int c = 0; c < 32; c++) { xr0[c] = sXr[c*128 + j0]; xr1[c] = sXr[c*128 + j1]; }
    float v0[12], v1[12];
#pragma unroll
    for (int o2 = 0; o2 < 12; o2++) { v0[o2] = 0.f; v1[o2] = 0.f; }

#pragma unroll 4
    for (int oi = 0; oi < 32; oi++) {
        int o1 = og*32 + oi;
        float u0 = sBe1[o1], u1 = sBe1[o1];
#pragma unroll
        for (int q = 0; q < 8; q++) {
            float4 w = *(const float4*)&sWbuf[o1*32 + q*4];
            u0 += w.x*xr0[q*4+0] + w.y*xr0[q*4+1] + w.z*xr0[q*4+2] + w.w*xr0[q*4+3];
            u1 += w.x*xr1[q*4+0] + w.y*xr1[q*4+1] + w.z*xr1[q*4+2] + w.w*xr1[q*4+3];
        }
        u0 = fmaxf(u0, 0.f); u1 = fmaxf(u1, 0.f);
#pragma unroll
        for (int q = 0; q < 3; q++) {
            float4 w2 = *(const float4*)&sWbuf[4096 + o1*16 + q*4];
            v0[q*4+0] += w2.x*u0; v0[q*4+1] += w2.y*u0; v0[q*4+2] += w2.z*u0; v0[q*4+3] += w2.w*u0;
            v1[q*4+0] += w2.x*u1; v1[q*4+1] += w2.y*u1; v1[q*4+2] += w2.z*u1; v1[q*4+3] += w2.w*u1;
        }
    }

#pragma unroll
    for (int g = 0; g < 4; g++) {
        if (og == g) {
#pragma unroll
            for (int o2 = 0; o2 < 12; o2++) {
                sV[o2*128 + j0] += v0[o2];
                sV[o2*128 + j1] += v1[o2];
            }
        }
        __syncthreads();
    }

    for (int i = t; i < 1536; i += 256) {
        int o2 = i >> 7, j = i & 127;
        float val = (sV[i] + b_e2[o2]) * Mm[n*128 + j];
        xout[((size_t)(b*12 + o2)*NN + n)*128 + j] = val;
    }
}

// ---------------- kp_fh: build relu(fh) bf16 [98304][288] ----------------
__global__ __launch_bounds__(256) void kp_fh(
    const float* __restrict__ xout, const float* __restrict__ hist, const float* __restrict__ h0,
    const float* __restrict__ hd, const float* __restrict__ T_emb, const float* __restrict__ D_emb,
    unsigned short* __restrict__ fhB)
{
    int pos_base = blockIdx.x * 128;
    for (int idx = threadIdx.x; idx < 128*288; idx += 256) {
        int r = idx / 288, k = idx - r*288;
        int pos = pos_base + r;
        float v = 0.f;
        if (k < 128)       v = xout[(size_t)pos*128 + k];
        else if (k < 160)  v = hist[(size_t)pos*32 + (k-128)];
        else if (k < 256)  v = h0[(size_t)pos*96 + (k-160)];
        else if (k < 266) { int ti = (int)(hd[(size_t)pos*5+3]*288.0f); v = T_emb[ti*10 + (k-256)]; }
        else if (k < 276) { int di = (int)hd[(size_t)pos*5+4];          v = D_emb[di*10 + (k-266)]; }
        fhB[(size_t)pos*288 + k] = f2bf(fmaxf(v, 0.f));
    }
}

// ---------------- kt_w1: W_f1 -> hi/lo bf16 [512][288] (n-major) ----------------
__global__ void kt_w1(const float* __restrict__ W_f1, unsigned short* __restrict__ w1hi,
                      unsigned short* __restrict__ w1lo)
{
    int idx = blockIdx.x*256 + threadIdx.x;
    if (idx >= 512*288) return;
    int n = idx / 288, k = idx - n*288;
    float w = (k < 276) ? W_f1[(size_t)k*512 + n] : 0.f;
    unsigned short hi = f2bf(w);
    w1hi[idx] = hi;
    w1lo[idx] = f2bf(w - bf2f(hi));
}

// ---------------- K10 MFMA head: fc += (relu(fhB @ W1 + b_f1)) @ W_f2 ----------------
__global__ __launch_bounds__(256) void k10_mfma(
    const unsigned short* __restrict__ fhB, const unsigned short* __restrict__ w1hi,
    const unsigned short* __restrict__ w1lo, const float* __restrict__ b_f1,
    const float* __restrict__ W_f2, float* __restrict__ fc)
{
    __shared__ __align__(16) unsigned short lds[2][3][128*32];
    __shared__ float fcp[384];

    const int t = threadIdx.x;

    // XCD swizzle: contiguous sid chunk per XCD; 4 col-blocks of one row-stripe adjacent.
    int id = blockIdx.x + gridDim.x*blockIdx.y;          // gridDim = (4, 768), 3072 blocks
    int cpx = (4*768) >> 3;
    int sid = (id & 7)*cpx + (id >> 3);
    int bx = sid & 3, by = sid >> 2;

    const int lane = t & 63, wid = t >> 6;
    const int wr = wid >> 1, wc = wid & 1;
    const int l15 = lane & 15, l4 = lane >> 4;
    const int swq8 = (l4 ^ ((l15 >> 1) & 3))*8;
    const int pos0 = by*128, col0 = bx*128;

    for (int i = t; i < 384; i += 256) fcp[i] = 0.f;

    float4v acc[4][4];
#pragma unroll
    for (int i = 0; i < 4; i++)
#pragma unroll
        for (int j = 0; j < 4; j++) acc[i][j] = (float4v){0.f,0.f,0.f,0.f};

    const unsigned short* Ab = fhB  + (size_t)pos0*288;
    const unsigned short* Hb = w1hi + (size_t)col0*288;
    const unsigned short* Lb = w1lo + (size_t)col0*288;

    stage_tile(Ab, 288, lds[0][0], t);
    stage_tile(Hb, 288, lds[0][1], t);
    stage_tile(Lb, 288, lds[0][2], t);
    __syncthreads();

    for (int ks = 0; ks < 9; ks++) {
        int cur = ks & 1;
        if (ks + 1 < 9) {
            stage_tile(Ab + (ks+1)*32, 288, lds[cur^1][0], t);
            stage_tile(Hb + (ks+1)*32, 288, lds[cur^1][1], t);
            stage_tile(Lb + (ks+1)*32, 288, lds[cur^1][2], t);
        }
        short8v a[4], bh[4], bl[4];
#pragma unroll
        for (int f = 0; f < 4; f++) {
            a[f]  = *(const short8v*)&lds[cur][0][(wr*64 + f*16 + l15)*32 + swq8];
            bh[f] = *(const short8v*)&lds[cur][1][(wc*64 + f*16 + l15)*32 + swq8];
            bl[f] = *(const short8v*)&lds[cur][2][(wc*64 + f*16 + l15)*32 + swq8];
        }
#pragma unroll
        for (int i = 0; i < 4; i++)
#pragma unroll
            for (int j = 0; j < 4; j++) {
                acc[i][j] = __builtin_amdgcn_mfma_f32_16x16x32_bf16(a[i], bh[j], acc[i][j], 0, 0, 0);
                acc[i][j] = __builtin_amdgcn_mfma_f32_16x16x32_bf16(a[i], bl[j], acc[i][j], 0, 0, 0);
            }
        __syncthreads();
    }

    // epilogue: z = relu(acc + b_f1), pk = z @ W_f2 (per-lane), then LDS atomics
    float pk[4][4][3];
#pragma unroll
    for (int i = 0; i < 4; i++)
#pragma unroll
        for (int r = 0; r < 4; r++)
#pragma unroll
            for (int k = 0; k < 3; k++) pk[i][r][k] = 0.f;

#pragma unroll
    for (int j = 0; j < 4; j++) {
        int gc = col0 + wc*64 + j*16 + l15;
        float bias = b_f1[gc];
        float w20 = W_f2[gc*3+0], w21 = W_f2[gc*3+1], w22 = W_f2[gc*3+2];
#pragma unroll
        for (int i = 0; i < 4; i++)
#pragma unroll
            for (int r = 0; r < 4; r++) {
                float z = fmaxf(acc[i][j][r] + bias, 0.f);
                pk[i][r][0] += z*w20; pk[i][r][1] += z*w21; pk[i][r][2] += z*w22;
            }
    }
#pragma unroll
    for (int i = 0; i < 4; i++)
#pragma unroll
        for (int r = 0; r < 4; r++) {
            int rowL = wr*64 + i*16 + l4*4 + r;
            atomicAdd(&fcp[rowL*3 + 0], pk[i][r][0]);
            atomicAdd(&fcp[rowL*3 + 1], pk[i][r][1]);
            atomicAdd(&fcp[rowL*3 + 2], pk[i][r][2]);
        }
    __syncthreads();
    for (int i = t; i < 384; i += 256) {
        atomicAdd(&fc[(size_t)pos0*3 + i], fcp[i]);
    }
}

// ---------------- K11: e3 epilogue + transpose ----------------
__global__ void k11_e3(const float* __restrict__ fc, const float* __restrict__ b_f2,
                       const float* __restrict__ W_e3, const float* __restrict__ b_e3,
                       float* __restrict__ out)
{
    int idx = blockIdx.x*256 + threadIdx.x;
    if (idx >= BB*NN*12) return;
    int ok = idx % 12;
    int o = ok / 3, k = ok % 3;
    int bn = idx / 12;
    int n = bn & 1023, b = bn >> 10;
    float s = b_e3[o];
    float bk = b_f2[k];
#pragma unroll
    for (int c = 0; c < 12; c++)
        s += W_e3[o*12+c] * (fc[((size_t)(b*12+c)*NN + n)*3 + k] + bk);
    out[idx] = s;
}

extern "C" void kernel_launch(void* const* d_in, const int* in_sizes, int n_in,
                              void* d_out, int out_size, void* d_ws, size_t ws_size,
                              hipStream_t stream)
{
    const float* hd      = (const float*)d_in[0];
    const float* W_emb   = (const float*)d_in[1];
    const float* b_emb   = (const float*)d_in[2];
    const float* T_emb   = (const float*)d_in[3];
    const float* D_emb   = (const float*)d_in[4];
    const float* node_u  = (const float*)d_in[5];
    const float* node_d  = (const float*)d_in[6];
    const float* W_std   = (const float*)d_in[7];
    const float* b_std   = (const float*)d_in[8];
    const float* W_mlp   = (const float*)d_in[9];
    const float* b_mlp   = (const float*)d_in[10];
    const float* W_start = (const float*)d_in[11];
    const float* b_start = (const float*)d_in[12];
    const float* W_g     = (const float*)d_in[13];
    const float* W_rnn   = (const float*)d_in[14];
    const float* b_rnn   = (const float*)d_in[15];
    const float* W_e1    = (const float*)d_in[16];
    const float* b_e1    = (const float*)d_in[17];
    const float* W_e2    = (const float*)d_in[18];
    const float* b_e2    = (const float*)d_in[19];
    const float* Mm      = (const float*)d_in[20];
    const float* W_f1    = (const float*)d_in[21];
    const float* b_f1    = (const float*)d_in[22];
    const float* W_f2    = (const float*)d_in[23];
    const float* b_f2    = (const float*)d_in[24];
    const float* W_e3    = (const float*)d_in[25];
    const float* b_e3    = (const float*)d_in[26];

    float* ws      = (float*)d_ws;
    float* hist    = ws + OFF_HIST;
    float* h0      = ws + OFF_H0;
    float* s4      = ws + OFF_S4;
    float* ratio   = ws + OFF_RATIO;
    float* cent    = ws + OFF_CENT;
    float* m1      = ws + OFF_M1;
    float* m2      = ws + OFF_M2;
    int*   label   = (int*)(ws + OFF_LABEL);
    float* An      = ws + OFF_AN;
    unsigned short* AcombB = (unsigned short*)(ws + OFF_ACOMBB);
    float* x0      = ws + OFF_X0;
    float* hfin    = ws + OFF_HFIN;
    float* wcombo  = ws + OFF_WCOMBO;
    float* xoutb   = ws + OFF_XOUT;
    float* fc      = ws + OFF_FC;
    unsigned short* AnB   = (unsigned short*)(ws + OFF_ANB);
    unsigned short* AnBT  = (unsigned short*)(ws + OFF_ANBT);
    unsigned short* x0T   = (unsigned short*)(ws + OFF_X0T);
    unsigned short* w1hi  = (unsigned short*)(ws + OFF_W1HI);
    unsigned short* w1lo  = (unsigned short*)(ws + OFF_W1LO);
    unsigned short* fhB   = (unsigned short*)(ws + OFF_X0);   // overlays x0+hfin after k9

    k1_embed<<<(BB*LL*NN)/256, 256, 0, stream>>>(hd, W_emb, b_emb, T_emb, D_emb, node_u,
                                                 W_std, b_std, W_mlp, b_mlp, hist, h0, s4);
    k2_ratio<<<(BB*NN)/256, 256, 0, stream>>>(s4, ratio);
    k3_centers<<<BB, 256, 0, stream>>>(ratio, cent);
    k4_labels<<<NN/256, 256, 0, stream>>>(ratio, cent, node_u, node_d, label, m1, m2);
    k5_A<<<NN, 256, 0, stream>>>(m1, m2, label, An);
    kt_transpose<true><<<dim3(16, 16), 256, 0, stream>>>(An, AnBT, AnB, 1024, 1024);
    gemm_mfma<0><<<dim3(8, 8), 256, 0, stream>>>(AnB, AnBT, AcombB, 1024, 1024);
    k7_x0<<<BB*NN, 256, 0, stream>>>(hist, W_start, b_start, x0);
    kt_transpose<false><<<dim3(128, 16), 256, 0, stream>>>(x0, x0T, (unsigned short*)0, 1024, 8192);
    gemm_mfma<1><<<dim3(64, 8), 256, 0, stream>>>(AcombB, x0T, hfin, 8192, 1024);
    kw_combo<<<1, 128, 0, stream>>>(W_g, W_rnn, wcombo);
    k9_rnn2<<<BB*NN, 256, 0, stream>>>(hfin, wcombo, b_rnn, W_e1, b_e1, W_e2, b_e2, Mm, xoutb);
    kp_fh<<<(BB*LL*NN)/128, 256, 0, stream>>>(xoutb, hist, h0, hd, T_emb, D_emb, fhB);
    kt_w1<<<(512*288)/256, 256, 0, stream>>>(W_f1, w1hi, w1lo);
    hipMemsetAsync(fc, 0, (size_t)BB*LL*NN*3*sizeof(float), stream);
    k10_mfma<<<dim3(4, 768), 256, 0, stream>>>(fhB, w1hi, w1lo, b_f1, W_f2, fc);
    k11_e3<<<(BB*NN*12)/256, 256, 0, stream>>>(fc, b_f2, W_e3, b_e3, (float*)d_out);
}

// Round 5
// 830.585 us; speedup vs baseline: 2.5953x; 1.0254x over previous
//
#include <hip/hip_runtime.h>
#include <math.h>

#define BB 8
#define LL 12
#define NN 1024
#define FF 3
#define HH 32
#define NDD 10
#define TTT 10
#define PP 3
#define DOUTT 128
constexpr float kALPHA = 3.0f;

typedef __attribute__((ext_vector_type(8))) short short8v;   // 8 bf16 (4 VGPR)
typedef __attribute__((ext_vector_type(4))) float float4v;

__device__ __forceinline__ unsigned short f2bf(float x) {
    union { float f; unsigned u; } v; v.f = x;
    unsigned r = v.u + 0x7FFF + ((v.u >> 16) & 1);
    return (unsigned short)(r >> 16);
}
__device__ __forceinline__ float bf2f(unsigned short u) {
    union { unsigned u; float f; } v; v.u = ((unsigned)u) << 16;
    return v.f;
}

// async global->LDS, 16B per lane. LDS dest = wave-uniform base + lane*16.
__device__ __forceinline__ void gload_lds16(const unsigned short* g, unsigned short* l) {
    __builtin_amdgcn_global_load_lds(
        (const __attribute__((address_space(1))) void*)g,
        (__attribute__((address_space(3))) void*)l,
        16, 0, 0);
}

// Stage a 128x32 bf16 tile (row-major, row stride = `stride` elems) into LDS,
// XOR-swizzled: LDS chunk (row, ql) holds global chunk (row, ql ^ ((row>>1)&3)).
__device__ __forceinline__ void stage_tile(const unsigned short* __restrict__ g, int stride,
                                           unsigned short* tile, int tid) {
#pragma unroll
    for (int rr = 0; rr < 2; rr++) {
        int c = rr*256 + tid;
        int row = c >> 2;
        int q = (c & 3) ^ ((row >> 1) & 3);
        gload_lds16(g + (size_t)row*stride + q*8,
                    tile + ((size_t)(rr*256 + (tid & 192)))*8);
    }
}

// ---------------- workspace layout (floats) ----------------
constexpr size_t OFF_HIST   = 0;                                         // B*L*N*32
constexpr size_t OFF_H0     = OFF_HIST  + (size_t)BB*LL*NN*HH;           // B*L*N*96
constexpr size_t OFF_S4     = OFF_H0    + (size_t)BB*LL*NN*3*HH;         // B*L*N*4
constexpr size_t OFF_RATIO  = OFF_S4    + (size_t)BB*LL*NN*4;            // B*N*3
constexpr size_t OFF_CENT   = OFF_RATIO + (size_t)BB*NN*3;               // 32
constexpr size_t OFF_M1     = OFF_CENT  + 32;                            // N*10
constexpr size_t OFF_M2     = OFF_M1    + (size_t)NN*NDD;                // N*10
constexpr size_t OFF_LABEL  = OFF_M2    + (size_t)NN*NDD;                // N ints
constexpr size_t OFF_AN     = OFF_LABEL + NN;                            // N*N fp32
constexpr size_t OFF_ACOMBB = OFF_AN    + (size_t)NN*NN;                 // N*N bf16
constexpr size_t OFF_X0     = OFF_ACOMBB+ (size_t)NN*NN;                 // N*8192 fp32 (later fhB overlay)
constexpr size_t OFF_HFIN   = OFF_X0    + (size_t)NN*BB*HH*HH;           // N*8192 fp32
constexpr size_t OFF_WCOMBO = OFF_HFIN  + (size_t)NN*BB*HH*HH;           // 32*128
constexpr size_t OFF_XOUT   = OFF_WCOMBO+ (size_t)HH*DOUTT;              // B*12*N*128 (bf16 now)
constexpr size_t OFF_FC     = OFF_XOUT  + (size_t)BB*LL*NN*DOUTT;        // B*12*N*3
constexpr size_t OFF_ANB    = OFF_FC    + (size_t)BB*LL*NN*3;            // 1024*1024 bf16
constexpr size_t OFF_ANBT   = OFF_ANB   + (size_t)NN*NN/2;               // 1024*1024 bf16
constexpr size_t OFF_X0T    = OFF_ANBT  + (size_t)NN*NN/2;               // 8192*1024 bf16
constexpr size_t OFF_W1HI   = OFF_X0T   + (size_t)BB*HH*HH*NN/2;         // 512*288 bf16
constexpr size_t OFF_W1LO   = OFF_W1HI  + (size_t)512*288/2;
constexpr size_t WS_FLOATS  = OFF_W1LO  + (size_t)512*288/2;             // ~201 MB

// ---------------- K1: embed + std decomposition ----------------
__global__ __launch_bounds__(256) void k1_embed(
    const float* __restrict__ hd, const float* __restrict__ W_emb, const float* __restrict__ b_emb,
    const float* __restrict__ T_emb, const float* __restrict__ D_emb, const float* __restrict__ node_u,
    const float* __restrict__ W_std, const float* __restrict__ b_std,
    const float* __restrict__ W_mlp, const float* __restrict__ b_mlp,
    float* __restrict__ hist, float* __restrict__ h0, float* __restrict__ s4)
{
    __shared__ float sW[2*62*32];
    for (int i = threadIdx.x; i < 2*62*32; i += 256) sW[i] = W_std[i];
    __syncthreads();

    int pos = blockIdx.x*256 + threadIdx.x;
    int n = pos & (NN-1);
    const float* hp = hd + (size_t)pos*5;
    float f0 = hp[0], f1 = hp[1], f2 = hp[2];
    int ti = (int)(hp[3]*288.0f);
    int di = (int)hp[4];

    float tv[10], dv[10], nu[10];
#pragma unroll
    for (int t = 0; t < 10; t++) {
        tv[t] = T_emb[ti*10+t]; dv[t] = D_emb[di*10+t]; nu[t] = node_u[n*10+t];
    }
    float h[32];
#pragma unroll
    for (int j = 0; j < 32; j++) h[j] = b_emb[j] + f0*W_emb[j] + f1*W_emb[32+j] + f2*W_emb[64+j];

    float a0[32], a1[32];
#pragma unroll
    for (int j = 0; j < 32; j++) { a0[j] = b_std[j]; a1[j] = b_std[32+j]; }

    auto accum = [&](float v, int i) {
#pragma unroll
        for (int q = 0; q < 8; q++) {
            float4 w0 = *(const float4*)&sW[i*32 + q*4];
            float4 w1 = *(const float4*)&sW[(62+i)*32 + q*4];
            a0[q*4+0] += v*w0.x; a0[q*4+1] += v*w0.y; a0[q*4+2] += v*w0.z; a0[q*4+3] += v*w0.w;
            a1[q*4+0] += v*w1.x; a1[q*4+1] += v*w1.y; a1[q*4+2] += v*w1.z; a1[q*4+3] += v*w1.w;
        }
    };
#pragma unroll
    for (int i = 0; i < 32; i++) accum(h[i], i);
#pragma unroll
    for (int i = 0; i < 10; i++) accum(nu[i], 32+i);
#pragma unroll
    for (int i = 0; i < 10; i++) accum(tv[i], 42+i);
#pragma unroll
    for (int i = 0; i < 10; i++) accum(dv[i], 52+i);

    float x0v[32], x1v[32], rv[32];
    float s0 = b_mlp[0], s1 = b_mlp[1], s2 = b_mlp[2], s3 = b_mlp[3];
#pragma unroll
    for (int j = 0; j < 32; j++) {
        float sg0 = 1.f/(1.f + __expf(-a0[j]));
        float sg1 = 1.f/(1.f + __expf(-a1[j]));
        x0v[j] = sg0*h[j]; x1v[j] = sg1*h[j]; rv[j] = h[j] - x0v[j] - x1v[j];
        s0 += h[j]  * W_mlp[j];
        s1 += x0v[j]* W_mlp[32+j];
        s2 += x1v[j]* W_mlp[64+j];
        s3 += rv[j] * W_mlp[96+j];
    }
    float* ho = hist + (size_t)pos*32;
    float* hz = h0   + (size_t)pos*96;
#pragma unroll
    for (int q = 0; q < 8; q++) {
        *(float4*)&ho[q*4]    = make_float4(h[q*4],   h[q*4+1],   h[q*4+2],   h[q*4+3]);
        *(float4*)&hz[q*4]    = make_float4(x0v[q*4], x0v[q*4+1], x0v[q*4+2], x0v[q*4+3]);
        *(float4*)&hz[32+q*4] = make_float4(x1v[q*4], x1v[q*4+1], x1v[q*4+2], x1v[q*4+3]);
        *(float4*)&hz[64+q*4] = make_float4(rv[q*4],  rv[q*4+1],  rv[q*4+2],  rv[q*4+3]);
    }
    *(float4*)&s4[(size_t)pos*4] = make_float4(s0, s1, s2, s3);
}

// ---------------- K2: ratios ----------------
__global__ void k2_ratio(const float* __restrict__ s4, float* __restrict__ ratio)
{
    int bn = blockIdx.x*256 + threadIdx.x;
    if (bn >= BB*NN) return;
    int b = bn >> 10, n = bn & 1023;
    float a0=0, a1=0, a2=0, a3=0;
    for (int l = 0; l < 12; l++) {
        const float* sp = s4 + ((size_t)(b*12+l)*NN + n)*4;
        a0 += sp[0]; a1 += sp[1]; a2 += sp[2]; a3 += sp[3];
    }
    float hm = a0/12.f;
    float* rp = ratio + (size_t)bn*3;
    rp[0] = (a1/12.f)/(hm + 1e-6f);
    rp[1] = (a2/12.f)/(hm + 1e-6f);
    rp[2] = (a3/12.f)/(hm + 1e-6f);
}

// ---------------- K3: per-b centers ----------------
__global__ __launch_bounds__(256) void k3_centers(const float* __restrict__ ratio, float* __restrict__ centers)
{
    int b = blockIdx.x;
    float m0=-3.4e38f, m1v=-3.4e38f, m2v=-3.4e38f;
    for (int n = threadIdx.x; n < NN; n += 256) {
        const float* rp = ratio + ((size_t)b*NN + n)*3;
        m0 = fmaxf(m0, rp[0]); m1v = fmaxf(m1v, rp[1]); m2v = fmaxf(m2v, rp[2]);
    }
#pragma unroll
    for (int off = 32; off > 0; off >>= 1) {
        m0  = fmaxf(m0,  __shfl_down(m0,  off));
        m1v = fmaxf(m1v, __shfl_down(m1v, off));
        m2v = fmaxf(m2v, __shfl_down(m2v, off));
    }
    __shared__ float red[4][3];
    int wid = threadIdx.x >> 6, lane = threadIdx.x & 63;
    if (lane == 0) { red[wid][0]=m0; red[wid][1]=m1v; red[wid][2]=m2v; }
    __syncthreads();
    if (threadIdx.x == 0) {
        centers[b*3+0] = fmaxf(fmaxf(red[0][0],red[1][0]), fmaxf(red[2][0],red[3][0]));
        centers[b*3+1] = fmaxf(fmaxf(red[0][1],red[1][1]), fmaxf(red[2][1],red[3][1]));
        centers[b*3+2] = fmaxf(fmaxf(red[0][2],red[1][2]), fmaxf(red[2][2],red[3][2]));
    }
}

// ---------------- K4: labels + m1/m2 ----------------
__global__ void k4_labels(const float* __restrict__ ratio, const float* __restrict__ centers,
                          const float* __restrict__ node_u, const float* __restrict__ node_d,
                          int* __restrict__ label, float* __restrict__ m1, float* __restrict__ m2)
{
    int n = blockIdx.x*256 + threadIdx.x;
    if (n >= NN) return;
    int c0=0, c1=0, c2=0;
    for (int b = 0; b < BB; b++) {
        const float* rp = ratio + ((size_t)b*NN + n)*3;
        const float* cp = centers + b*3;
        float d0 = fabsf(rp[0]-cp[0]), d1 = fabsf(rp[1]-cp[1]), d2 = fabsf(rp[2]-cp[2]);
        int a = 0; float best = d0;
        if (d1 < best) { best = d1; a = 1; }
        if (d2 < best) { best = d2; a = 2; }
        if (a == 0) c0++; else if (a == 1) c1++; else c2++;
    }
    int lab = 0, bc = c0;
    if (c1 > bc) { bc = c1; lab = 1; }
    if (c2 > bc) { bc = c2; lab = 2; }
    label[n] = lab;
#pragma unroll
    for (int d = 0; d < 10; d++) {
        m1[n*10+d] = tanhf(kALPHA*node_u[n*10+d]);
        m2[n*10+d] = tanhf(kALPHA*node_d[n*10+d]);
    }
}

// ---------------- K5: An ----------------
__global__ __launch_bounds__(256) void k5_A(const float* __restrict__ m1, const float* __restrict__ m2,
                                            const int* __restrict__ label, float* __restrict__ An)
{
    int n = blockIdx.x;
    __shared__ float row[1024];
    __shared__ float m1n[10], m2n[10];
    __shared__ float ssum[4];
    int t = threadIdx.x;
    if (t < 10) { m1n[t] = m1[n*10+t]; m2n[t] = m2[n*10+t]; }
    __syncthreads();
    int labn = label[n];
    float lsum = 0.f;
    for (int m = t; m < 1024; m += 256) {
        float a = 0.f;
        if (label[m] == labn) {
            float x = 0.f;
#pragma unroll
            for (int d = 0; d < 10; d++) x += m1n[d]*m2[m*10+d] - m2n[d]*m1[m*10+d];
            a = fmaxf(tanhf(3.f*x), 0.f);
        }
        row[m] = a; lsum += a;
    }
#pragma unroll
    for (int off = 32; off > 0; off >>= 1) lsum += __shfl_down(lsum, off);
    int wid = t >> 6, lane = t & 63;
    if (lane == 0) ssum[wid] = lsum;
    __syncthreads();
    float inv = 1.f/((ssum[0]+ssum[1]+ssum[2]+ssum[3]) + 1e-6f);
    for (int m = t; m < 1024; m += 256) An[(size_t)n*1024 + m] = row[m]*inv;
}

// ---------------- transpose fp32 [R][C] -> bf16 outT[C][R] ----------------
template<bool ALSO_DIRECT>
__global__ __launch_bounds__(256) void kt_transpose(const float* __restrict__ in,
                                                    unsigned short* __restrict__ outT,
                                                    unsigned short* __restrict__ outD,
                                                    int R, int C)
{
    __shared__ float tile[64][65];
    int c0 = blockIdx.x*64, r0 = blockIdx.y*64;
    for (int i = threadIdx.x; i < 64*64; i += 256) {
        int r = i >> 6, c = i & 63;
        float v = in[(size_t)(r0+r)*C + c0+c];
        tile[r][c] = v;
        if (ALSO_DIRECT) outD[(size_t)(r0+r)*C + c0+c] = f2bf(v);
    }
    __syncthreads();
    for (int i = threadIdx.x; i < 64*64; i += 256) {
        int c = i >> 6, r = i & 63;
        outT[(size_t)(c0+c)*R + r0+r] = f2bf(tile[r][c]);
    }
}

// ---------------- bf16 MFMA GEMM, 128x128 tile, 2-phase pipelined, swizzled gload_lds ----------------
template<int MODE>
__global__ __launch_bounds__(256) void gemm_mfma(
    const unsigned short* __restrict__ A, const unsigned short* __restrict__ B,
    void* __restrict__ Cout, int Nout, int K)
{
    __shared__ __align__(16) unsigned short lds[2][2][128*32];
    const int t = threadIdx.x;

    int id = blockIdx.x + gridDim.x*blockIdx.y;
    int gx8 = gridDim.x >> 3;
    int xcd = id & 7, local = id >> 3;
    int bx = xcd*gx8 + (local % gx8);
    int by = local / gx8;

    const int lane = t & 63, wid = t >> 6;
    const int wr = wid >> 1, wc = wid & 1;
    const int l15 = lane & 15, l4 = lane >> 4;
    const int swq8 = (l4 ^ ((l15 >> 1) & 3))*8;
    const int row0 = by*128, col0 = bx*128;

    float4v acc[4][4];
#pragma unroll
    for (int i = 0; i < 4; i++)
#pragma unroll
        for (int j = 0; j < 4; j++) acc[i][j] = (float4v){0.f,0.f,0.f,0.f};

    const unsigned short* Ab = A + (size_t)row0*K;
    const unsigned short* Bb = B + (size_t)col0*K;

    stage_tile(Ab, K, lds[0][0], t);
    stage_tile(Bb, K, lds[0][1], t);
    __syncthreads();

    const int nk = K >> 5;
    for (int ks = 0; ks < nk; ks++) {
        int cur = ks & 1;
        if (ks + 1 < nk) {
            stage_tile(Ab + (ks+1)*32, K, lds[cur^1][0], t);
            stage_tile(Bb + (ks+1)*32, K, lds[cur^1][1], t);
        }
        short8v a[4], b[4];
#pragma unroll
        for (int f = 0; f < 4; f++) {
            a[f] = *(const short8v*)&lds[cur][0][(wr*64 + f*16 + l15)*32 + swq8];
            b[f] = *(const short8v*)&lds[cur][1][(wc*64 + f*16 + l15)*32 + swq8];
        }
#pragma unroll
        for (int i = 0; i < 4; i++)
#pragma unroll
            for (int j = 0; j < 4; j++)
                acc[i][j] = __builtin_amdgcn_mfma_f32_16x16x32_bf16(a[i], b[j], acc[i][j], 0, 0, 0);
        __syncthreads();
    }

#pragma unroll
    for (int i = 0; i < 4; i++) {
#pragma unroll
        for (int j = 0; j < 4; j++) {
            int gc = col0 + wc*64 + j*16 + l15;
#pragma unroll
            for (int r = 0; r < 4; r++) {
                int gr = row0 + wr*64 + i*16 + l4*4 + r;
                if (MODE == 0) {
                    float an = bf2f(A[(size_t)gr*K + gc]);
                    float v = 0.9025f*acc[i][j][r] + 0.0475f*an + ((gr==gc) ? 0.05f : 0.f);
                    ((unsigned short*)Cout)[(size_t)gr*Nout + gc] = f2bf(v);
                } else {
                    ((float*)Cout)[(size_t)gr*Nout + gc] = acc[i][j][r];
                }
            }
        }
    }
}

// ---------------- K7: x0[n, b*1024 + c*32 + h] ----------------
__global__ __launch_bounds__(256) void k7_x0(const float* __restrict__ hist,
                                             const float* __restrict__ W_start, const float* __restrict__ b_start,
                                             float* __restrict__ x0)
{
    int bid = blockIdx.x; int n = bid & (NN-1), b = bid >> 10;
    __shared__ float hl[384];
    __shared__ float sw[384];
    int t = threadIdx.x;
    for (int idx = t; idx < 384; idx += 256) {
        int l = idx >> 5, hh = idx & 31;
        hl[idx] = hist[((size_t)(b*12+l)*NN + n)*32 + hh];
    }
    for (int idx = t; idx < 384; idx += 256) sw[idx] = W_start[idx];
    __syncthreads();
    int c = t >> 3, h4 = (t & 7)*4;
    float bs = b_start[c];
    float o0 = bs, o1 = bs, o2 = bs, o3 = bs;
#pragma unroll
    for (int l = 0; l < 12; l++) {
        float w = sw[c*12+l];
        o0 += w*hl[l*32+h4];   o1 += w*hl[l*32+h4+1];
        o2 += w*hl[l*32+h4+2]; o3 += w*hl[l*32+h4+3];
    }
    *(float4*)&x0[(size_t)n*8192 + b*1024 + c*32 + h4] = make_float4(o0, o1, o2, o3);
}

// ---------------- Kw: Wcombo ----------------
__global__ void kw_combo(const float* __restrict__ W_g, const float* __restrict__ W_rnn, float* __restrict__ wcombo)
{
    int j = threadIdx.x;
    for (int hh = 0; hh < 32; hh++) {
        float s = 0.f;
        for (int k = 0; k < 32; k++) s += (W_g[hh*32+k] + W_g[1024 + hh*32+k]) * W_rnn[k*128 + j];
        wcombo[hh*128 + j] = s;
    }
}

// ---------------- K9 v3: higher reg budget; bf16 relu'd output ----------------
__global__ __launch_bounds__(256, 2) void k9_rnn2(
    const float* __restrict__ hfin, const float* __restrict__ wcombo,
    const float* __restrict__ b_rnn, const float* __restrict__ W_e1,
    const float* __restrict__ b_e1, const float* __restrict__ W_e2,
    const float* __restrict__ b_e2, const float* __restrict__ Mm,
    unsigned short* __restrict__ xoutB)
{
    __shared__ float sXr[32*128];
    __shared__ float sH[1024];
    __shared__ float sWbuf[4096 + 2048];
    __shared__ float sV[12*128];
    __shared__ float sBe1[128];

    const int bid = blockIdx.x;
    const int n = bid & (NN-1), b = bid >> 10;
    const int t = threadIdx.x;
    const int j2 = t & 63;
    const int og = t >> 6;
    const int j0 = j2, j1 = j2 + 64;

    for (int i = t; i < 4096; i += 256) sWbuf[i] = wcombo[i];
    for (int i = t; i < 1024; i += 256) sH[i] = hfin[(size_t)n*8192 + (size_t)b*1024 + i];
    for (int i = t; i < 1536; i += 256) sV[i] = 0.f;
    if (t < 128) sBe1[t] = b_e1[t];
    __syncthreads();

    float wc0[32], wc1[32];
#pragma unroll
    for (int h = 0; h < 32; h++) { wc0[h] = sWbuf[h*128 + j0]; wc1[h] = sWbuf[h*128 + j1]; }
    float br0 = b_rnn[j0], br1 = b_rnn[j1];
#pragma unroll
    for (int ci = 0; ci < 8; ci++) {
        int c = og*8 + ci;
        float u0 = br0, u1 = br1;
#pragma unroll
        for (int q = 0; q < 8; q++) {
            float4 hv = *(const float4*)&sH[c*32 + q*4];
            u0 += hv.x*wc0[q*4+0] + hv.y*wc0[q*4+1] + hv.z*wc0[q*4+2] + hv.w*wc0[q*4+3];
            u1 += hv.x*wc1[q*4+0] + hv.y*wc1[q*4+1] + hv.z*wc1[q*4+2] + hv.w*wc1[q*4+3];
        }
        sXr[c*128 + j0] = tanhf(u0);
        sXr[c*128 + j1] = tanhf(u1);
    }
    __syncthreads();

    for (int i = t; i < 4096; i += 256) sWbuf[i] = W_e1[i];
    for (int i = t; i < 2048; i += 256) {
        int o1 = i >> 4, o2 = i & 15;
        sWbuf[4096 + i] = (o2 < 12) ? W_e2[o2*128 + o1] : 0.f;
    }
    __syncthreads();

    float xr0[32], xr1[32];
#pragma unroll
    for (int c = 0; c < 32; c++) { xr0[c] = sXr[c*128 + j0]; xr1[c] = sXr[c*128 + j1]; }
    float v0[12], v1[12];
#pragma unroll
    for (int o2 = 0; o2 < 12; o2++) { v0[o2] = 0.f; v1[o2] = 0.f; }

#pragma unroll 4
    for (int oi = 0; oi < 32; oi++) {
        int o1 = og*32 + oi;
        float u0 = sBe1[o1], u1 = sBe1[o1];
#pragma unroll
        for (int q = 0; q < 8; q++) {
            float4 w = *(const float4*)&sWbuf[o1*32 + q*4];
            u0 += w.x*xr0[q*4+0] + w.y*xr0[q*4+1] + w.z*xr0[q*4+2] + w.w*xr0[q*4+3];
            u1 += w.x*xr1[q*4+0] + w.y*xr1[q*4+1] + w.z*xr1[q*4+2] + w.w*xr1[q*4+3];
        }
        u0 = fmaxf(u0, 0.f); u1 = fmaxf(u1, 0.f);
#pragma unroll
        for (int q = 0; q < 3; q++) {
            float4 w2 = *(const float4*)&sWbuf[4096 + o1*16 + q*4];
            v0[q*4+0] += w2.x*u0; v0[q*4+1] += w2.y*u0; v0[q*4+2] += w2.z*u0; v0[q*4+3] += w2.w*u0;
            v1[q*4+0] += w2.x*u1; v1[q*4+1] += w2.y*u1; v1[q*4+2] += w2.z*u1; v1[q*4+3] += w2.w*u1;
        }
    }

#pragma unroll
    for (int g = 0; g < 4; g++) {
        if (og == g) {
#pragma unroll
            for (int o2 = 0; o2 < 12; o2++) {
                sV[o2*128 + j0] += v0[o2];
                sV[o2*128 + j1] += v1[o2];
            }
        }
        __syncthreads();
    }

    // epilogue: add b_e2, apply M, relu-fold, bf16 store (consumed by kp_fh/k10 as relu(fh) cols 0..127)
    for (int i = t; i < 1536; i += 256) {
        int o2 = i >> 7, j = i & 127;
        float val = (sV[i] + b_e2[o2]) * Mm[n*128 + j];
        xoutB[((size_t)(b*12 + o2)*NN + n)*128 + j] = f2bf(fmaxf(val, 0.f));
    }
}

// ---------------- kp_fh: build relu(fh) bf16 [98304][288] ----------------
__global__ __launch_bounds__(256) void kp_fh(
    const unsigned short* __restrict__ xoutB, const float* __restrict__ hist, const float* __restrict__ h0,
    const float* __restrict__ hd, const float* __restrict__ T_emb, const float* __restrict__ D_emb,
    unsigned short* __restrict__ fhB)
{
    int pos_base = blockIdx.x * 128;
    for (int idx = threadIdx.x; idx < 128*288; idx += 256) {
        int r = idx / 288, k = idx - r*288;
        int pos = pos_base + r;
        if (k < 128) {
            fhB[(size_t)pos*288 + k] = xoutB[(size_t)pos*128 + k];   // already relu'd bf16
            continue;
        }
        float v = 0.f;
        if (k < 160)       v = hist[(size_t)pos*32 + (k-128)];
        else if (k < 256)  v = h0[(size_t)pos*96 + (k-160)];
        else if (k < 266) { int ti = (int)(hd[(size_t)pos*5+3]*288.0f); v = T_emb[ti*10 + (k-256)]; }
        else if (k < 276) { int di = (int)hd[(size_t)pos*5+4];          v = D_emb[di*10 + (k-266)]; }
        fhB[(size_t)pos*288 + k] = f2bf(fmaxf(v, 0.f));
    }
}

// ---------------- kt_w1: W_f1 -> hi/lo bf16 [512][288] (n-major) ----------------
__global__ void kt_w1(const float* __restrict__ W_f1, unsigned short* __restrict__ w1hi,
                      unsigned short* __restrict__ w1lo)
{
    int idx = blockIdx.x*256 + threadIdx.x;
    if (idx >= 512*288) return;
    int n = idx / 288, k = idx - n*288;
    float w = (k < 276) ? W_f1[(size_t)k*512 + n] : 0.f;
    unsigned short hi = f2bf(w);
    w1hi[idx] = hi;
    w1lo[idx] = f2bf(w - bf2f(hi));
}

// ---------------- K10 MFMA head ----------------
__global__ __launch_bounds__(256) void k10_mfma(
    const unsigned short* __restrict__ fhB, const unsigned short* __restrict__ w1hi,
    const unsigned short* __restrict__ w1lo, const float* __restrict__ b_f1,
    const float* __restrict__ W_f2, float* __restrict__ fc)
{
    __shared__ __align__(16) unsigned short lds[2][3][128*32];
    __shared__ float fcp[384];

    const int t = threadIdx.x;

    int id = blockIdx.x + gridDim.x*blockIdx.y;          // gridDim = (4, 768)
    int cpx = (4*768) >> 3;
    int sid = (id & 7)*cpx + (id >> 3);
    int bx = sid & 3, by = sid >> 2;

    const int lane = t & 63, wid = t >> 6;
    const int wr = wid >> 1, wc = wid & 1;
    const int l15 = lane & 15, l4 = lane >> 4;
    const int swq8 = (l4 ^ ((l15 >> 1) & 3))*8;
    const int pos0 = by*128, col0 = bx*128;

    for (int i = t; i < 384; i += 256) fcp[i] = 0.f;

    float4v acc[4][4];
#pragma unroll
    for (int i = 0; i < 4; i++)
#pragma unroll
        for (int j = 0; j < 4; j++) acc[i][j] = (float4v){0.f,0.f,0.f,0.f};

    const unsigned short* Ab = fhB  + (size_t)pos0*288;
    const unsigned short* Hb = w1hi + (size_t)col0*288;
    const unsigned short* Lb = w1lo + (size_t)col0*288;

    stage_tile(Ab, 288, lds[0][0], t);
    stage_tile(Hb, 288, lds[0][1], t);
    stage_tile(Lb, 288, lds[0][2], t);
    __syncthreads();

    for (int ks = 0; ks < 9; ks++) {
        int cur = ks & 1;
        if (ks + 1 < 9) {
            stage_tile(Ab + (ks+1)*32, 288, lds[cur^1][0], t);
            stage_tile(Hb + (ks+1)*32, 288, lds[cur^1][1], t);
            stage_tile(Lb + (ks+1)*32, 288, lds[cur^1][2], t);
        }
        short8v a[4], bh[4], bl[4];
#pragma unroll
        for (int f = 0; f < 4; f++) {
            a[f]  = *(const short8v*)&lds[cur][0][(wr*64 + f*16 + l15)*32 + swq8];
            bh[f] = *(const short8v*)&lds[cur][1][(wc*64 + f*16 + l15)*32 + swq8];
            bl[f] = *(const short8v*)&lds[cur][2][(wc*64 + f*16 + l15)*32 + swq8];
        }
#pragma unroll
        for (int i = 0; i < 4; i++)
#pragma unroll
            for (int j = 0; j < 4; j++) {
                acc[i][j] = __builtin_amdgcn_mfma_f32_16x16x32_bf16(a[i], bh[j], acc[i][j], 0, 0, 0);
                acc[i][j] = __builtin_amdgcn_mfma_f32_16x16x32_bf16(a[i], bl[j], acc[i][j], 0, 0, 0);
            }
        __syncthreads();
    }

    float pk[4][4][3];
#pragma unroll
    for (int i = 0; i < 4; i++)
#pragma unroll
        for (int r = 0; r < 4; r++)
#pragma unroll
            for (int k = 0; k < 3; k++) pk[i][r][k] = 0.f;

#pragma unroll
    for (int j = 0; j < 4; j++) {
        int gc = col0 + wc*64 + j*16 + l15;
        float bias = b_f1[gc];
        float w20 = W_f2[gc*3+0], w21 = W_f2[gc*3+1], w22 = W_f2[gc*3+2];
#pragma unroll
        for (int i = 0; i < 4; i++)
#pragma unroll
            for (int r = 0; r < 4; r++) {
                float z = fmaxf(acc[i][j][r] + bias, 0.f);
                pk[i][r][0] += z*w20; pk[i][r][1] += z*w21; pk[i][r][2] += z*w22;
            }
    }
#pragma unroll
    for (int i = 0; i < 4; i++)
#pragma unroll
        for (int r = 0; r < 4; r++) {
            int rowL = wr*64 + i*16 + l4*4 + r;
            atomicAdd(&fcp[rowL*3 + 0], pk[i][r][0]);
            atomicAdd(&fcp[rowL*3 + 1], pk[i][r][1]);
            atomicAdd(&fcp[rowL*3 + 2], pk[i][r][2]);
        }
    __syncthreads();
    for (int i = t; i < 384; i += 256) {
        atomicAdd(&fc[(size_t)pos0*3 + i], fcp[i]);
    }
}

// ---------------- K11: e3 epilogue + transpose ----------------
__global__ void k11_e3(const float* __restrict__ fc, const float* __restrict__ b_f2,
                       const float* __restrict__ W_e3, const float* __restrict__ b_e3,
                       float* __restrict__ out)
{
    int idx = blockIdx.x*256 + threadIdx.x;
    if (idx >= BB*NN*12) return;
    int ok = idx % 12;
    int o = ok / 3, k = ok % 3;
    int bn = idx / 12;
    int n = bn & 1023, b = bn >> 10;
    float s = b_e3[o];
    float bk = b_f2[k];
#pragma unroll
    for (int c = 0; c < 12; c++)
        s += W_e3[o*12+c] * (fc[((size_t)(b*12+c)*NN + n)*3 + k] + bk);
    out[idx] = s;
}

extern "C" void kernel_launch(void* const* d_in, const int* in_sizes, int n_in,
                              void* d_out, int out_size, void* d_ws, size_t ws_size,
                              hipStream_t stream)
{
    const float* hd      = (const float*)d_in[0];
    const float* W_emb   = (const float*)d_in[1];
    const float* b_emb   = (const float*)d_in[2];
    const float* T_emb   = (const float*)d_in[3];
    const float* D_emb   = (const float*)d_in[4];
    const float* node_u  = (const float*)d_in[5];
    const float* node_d  = (const float*)d_in[6];
    const float* W_std   = (const float*)d_in[7];
    const float* b_std   = (const float*)d_in[8];
    const float* W_mlp   = (const float*)d_in[9];
    const float* b_mlp   = (const float*)d_in[10];
    const float* W_start = (const float*)d_in[11];
    const float* b_start = (const float*)d_in[12];
    const float* W_g     = (const float*)d_in[13];
    const float* W_rnn   = (const float*)d_in[14];
    const float* b_rnn   = (const float*)d_in[15];
    const float* W_e1    = (const float*)d_in[16];
    const float* b_e1    = (const float*)d_in[17];
    const float* W_e2    = (const float*)d_in[18];
    const float* b_e2    = (const float*)d_in[19];
    const float* Mm      = (const float*)d_in[20];
    const float* W_f1    = (const float*)d_in[21];
    const float* b_f1    = (const float*)d_in[22];
    const float* W_f2    = (const float*)d_in[23];
    const float* b_f2    = (const float*)d_in[24];
    const float* W_e3    = (const float*)d_in[25];
    const float* b_e3    = (const float*)d_in[26];

    float* ws      = (float*)d_ws;
    float* hist    = ws + OFF_HIST;
    float* h0      = ws + OFF_H0;
    float* s4      = ws + OFF_S4;
    float* ratio   = ws + OFF_RATIO;
    float* cent    = ws + OFF_CENT;
    float* m1      = ws + OFF_M1;
    float* m2      = ws + OFF_M2;
    int*   label   = (int*)(ws + OFF_LABEL);
    float* An      = ws + OFF_AN;
    unsigned short* AcombB = (unsigned short*)(ws + OFF_ACOMBB);
    float* x0      = ws + OFF_X0;
    float* hfin    = ws + OFF_HFIN;
    float* wcombo  = ws + OFF_WCOMBO;
    unsigned short* xoutB = (unsigned short*)(ws + OFF_XOUT);
    float* fc      = ws + OFF_FC;
    unsigned short* AnB   = (unsigned short*)(ws + OFF_ANB);
    unsigned short* AnBT  = (unsigned short*)(ws + OFF_ANBT);
    unsigned short* x0T   = (unsigned short*)(ws + OFF_X0T);
    unsigned short* w1hi  = (unsigned short*)(ws + OFF_W1HI);
    unsigned short* w1lo  = (unsigned short*)(ws + OFF_W1LO);
    unsigned short* fhB   = (unsigned short*)(ws + OFF_X0);   // overlays x0+hfin after k9

    k1_embed<<<(BB*LL*NN)/256, 256, 0, stream>>>(hd, W_emb, b_emb, T_emb, D_emb, node_u,
                                                 W_std, b_std, W_mlp, b_mlp, hist, h0, s4);
    k2_ratio<<<(BB*NN)/256, 256, 0, stream>>>(s4, ratio);
    k3_centers<<<BB, 256, 0, stream>>>(ratio, cent);
    k4_labels<<<NN/256, 256, 0, stream>>>(ratio, cent, node_u, node_d, label, m1, m2);
    k5_A<<<NN, 256, 0, stream>>>(m1, m2, label, An);
    kt_transpose<true><<<dim3(16, 16), 256, 0, stream>>>(An, AnBT, AnB, 1024, 1024);
    gemm_mfma<0><<<dim3(8, 8), 256, 0, stream>>>(AnB, AnBT, AcombB, 1024, 1024);
    k7_x0<<<BB*NN, 256, 0, stream>>>(hist, W_start, b_start, x0);
    kt_transpose<false><<<dim3(128, 16), 256, 0, stream>>>(x0, x0T, (unsigned short*)0, 1024, 8192);
    gemm_mfma<1><<<dim3(64, 8), 256, 0, stream>>>(AcombB, x0T, hfin, 8192, 1024);
    kw_combo<<<1, 128, 0, stream>>>(W_g, W_rnn, wcombo);
    k9_rnn2<<<BB*NN, 256, 0, stream>>>(hfin, wcombo, b_rnn, W_e1, b_e1, W_e2, b_e2, Mm, xoutB);
    kp_fh<<<(BB*LL*NN)/128, 256, 0, stream>>>(xoutB, hist, h0, hd, T_emb, D_emb, fhB);
    kt_w1<<<(512*288)/256, 256, 0, stream>>>(W_f1, w1hi, w1lo);
    hipMemsetAsync(fc, 0, (size_t)BB*LL*NN*3*sizeof(float), stream);
    k10_mfma<<<dim3(4, 768), 256, 0, stream>>>(fhB, w1hi, w1lo, b_f1, W_f2, fc);
    k11_e3<<<(BB*NN*12)/256, 256, 0, stream>>>(fc, b_f2, W_e3, b_e3, (float*)d_out);
}

// Round 6
// 623.369 us; speedup vs baseline: 3.4580x; 1.3324x over previous
//
#include <hip/hip_runtime.h>
#include <math.h>

#define BB 8
#define LL 12
#define NN 1024
#define FF 3
#define HH 32
#define NDD 10
#define TTT 10
#define PP 3
#define DOUTT 128
constexpr float kALPHA = 3.0f;

typedef __attribute__((ext_vector_type(8))) short short8v;   // 8 bf16 (4 VGPR)
typedef __attribute__((ext_vector_type(4))) float float4v;

__device__ __forceinline__ unsigned short f2bf(float x) {
    union { float f; unsigned u; } v; v.f = x;
    unsigned r = v.u + 0x7FFF + ((v.u >> 16) & 1);
    return (unsigned short)(r >> 16);
}
__device__ __forceinline__ float bf2f(unsigned short u) {
    union { unsigned u; float f; } v; v.u = ((unsigned)u) << 16;
    return v.f;
}

// async global->LDS, 16B per lane. LDS dest = wave-uniform base + lane*16.
__device__ __forceinline__ void gload_lds16(const unsigned short* g, unsigned short* l) {
    __builtin_amdgcn_global_load_lds(
        (const __attribute__((address_space(1))) void*)g,
        (__attribute__((address_space(3))) void*)l,
        16, 0, 0);
}

// Stage a 128x32 bf16 tile (row-major, row stride = `stride` elems) into LDS,
// XOR-swizzled: LDS chunk (row, ql) holds global chunk (row, ql ^ ((row>>1)&3)).
__device__ __forceinline__ void stage_tile(const unsigned short* __restrict__ g, int stride,
                                           unsigned short* tile, int tid) {
#pragma unroll
    for (int rr = 0; rr < 2; rr++) {
        int c = rr*256 + tid;
        int row = c >> 2;
        int q = (c & 3) ^ ((row >> 1) & 3);
        gload_lds16(g + (size_t)row*stride + q*8,
                    tile + ((size_t)(rr*256 + (tid & 192)))*8);
    }
}

// ---------------- workspace layout (floats) ----------------
constexpr size_t OFF_HIST    = 0;                                          // B*L*N*32
constexpr size_t OFF_H0      = OFF_HIST   + (size_t)BB*LL*NN*HH;           // B*L*N*96
constexpr size_t OFF_S4      = OFF_H0     + (size_t)BB*LL*NN*3*HH;         // B*L*N*4
constexpr size_t OFF_RATIO   = OFF_S4     + (size_t)BB*LL*NN*4;            // B*N*3
constexpr size_t OFF_CENT    = OFF_RATIO  + (size_t)BB*NN*3;               // 32
constexpr size_t OFF_M1      = OFF_CENT   + 32;                            // N*10
constexpr size_t OFF_M2      = OFF_M1     + (size_t)NN*NDD;                // N*10
constexpr size_t OFF_LABEL   = OFF_M2     + (size_t)NN*NDD;                // N ints
constexpr size_t OFF_AN      = OFF_LABEL  + NN;                            // N*N fp32
constexpr size_t OFF_ACOMBB  = OFF_AN     + (size_t)NN*NN;                 // N*N bf16
constexpr size_t OFF_X0      = OFF_ACOMBB + (size_t)NN*NN/2;               // N*8192 fp32
constexpr size_t OFF_HFINB   = OFF_X0     + (size_t)NN*BB*HH*HH;           // N*8192 bf16
constexpr size_t OFF_WCOMBOT = OFF_HFINB  + (size_t)NN*BB*HH*HH/2;         // 128*32 bf16
constexpr size_t OFF_WE1B    = OFF_WCOMBOT+ 1024*4;                        // 128*32 bf16
constexpr size_t OFF_FC      = OFF_WE1B   + 1024*4;                        // B*12*N*3
constexpr size_t OFF_ANB     = OFF_FC     + (size_t)BB*LL*NN*3;            // 1024*1024 bf16
constexpr size_t OFF_ANBT    = OFF_ANB    + (size_t)NN*NN/2;               // 1024*1024 bf16
constexpr size_t OFF_X0T     = OFF_ANBT   + (size_t)NN*NN/2;               // 8192*1024 bf16
constexpr size_t OFF_W1HI    = OFF_X0T    + (size_t)BB*HH*HH*NN/2;         // 512*288 bf16
constexpr size_t OFF_W1LO    = OFF_W1HI   + (size_t)512*288/2;
constexpr size_t OFF_FHB     = OFF_W1LO   + (size_t)512*288/2;             // 98304*288 bf16
constexpr size_t WS_FLOATS   = OFF_FHB    + (size_t)BB*LL*NN*288/2;        // ~188 MB

// ---------------- K1: embed + std decomposition ----------------
__global__ __launch_bounds__(256) void k1_embed(
    const float* __restrict__ hd, const float* __restrict__ W_emb, const float* __restrict__ b_emb,
    const float* __restrict__ T_emb, const float* __restrict__ D_emb, const float* __restrict__ node_u,
    const float* __restrict__ W_std, const float* __restrict__ b_std,
    const float* __restrict__ W_mlp, const float* __restrict__ b_mlp,
    float* __restrict__ hist, float* __restrict__ h0, float* __restrict__ s4)
{
    __shared__ float sW[2*62*32];
    for (int i = threadIdx.x; i < 2*62*32; i += 256) sW[i] = W_std[i];
    __syncthreads();

    int pos = blockIdx.x*256 + threadIdx.x;
    int n = pos & (NN-1);
    const float* hp = hd + (size_t)pos*5;
    float f0 = hp[0], f1 = hp[1], f2 = hp[2];
    int ti = (int)(hp[3]*288.0f);
    int di = (int)hp[4];

    float tv[10], dv[10], nu[10];
#pragma unroll
    for (int t = 0; t < 10; t++) {
        tv[t] = T_emb[ti*10+t]; dv[t] = D_emb[di*10+t]; nu[t] = node_u[n*10+t];
    }
    float h[32];
#pragma unroll
    for (int j = 0; j < 32; j++) h[j] = b_emb[j] + f0*W_emb[j] + f1*W_emb[32+j] + f2*W_emb[64+j];

    float a0[32], a1[32];
#pragma unroll
    for (int j = 0; j < 32; j++) { a0[j] = b_std[j]; a1[j] = b_std[32+j]; }

    auto accum = [&](float v, int i) {
#pragma unroll
        for (int q = 0; q < 8; q++) {
            float4 w0 = *(const float4*)&sW[i*32 + q*4];
            float4 w1 = *(const float4*)&sW[(62+i)*32 + q*4];
            a0[q*4+0] += v*w0.x; a0[q*4+1] += v*w0.y; a0[q*4+2] += v*w0.z; a0[q*4+3] += v*w0.w;
            a1[q*4+0] += v*w1.x; a1[q*4+1] += v*w1.y; a1[q*4+2] += v*w1.z; a1[q*4+3] += v*w1.w;
        }
    };
#pragma unroll
    for (int i = 0; i < 32; i++) accum(h[i], i);
#pragma unroll
    for (int i = 0; i < 10; i++) accum(nu[i], 32+i);
#pragma unroll
    for (int i = 0; i < 10; i++) accum(tv[i], 42+i);
#pragma unroll
    for (int i = 0; i < 10; i++) accum(dv[i], 52+i);

    float x0v[32], x1v[32], rv[32];
    float s0 = b_mlp[0], s1 = b_mlp[1], s2 = b_mlp[2], s3 = b_mlp[3];
#pragma unroll
    for (int j = 0; j < 32; j++) {
        float sg0 = 1.f/(1.f + __expf(-a0[j]));
        float sg1 = 1.f/(1.f + __expf(-a1[j]));
        x0v[j] = sg0*h[j]; x1v[j] = sg1*h[j]; rv[j] = h[j] - x0v[j] - x1v[j];
        s0 += h[j]  * W_mlp[j];
        s1 += x0v[j]* W_mlp[32+j];
        s2 += x1v[j]* W_mlp[64+j];
        s3 += rv[j] * W_mlp[96+j];
    }
    float* ho = hist + (size_t)pos*32;
    float* hz = h0   + (size_t)pos*96;
#pragma unroll
    for (int q = 0; q < 8; q++) {
        *(float4*)&ho[q*4]    = make_float4(h[q*4],   h[q*4+1],   h[q*4+2],   h[q*4+3]);
        *(float4*)&hz[q*4]    = make_float4(x0v[q*4], x0v[q*4+1], x0v[q*4+2], x0v[q*4+3]);
        *(float4*)&hz[32+q*4] = make_float4(x1v[q*4], x1v[q*4+1], x1v[q*4+2], x1v[q*4+3]);
        *(float4*)&hz[64+q*4] = make_float4(rv[q*4],  rv[q*4+1],  rv[q*4+2],  rv[q*4+3]);
    }
    *(float4*)&s4[(size_t)pos*4] = make_float4(s0, s1, s2, s3);
}

// ---------------- K2: ratios ----------------
__global__ void k2_ratio(const float* __restrict__ s4, float* __restrict__ ratio)
{
    int bn = blockIdx.x*256 + threadIdx.x;
    if (bn >= BB*NN) return;
    int b = bn >> 10, n = bn & 1023;
    float a0=0, a1=0, a2=0, a3=0;
    for (int l = 0; l < 12; l++) {
        const float* sp = s4 + ((size_t)(b*12+l)*NN + n)*4;
        a0 += sp[0]; a1 += sp[1]; a2 += sp[2]; a3 += sp[3];
    }
    float hm = a0/12.f;
    float* rp = ratio + (size_t)bn*3;
    rp[0] = (a1/12.f)/(hm + 1e-6f);
    rp[1] = (a2/12.f)/(hm + 1e-6f);
    rp[2] = (a3/12.f)/(hm + 1e-6f);
}

// ---------------- K3: per-b centers ----------------
__global__ __launch_bounds__(256) void k3_centers(const float* __restrict__ ratio, float* __restrict__ centers)
{
    int b = blockIdx.x;
    float m0=-3.4e38f, m1v=-3.4e38f, m2v=-3.4e38f;
    for (int n = threadIdx.x; n < NN; n += 256) {
        const float* rp = ratio + ((size_t)b*NN + n)*3;
        m0 = fmaxf(m0, rp[0]); m1v = fmaxf(m1v, rp[1]); m2v = fmaxf(m2v, rp[2]);
    }
#pragma unroll
    for (int off = 32; off > 0; off >>= 1) {
        m0  = fmaxf(m0,  __shfl_down(m0,  off));
        m1v = fmaxf(m1v, __shfl_down(m1v, off));
        m2v = fmaxf(m2v, __shfl_down(m2v, off));
    }
    __shared__ float red[4][3];
    int wid = threadIdx.x >> 6, lane = threadIdx.x & 63;
    if (lane == 0) { red[wid][0]=m0; red[wid][1]=m1v; red[wid][2]=m2v; }
    __syncthreads();
    if (threadIdx.x == 0) {
        centers[b*3+0] = fmaxf(fmaxf(red[0][0],red[1][0]), fmaxf(red[2][0],red[3][0]));
        centers[b*3+1] = fmaxf(fmaxf(red[0][1],red[1][1]), fmaxf(red[2][1],red[3][1]));
        centers[b*3+2] = fmaxf(fmaxf(red[0][2],red[1][2]), fmaxf(red[2][2],red[3][2]));
    }
}

// ---------------- K4: labels + m1/m2 ----------------
__global__ void k4_labels(const float* __restrict__ ratio, const float* __restrict__ centers,
                          const float* __restrict__ node_u, const float* __restrict__ node_d,
                          int* __restrict__ label, float* __restrict__ m1, float* __restrict__ m2)
{
    int n = blockIdx.x*256 + threadIdx.x;
    if (n >= NN) return;
    int c0=0, c1=0, c2=0;
    for (int b = 0; b < BB; b++) {
        const float* rp = ratio + ((size_t)b*NN + n)*3;
        const float* cp = centers + b*3;
        float d0 = fabsf(rp[0]-cp[0]), d1 = fabsf(rp[1]-cp[1]), d2 = fabsf(rp[2]-cp[2]);
        int a = 0; float best = d0;
        if (d1 < best) { best = d1; a = 1; }
        if (d2 < best) { best = d2; a = 2; }
        if (a == 0) c0++; else if (a == 1) c1++; else c2++;
    }
    int lab = 0, bc = c0;
    if (c1 > bc) { bc = c1; lab = 1; }
    if (c2 > bc) { bc = c2; lab = 2; }
    label[n] = lab;
#pragma unroll
    for (int d = 0; d < 10; d++) {
        m1[n*10+d] = tanhf(kALPHA*node_u[n*10+d]);
        m2[n*10+d] = tanhf(kALPHA*node_d[n*10+d]);
    }
}

// ---------------- K5: An ----------------
__global__ __launch_bounds__(256) void k5_A(const float* __restrict__ m1, const float* __restrict__ m2,
                                            const int* __restrict__ label, float* __restrict__ An)
{
    int n = blockIdx.x;
    __shared__ float row[1024];
    __shared__ float m1n[10], m2n[10];
    __shared__ float ssum[4];
    int t = threadIdx.x;
    if (t < 10) { m1n[t] = m1[n*10+t]; m2n[t] = m2[n*10+t]; }
    __syncthreads();
    int labn = label[n];
    float lsum = 0.f;
    for (int m = t; m < 1024; m += 256) {
        float a = 0.f;
        if (label[m] == labn) {
            float x = 0.f;
#pragma unroll
            for (int d = 0; d < 10; d++) x += m1n[d]*m2[m*10+d] - m2n[d]*m1[m*10+d];
            a = fmaxf(tanhf(3.f*x), 0.f);
        }
        row[m] = a; lsum += a;
    }
#pragma unroll
    for (int off = 32; off > 0; off >>= 1) lsum += __shfl_down(lsum, off);
    int wid = t >> 6, lane = t & 63;
    if (lane == 0) ssum[wid] = lsum;
    __syncthreads();
    float inv = 1.f/((ssum[0]+ssum[1]+ssum[2]+ssum[3]) + 1e-6f);
    for (int m = t; m < 1024; m += 256) An[(size_t)n*1024 + m] = row[m]*inv;
}

// ---------------- transpose fp32 [R][C] -> bf16 outT[C][R] ----------------
template<bool ALSO_DIRECT>
__global__ __launch_bounds__(256) void kt_transpose(const float* __restrict__ in,
                                                    unsigned short* __restrict__ outT,
                                                    unsigned short* __restrict__ outD,
                                                    int R, int C)
{
    __shared__ float tile[64][65];
    int c0 = blockIdx.x*64, r0 = blockIdx.y*64;
    for (int i = threadIdx.x; i < 64*64; i += 256) {
        int r = i >> 6, c = i & 63;
        float v = in[(size_t)(r0+r)*C + c0+c];
        tile[r][c] = v;
        if (ALSO_DIRECT) outD[(size_t)(r0+r)*C + c0+c] = f2bf(v);
    }
    __syncthreads();
    for (int i = threadIdx.x; i < 64*64; i += 256) {
        int c = i >> 6, r = i & 63;
        outT[(size_t)(c0+c)*R + r0+r] = f2bf(tile[r][c]);
    }
}

// ---------------- bf16 MFMA GEMM, 128x128 tile, 2-phase pipelined, swizzled gload_lds ----------------
// MODE 0: AcombB(bf16) = bf16(0.9025*acc + 0.0475*A + 0.05*I)
// MODE 2: C(bf16) = acc
template<int MODE>
__global__ __launch_bounds__(256) void gemm_mfma(
    const unsigned short* __restrict__ A, const unsigned short* __restrict__ B,
    void* __restrict__ Cout, int Nout, int K)
{
    __shared__ __align__(16) unsigned short lds[2][2][128*32];
    const int t = threadIdx.x;

    int id = blockIdx.x + gridDim.x*blockIdx.y;
    int gx8 = gridDim.x >> 3;
    int xcd = id & 7, local = id >> 3;
    int bx = xcd*gx8 + (local % gx8);
    int by = local / gx8;

    const int lane = t & 63, wid = t >> 6;
    const int wr = wid >> 1, wc = wid & 1;
    const int l15 = lane & 15, l4 = lane >> 4;
    const int swq8 = (l4 ^ ((l15 >> 1) & 3))*8;
    const int row0 = by*128, col0 = bx*128;

    float4v acc[4][4];
#pragma unroll
    for (int i = 0; i < 4; i++)
#pragma unroll
        for (int j = 0; j < 4; j++) acc[i][j] = (float4v){0.f,0.f,0.f,0.f};

    const unsigned short* Ab = A + (size_t)row0*K;
    const unsigned short* Bb = B + (size_t)col0*K;

    stage_tile(Ab, K, lds[0][0], t);
    stage_tile(Bb, K, lds[0][1], t);
    __syncthreads();

    const int nk = K >> 5;
    for (int ks = 0; ks < nk; ks++) {
        int cur = ks & 1;
        if (ks + 1 < nk) {
            stage_tile(Ab + (ks+1)*32, K, lds[cur^1][0], t);
            stage_tile(Bb + (ks+1)*32, K, lds[cur^1][1], t);
        }
        short8v a[4], b[4];
#pragma unroll
        for (int f = 0; f < 4; f++) {
            a[f] = *(const short8v*)&lds[cur][0][(wr*64 + f*16 + l15)*32 + swq8];
            b[f] = *(const short8v*)&lds[cur][1][(wc*64 + f*16 + l15)*32 + swq8];
        }
#pragma unroll
        for (int i = 0; i < 4; i++)
#pragma unroll
            for (int j = 0; j < 4; j++)
                acc[i][j] = __builtin_amdgcn_mfma_f32_16x16x32_bf16(a[i], b[j], acc[i][j], 0, 0, 0);
        __syncthreads();
    }

#pragma unroll
    for (int i = 0; i < 4; i++) {
#pragma unroll
        for (int j = 0; j < 4; j++) {
            int gc = col0 + wc*64 + j*16 + l15;
#pragma unroll
            for (int r = 0; r < 4; r++) {
                int gr = row0 + wr*64 + i*16 + l4*4 + r;
                if (MODE == 0) {
                    float an = bf2f(A[(size_t)gr*K + gc]);
                    float v = 0.9025f*acc[i][j][r] + 0.0475f*an + ((gr==gc) ? 0.05f : 0.f);
                    ((unsigned short*)Cout)[(size_t)gr*Nout + gc] = f2bf(v);
                } else {
                    ((unsigned short*)Cout)[(size_t)gr*Nout + gc] = f2bf(acc[i][j][r]);
                }
            }
        }
    }
}

// ---------------- K7: x0[n, b*1024 + c*32 + h] ----------------
__global__ __launch_bounds__(256) void k7_x0(const float* __restrict__ hist,
                                             const float* __restrict__ W_start, const float* __restrict__ b_start,
                                             float* __restrict__ x0)
{
    int bid = blockIdx.x; int n = bid & (NN-1), b = bid >> 10;
    __shared__ float hl[384];
    __shared__ float sw[384];
    int t = threadIdx.x;
    for (int idx = t; idx < 384; idx += 256) {
        int l = idx >> 5, hh = idx & 31;
        hl[idx] = hist[((size_t)(b*12+l)*NN + n)*32 + hh];
    }
    for (int idx = t; idx < 384; idx += 256) sw[idx] = W_start[idx];
    __syncthreads();
    int c = t >> 3, h4 = (t & 7)*4;
    float bs = b_start[c];
    float o0 = bs, o1 = bs, o2 = bs, o3 = bs;
#pragma unroll
    for (int l = 0; l < 12; l++) {
        float w = sw[c*12+l];
        o0 += w*hl[l*32+h4];   o1 += w*hl[l*32+h4+1];
        o2 += w*hl[l*32+h4+2]; o3 += w*hl[l*32+h4+3];
    }
    *(float4*)&x0[(size_t)n*8192 + b*1024 + c*32 + h4] = make_float4(o0, o1, o2, o3);
}

// ---------------- Kw: wcomboT bf16 [128 j][32 h] + we1B bf16 [128 o1][32 c] ----------------
__global__ void kw_combo2(const float* __restrict__ W_g, const float* __restrict__ W_rnn,
                          const float* __restrict__ W_e1,
                          unsigned short* __restrict__ wcomboT, unsigned short* __restrict__ we1B)
{
    int j = threadIdx.x;  // 128
    for (int hh = 0; hh < 32; hh++) {
        float s = 0.f;
        for (int k = 0; k < 32; k++) s += (W_g[hh*32+k] + W_g[1024 + hh*32+k]) * W_rnn[k*128 + j];
        wcomboT[j*32 + hh] = f2bf(s);
    }
    for (int i = j; i < 4096; i += 128) we1B[i] = f2bf(W_e1[i]);
}

// ---------------- K9 MFMA: per (b,n): xr=tanh(H@WcT+b); y=relu(We1@xr+b); v=We2@y; fhB[:,0:128] ----------------
// 4 waves; wave `wid` owns j in [wid*32, wid*32+32). No inter-wave deps after staging barrier.
__global__ __launch_bounds__(256) void k9_mfma(
    const unsigned short* __restrict__ hfinB,    // [N][8192] bf16
    const unsigned short* __restrict__ wcomboT,  // [128][32] bf16
    const float* __restrict__ b_rnn,
    const unsigned short* __restrict__ we1B,     // [128][32] bf16
    const float* __restrict__ b_e1,
    const float* __restrict__ W_e2,              // [12][128]
    const float* __restrict__ b_e2,
    const float* __restrict__ Mm,                // [N][128]
    unsigned short* __restrict__ fhB)            // [98304][288], cols 0..127
{
    __shared__ __align__(16) unsigned short xrT[4][1024];   // per-wave [jl][c] swizzled, 8KB
    __shared__ float sWe2T[128][12];                        // [o1][o2], 6KB
    __shared__ float sBe1[128];
    __shared__ float sBe2[16];

    const int t = threadIdx.x;
    const int bid = blockIdx.x;
    const int n = bid & (NN-1), b = bid >> 10;
    const int lane = t & 63, wid = t >> 6;
    const int l15 = lane & 15, l4 = lane >> 4;
    const int j0 = wid*32;

    for (int i = t; i < 12*128; i += 256) {
        int o2 = i >> 7, o1 = i & 127;
        sWe2T[o1][o2] = W_e2[i];
    }
    if (t < 128) sBe1[t] = b_e1[t];
    if (t < 12)  sBe2[t] = b_e2[t];
    __syncthreads();

    // ---- phase A: xr[32c x 32j] = tanh(H @ WcT + b_rnn) ----
    const unsigned short* Hb = hfinB + (size_t)n*8192 + (size_t)b*1024;
    short8v ah[2], bw[2];
#pragma unroll
    for (int f = 0; f < 2; f++) {
        ah[f] = *(const short8v*)&Hb[(f*16 + l15)*32 + l4*8];
        bw[f] = *(const short8v*)&wcomboT[(j0 + f*16 + l15)*32 + l4*8];
    }
    float br[2];
    br[0] = b_rnn[j0 + l15];
    br[1] = b_rnn[j0 + 16 + l15];
    float4v accA[2][2];
#pragma unroll
    for (int cf = 0; cf < 2; cf++)
#pragma unroll
        for (int jf = 0; jf < 2; jf++)
            accA[cf][jf] = (float4v){br[jf], br[jf], br[jf], br[jf]};
#pragma unroll
    for (int cf = 0; cf < 2; cf++)
#pragma unroll
        for (int jf = 0; jf < 2; jf++)
            accA[cf][jf] = __builtin_amdgcn_mfma_f32_16x16x32_bf16(ah[cf], bw[jf], accA[cf][jf], 0, 0, 0);

    // tanh + bf16 pack + swizzled LDS write (per-wave private slice; no barrier needed)
#pragma unroll
    for (int cf = 0; cf < 2; cf++)
#pragma unroll
        for (int jf = 0; jf < 2; jf++) {
            int jl = jf*16 + l15;
            int csw = (cf*16 + l4*4) ^ ((jl & 3) << 3);
            unsigned short p0 = f2bf(tanhf(accA[cf][jf][0]));
            unsigned short p1 = f2bf(tanhf(accA[cf][jf][1]));
            unsigned short p2 = f2bf(tanhf(accA[cf][jf][2]));
            unsigned short p3 = f2bf(tanhf(accA[cf][jf][3]));
            unsigned int lo = (unsigned)p0 | ((unsigned)p1 << 16);
            unsigned int hi = (unsigned)p2 | ((unsigned)p3 << 16);
            *(uint2*)&xrT[wid][jl*32 + csw] = make_uint2(lo, hi);
        }

    // ---- phase B: y[128 o1 x 32j] = We1 @ xr (MFMA, acc holds y pre-bias) ----
    short8v bx[2];
#pragma unroll
    for (int jf = 0; jf < 2; jf++) {
        int jl = jf*16 + l15;
        int csw = (l4*8) ^ ((jl & 3) << 3);
        bx[jf] = *(const short8v*)&xrT[wid][jl*32 + csw];
    }
    float4v accB[8][2];
#pragma unroll
    for (int of = 0; of < 8; of++)
#pragma unroll
        for (int jf = 0; jf < 2; jf++) accB[of][jf] = (float4v){0.f,0.f,0.f,0.f};
#pragma unroll
    for (int of = 0; of < 8; of++) {
        short8v aw = *(const short8v*)&we1B[(of*16 + l15)*32 + l4*8];
        accB[of][0] = __builtin_amdgcn_mfma_f32_16x16x32_bf16(aw, bx[0], accB[of][0], 0, 0, 0);
        accB[of][1] = __builtin_amdgcn_mfma_f32_16x16x32_bf16(aw, bx[1], accB[of][1], 0, 0, 0);
    }

    // ---- e2 (VALU on fp32 acc): v[o2][j] = sum_o1 We2[o2][o1] * relu(y + be1) ----
    float v0[12], v1[12];
#pragma unroll
    for (int o2 = 0; o2 < 12; o2++) { v0[o2] = 0.f; v1[o2] = 0.f; }
#pragma unroll
    for (int of = 0; of < 8; of++) {
#pragma unroll
        for (int r = 0; r < 4; r++) {
            int o1 = of*16 + l4*4 + r;
            float be = sBe1[o1];
            float z0 = fmaxf(accB[of][0][r] + be, 0.f);
            float z1 = fmaxf(accB[of][1][r] + be, 0.f);
#pragma unroll
            for (int q = 0; q < 3; q++) {
                float4 w = *(const float4*)&sWe2T[o1][q*4];
                v0[q*4+0] += w.x*z0; v0[q*4+1] += w.y*z0; v0[q*4+2] += w.z*z0; v0[q*4+3] += w.w*z0;
                v1[q*4+0] += w.x*z1; v1[q*4+1] += w.y*z1; v1[q*4+2] += w.z*z1; v1[q*4+3] += w.w*z1;
            }
        }
    }
    // butterfly over l4 groups (rows) -> full column sums in every lane
#pragma unroll
    for (int o2 = 0; o2 < 12; o2++) {
        v0[o2] += __shfl_xor(v0[o2], 16);
        v0[o2] += __shfl_xor(v0[o2], 32);
        v1[o2] += __shfl_xor(v1[o2], 16);
        v1[o2] += __shfl_xor(v1[o2], 32);
    }

    // epilogue: each l4 group stores 3 o2 rows; fold +b_e2, *M, relu, bf16
    float mm0 = Mm[(size_t)n*128 + j0 + l15];
    float mm1 = Mm[(size_t)n*128 + j0 + 16 + l15];
#pragma unroll
    for (int e = 0; e < 3; e++) {
        int o2 = l4*3 + e;
        float be2 = sBe2[o2];
        size_t base = ((size_t)((b*12 + o2)*NN + n))*288;
        float val0 = (v0[o2] + be2) * mm0;
        float val1 = (v1[o2] + be2) * mm1;
        fhB[base + j0 + l15]      = f2bf(fmaxf(val0, 0.f));
        fhB[base + j0 + 16 + l15] = f2bf(fmaxf(val1, 0.f));
    }
}

// ---------------- kp_fh: fill fhB cols 128..287 (hist/h0/tid/diw), relu'd bf16 ----------------
__global__ __launch_bounds__(256) void kp_fh(
    const float* __restrict__ hist, const float* __restrict__ h0,
    const float* __restrict__ hd, const float* __restrict__ T_emb, const float* __restrict__ D_emb,
    unsigned short* __restrict__ fhB)
{
    int pos_base = blockIdx.x * 128;
    for (int idx = threadIdx.x; idx < 128*160; idx += 256) {
        int r = idx / 160, kk = idx - r*160;
        int k = 128 + kk;
        int pos = pos_base + r;
        float v = 0.f;
        if (k < 160)       v = hist[(size_t)pos*32 + (k-128)];
        else if (k < 256)  v = h0[(size_t)pos*96 + (k-160)];
        else if (k < 266) { int ti = (int)(hd[(size_t)pos*5+3]*288.0f); v = T_emb[ti*10 + (k-256)]; }
        else if (k < 276) { int di = (int)hd[(size_t)pos*5+4];          v = D_emb[di*10 + (k-266)]; }
        fhB[(size_t)pos*288 + k] = f2bf(fmaxf(v, 0.f));
    }
}

// ---------------- kt_w1: W_f1 -> hi/lo bf16 [512][288] (n-major) ----------------
__global__ void kt_w1(const float* __restrict__ W_f1, unsigned short* __restrict__ w1hi,
                      unsigned short* __restrict__ w1lo)
{
    int idx = blockIdx.x*256 + threadIdx.x;
    if (idx >= 512*288) return;
    int n = idx / 288, k = idx - n*288;
    float w = (k < 276) ? W_f1[(size_t)k*512 + n] : 0.f;
    unsigned short hi = f2bf(w);
    w1hi[idx] = hi;
    w1lo[idx] = f2bf(w - bf2f(hi));
}

// ---------------- K10 MFMA head ----------------
__global__ __launch_bounds__(256) void k10_mfma(
    const unsigned short* __restrict__ fhB, const unsigned short* __restrict__ w1hi,
    const unsigned short* __restrict__ w1lo, const float* __restrict__ b_f1,
    const float* __restrict__ W_f2, float* __restrict__ fc)
{
    __shared__ __align__(16) unsigned short lds[2][3][128*32];
    __shared__ float fcp[384];

    const int t = threadIdx.x;

    int id = blockIdx.x + gridDim.x*blockIdx.y;          // gridDim = (4, 768)
    int cpx = (4*768) >> 3;
    int sid = (id & 7)*cpx + (id >> 3);
    int bx = sid & 3, by = sid >> 2;

    const int lane = t & 63, wid = t >> 6;
    const int wr = wid >> 1, wc = wid & 1;
    const int l15 = lane & 15, l4 = lane >> 4;
    const int swq8 = (l4 ^ ((l15 >> 1) & 3))*8;
    const int pos0 = by*128, col0 = bx*128;

    for (int i = t; i < 384; i += 256) fcp[i] = 0.f;

    float4v acc[4][4];
#pragma unroll
    for (int i = 0; i < 4; i++)
#pragma unroll
        for (int j = 0; j < 4; j++) acc[i][j] = (float4v){0.f,0.f,0.f,0.f};

    const unsigned short* Ab = fhB  + (size_t)pos0*288;
    const unsigned short* Hb = w1hi + (size_t)col0*288;
    const unsigned short* Lb = w1lo + (size_t)col0*288;

    stage_tile(Ab, 288, lds[0][0], t);
    stage_tile(Hb, 288, lds[0][1], t);
    stage_tile(Lb, 288, lds[0][2], t);
    __syncthreads();

    for (int ks = 0; ks < 9; ks++) {
        int cur = ks & 1;
        if (ks + 1 < 9) {
            stage_tile(Ab + (ks+1)*32, 288, lds[cur^1][0], t);
            stage_tile(Hb + (ks+1)*32, 288, lds[cur^1][1], t);
            stage_tile(Lb + (ks+1)*32, 288, lds[cur^1][2], t);
        }
        short8v a[4], bh[4], bl[4];
#pragma unroll
        for (int f = 0; f < 4; f++) {
            a[f]  = *(const short8v*)&lds[cur][0][(wr*64 + f*16 + l15)*32 + swq8];
            bh[f] = *(const short8v*)&lds[cur][1][(wc*64 + f*16 + l15)*32 + swq8];
            bl[f] = *(const short8v*)&lds[cur][2][(wc*64 + f*16 + l15)*32 + swq8];
        }
#pragma unroll
        for (int i = 0; i < 4; i++)
#pragma unroll
            for (int j = 0; j < 4; j++) {
                acc[i][j] = __builtin_amdgcn_mfma_f32_16x16x32_bf16(a[i], bh[j], acc[i][j], 0, 0, 0);
                acc[i][j] = __builtin_amdgcn_mfma_f32_16x16x32_bf16(a[i], bl[j], acc[i][j], 0, 0, 0);
            }
        __syncthreads();
    }

    float pk[4][4][3];
#pragma unroll
    for (int i = 0; i < 4; i++)
#pragma unroll
        for (int r = 0; r < 4; r++)
#pragma unroll
            for (int k = 0; k < 3; k++) pk[i][r][k] = 0.f;

#pragma unroll
    for (int j = 0; j < 4; j++) {
        int gc = col0 + wc*64 + j*16 + l15;
        float bias = b_f1[gc];
        float w20 = W_f2[gc*3+0], w21 = W_f2[gc*3+1], w22 = W_f2[gc*3+2];
#pragma unroll
        for (int i = 0; i < 4; i++)
#pragma unroll
            for (int r = 0; r < 4; r++) {
                float z = fmaxf(acc[i][j][r] + bias, 0.f);
                pk[i][r][0] += z*w20; pk[i][r][1] += z*w21; pk[i][r][2] += z*w22;
            }
    }
#pragma unroll
    for (int i = 0; i < 4; i++)
#pragma unroll
        for (int r = 0; r < 4; r++) {
            int rowL = wr*64 + i*16 + l4*4 + r;
            atomicAdd(&fcp[rowL*3 + 0], pk[i][r][0]);
            atomicAdd(&fcp[rowL*3 + 1], pk[i][r][1]);
            atomicAdd(&fcp[rowL*3 + 2], pk[i][r][2]);
        }
    __syncthreads();
    for (int i = t; i < 384; i += 256) {
        atomicAdd(&fc[(size_t)pos0*3 + i], fcp[i]);
    }
}

// ---------------- K11: e3 epilogue + transpose ----------------
__global__ void k11_e3(const float* __restrict__ fc, const float* __restrict__ b_f2,
                       const float* __restrict__ W_e3, const float* __restrict__ b_e3,
                       float* __restrict__ out)
{
    int idx = blockIdx.x*256 + threadIdx.x;
    if (idx >= BB*NN*12) return;
    int ok = idx % 12;
    int o = ok / 3, k = ok % 3;
    int bn = idx / 12;
    int n = bn & 1023, b = bn >> 10;
    float s = b_e3[o];
    float bk = b_f2[k];
#pragma unroll
    for (int c = 0; c < 12; c++)
        s += W_e3[o*12+c] * (fc[((size_t)(b*12+c)*NN + n)*3 + k] + bk);
    out[idx] = s;
}

extern "C" void kernel_launch(void* const* d_in, const int* in_sizes, int n_in,
                              void* d_out, int out_size, void* d_ws, size_t ws_size,
                              hipStream_t stream)
{
    const float* hd      = (const float*)d_in[0];
    const float* W_emb   = (const float*)d_in[1];
    const float* b_emb   = (const float*)d_in[2];
    const float* T_emb   = (const float*)d_in[3];
    const float* D_emb   = (const float*)d_in[4];
    const float* node_u  = (const float*)d_in[5];
    const float* node_d  = (const float*)d_in[6];
    const float* W_std   = (const float*)d_in[7];
    const float* b_std   = (const float*)d_in[8];
    const float* W_mlp   = (const float*)d_in[9];
    const float* b_mlp   = (const float*)d_in[10];
    const float* W_start = (const float*)d_in[11];
    const float* b_start = (const float*)d_in[12];
    const float* W_g     = (const float*)d_in[13];
    const float* W_rnn   = (const float*)d_in[14];
    const float* b_rnn   = (const float*)d_in[15];
    const float* W_e1    = (const float*)d_in[16];
    const float* b_e1    = (const float*)d_in[17];
    const float* W_e2    = (const float*)d_in[18];
    const float* b_e2    = (const float*)d_in[19];
    const float* Mm      = (const float*)d_in[20];
    const float* W_f1    = (const float*)d_in[21];
    const float* b_f1    = (const float*)d_in[22];
    const float* W_f2    = (const float*)d_in[23];
    const float* b_f2    = (const float*)d_in[24];
    const float* W_e3    = (const float*)d_in[25];
    const float* b_e3    = (const float*)d_in[26];

    float* ws      = (float*)d_ws;
    float* hist    = ws + OFF_HIST;
    float* h0      = ws + OFF_H0;
    float* s4      = ws + OFF_S4;
    float* ratio   = ws + OFF_RATIO;
    float* cent    = ws + OFF_CENT;
    float* m1      = ws + OFF_M1;
    float* m2      = ws + OFF_M2;
    int*   label   = (int*)(ws + OFF_LABEL);
    float* An      = ws + OFF_AN;
    unsigned short* AcombB  = (unsigned short*)(ws + OFF_ACOMBB);
    float* x0      = ws + OFF_X0;
    unsigned short* hfinB   = (unsigned short*)(ws + OFF_HFINB);
    unsigned short* wcomboT = (unsigned short*)(ws + OFF_WCOMBOT);
    unsigned short* we1B    = (unsigned short*)(ws + OFF_WE1B);
    float* fc      = ws + OFF_FC;
    unsigned short* AnB   = (unsigned short*)(ws + OFF_ANB);
    unsigned short* AnBT  = (unsigned short*)(ws + OFF_ANBT);
    unsigned short* x0T   = (unsigned short*)(ws + OFF_X0T);
    unsigned short* w1hi  = (unsigned short*)(ws + OFF_W1HI);
    unsigned short* w1lo  = (unsigned short*)(ws + OFF_W1LO);
    unsigned short* fhB   = (unsigned short*)(ws + OFF_FHB);

    k1_embed<<<(BB*LL*NN)/256, 256, 0, stream>>>(hd, W_emb, b_emb, T_emb, D_emb, node_u,
                                                 W_std, b_std, W_mlp, b_mlp, hist, h0, s4);
    k2_ratio<<<(BB*NN)/256, 256, 0, stream>>>(s4, ratio);
    k3_centers<<<BB, 256, 0, stream>>>(ratio, cent);
    k4_labels<<<NN/256, 256, 0, stream>>>(ratio, cent, node_u, node_d, label, m1, m2);
    k5_A<<<NN, 256, 0, stream>>>(m1, m2, label, An);
    kt_transpose<true><<<dim3(16, 16), 256, 0, stream>>>(An, AnBT, AnB, 1024, 1024);
    gemm_mfma<0><<<dim3(8, 8), 256, 0, stream>>>(AnB, AnBT, AcombB, 1024, 1024);
    k7_x0<<<BB*NN, 256, 0, stream>>>(hist, W_start, b_start, x0);
    kt_transpose<false><<<dim3(128, 16), 256, 0, stream>>>(x0, x0T, (unsigned short*)0, 1024, 8192);
    gemm_mfma<2><<<dim3(64, 8), 256, 0, stream>>>(AcombB, x0T, hfinB, 8192, 1024);
    kw_combo2<<<1, 128, 0, stream>>>(W_g, W_rnn, W_e1, wcomboT, we1B);
    kp_fh<<<(BB*LL*NN)/128, 256, 0, stream>>>(hist, h0, hd, T_emb, D_emb, fhB);
    k9_mfma<<<BB*NN, 256, 0, stream>>>(hfinB, wcomboT, b_rnn, we1B, b_e1, W_e2, b_e2, Mm, fhB);
    kt_w1<<<(512*288)/256, 256, 0, stream>>>(W_f1, w1hi, w1lo);
    hipMemsetAsync(fc, 0, (size_t)BB*LL*NN*3*sizeof(float), stream);
    k10_mfma<<<dim3(4, 768), 256, 0, stream>>>(fhB, w1hi, w1lo, b_f1, W_f2, fc);
    k11_e3<<<(BB*NN*12)/256, 256, 0, stream>>>(fc, b_f2, W_e3, b_e3, (float*)d_out);
}